// Round 4
// baseline (1369.100 us; speedup 1.0000x reference)
//
#include <hip/hip_runtime.h>
#include <math.h>

#define NN 50000
#define NE 800000
#define DIN 128
#define DH 256
#define DED 32
#define NG 500
#define DOUT 16
#define SCAN_T 256

typedef __bf16 bf16_t;
typedef __bf16 bf16x4 __attribute__((ext_vector_type(4)));
typedef __bf16 bf16x8 __attribute__((ext_vector_type(8)));
typedef float f32x4 __attribute__((ext_vector_type(4)));

// async global->LDS, 16B per lane (global_load_lds_dwordx4)
__device__ __forceinline__ void async_copy16(const bf16_t* g, bf16_t* l) {
  __builtin_amdgcn_global_load_lds(
      (const __attribute__((address_space(1))) void*)g,
      (__attribute__((address_space(3))) void*)l, 16, 0, 0);
}

// ---------------- utility ----------------
__global__ void fill_i32(int* __restrict__ p, int v, int n) {
  int i = blockIdx.x * 256 + threadIdx.x;
  if (i < n) p[i] = v;
}
__global__ void cast_bf16x8_k(const float* __restrict__ in, bf16_t* __restrict__ o, long n8) {
  long i = (long)blockIdx.x * 256 + threadIdx.x;
  if (i >= n8) return;
  const f32x4* sp = (const f32x4*)&in[i * 8];
  f32x4 a = __builtin_nontemporal_load(sp);
  f32x4 b = __builtin_nontemporal_load(sp + 1);
  bf16x8 r;
#pragma unroll
  for (int j = 0; j < 4; ++j) { r[j] = (bf16_t)a[j]; r[j + 4] = (bf16_t)b[j]; }
  *(bf16x8*)&o[i * 8] = r;
}

// ---------------- CSR build (by dst) ----------------
__global__ void count_k(const int* __restrict__ dst, int* __restrict__ deg) {
  int e = blockIdx.x * 256 + threadIdx.x;
  if (e < NE) atomicAdd(&deg[dst[e]], 1);
}
__global__ void scan1(const int* __restrict__ deg, int* __restrict__ rowptr,
                      int* __restrict__ bsum, int n) {
  __shared__ int s[SCAN_T];
  int t = threadIdx.x, i = blockIdx.x * SCAN_T + t;
  int v = (i < n) ? deg[i] : 0;
  s[t] = v; __syncthreads();
  for (int off = 1; off < SCAN_T; off <<= 1) {
    int add = (t >= off) ? s[t - off] : 0;
    __syncthreads(); s[t] += add; __syncthreads();
  }
  if (i < n) rowptr[i + 1] = s[t];
  if (t == SCAN_T - 1) bsum[blockIdx.x] = s[t];
}
__global__ void scan2(const int* __restrict__ bsum, int* __restrict__ boff, int nb) {
  __shared__ int s[SCAN_T];
  int t = threadIdx.x;
  int v = (t < nb) ? bsum[t] : 0;
  s[t] = v; __syncthreads();
  for (int off = 1; off < SCAN_T; off <<= 1) {
    int add = (t >= off) ? s[t - off] : 0;
    __syncthreads(); s[t] += add; __syncthreads();
  }
  boff[t] = s[t] - v;
}
__global__ void scan3(int* __restrict__ rowptr, const int* __restrict__ boff, int n) {
  int i = blockIdx.x * 256 + threadIdx.x;
  if (i < n) rowptr[i + 1] += boff[i >> 8];
  if (i == 0) rowptr[0] = 0;
}
// records epos[e] = CSR slot of edge e (inverse permutation) so edge_attr can be
// stream-read / scatter-written instead of gather-read.
__global__ void scatter_k(const int* __restrict__ dst, const int* __restrict__ src,
                          const int* __restrict__ rowptr, int* __restrict__ cursor,
                          int* __restrict__ esrc, int* __restrict__ epos) {
  int e = blockIdx.x * 256 + threadIdx.x;
  if (e < NE) {
    int d = dst[e];
    int pos = rowptr[d] + atomicAdd(&cursor[d], 1);
    esrc[pos] = src[e];
    epos[e] = pos;
  }
}
// cast + permute edge_attr into CSR order: sequential fp32 reads (stream),
// scattered 64B bf16 writes (write path tolerates randomness far better).
__global__ void permute_ea(const int* __restrict__ epos, const float* __restrict__ ea,
                           bf16_t* __restrict__ eac) {
  long t = (long)blockIdx.x * 256 + threadIdx.x;
  if (t >= (long)NE * 4) return;
  int e = (int)(t >> 2), c8 = ((int)t & 3) * 8;
  int pos = epos[e];
  const f32x4* sp = (const f32x4*)&ea[(size_t)e * DED + c8];
  f32x4 a = __builtin_nontemporal_load(sp);
  f32x4 b = __builtin_nontemporal_load(sp + 1);
  bf16x8 o;
#pragma unroll
  for (int j = 0; j < 4; ++j) { o[j] = (bf16_t)a[j]; o[j + 4] = (bf16_t)b[j]; }
  __builtin_nontemporal_store(o, (bf16x8*)&eac[(size_t)pos * DED + c8]);
}

// ---------------- weight fragment packing (all weights, one dispatch) ----------------
struct PackEnt { const float* src; bf16_t* dst; int K; int N; };
struct PackArgs { PackEnt e[16]; };
__global__ void pack_all(PackArgs pa) {
  PackEnt en = pa.e[blockIdx.y];
  int i = blockIdx.x * 256 + threadIdx.x;
  if (i >= en.K * en.N) return;
  int el = i & 511, f = i >> 9;
  int ntiles = en.N >> 4;
  int ks = f / ntiles, t = f - ks * ntiles;
  int lane = el >> 3, j = el & 7;
  int k = ks * 32 + (lane >> 4) * 8 + j;
  int n = t * 16 + (lane & 15);
  en.dst[i] = (bf16_t)en.src[(size_t)k * en.N + n];
}

// Wqe[d][j] = sum_h Wq[d][h]*We[j][h]; bqe[j] = sum_h bq[h]*We[j][h]
__global__ void wqe_k(const float* __restrict__ Wq, const float* __restrict__ We,
                      const float* __restrict__ bq, float* __restrict__ Wqe,
                      float* __restrict__ bqe, int din) {
  int idx = blockIdx.x * 256 + threadIdx.x;
  if (idx < din * 32) {
    int d = idx >> 5, j = idx & 31;
    float s = 0.f;
    for (int h = 0; h < DH; ++h) s += Wq[(size_t)d * DH + h] * We[(size_t)j * DH + h];
    Wqe[idx] = s;
  }
  if (idx < 32) {
    float s = 0.f;
    for (int h = 0; h < DH; ++h) s += bq[h] * We[(size_t)idx * DH + h];
    bqe[idx] = s;
  }
}

// ---------------- MFMA GEMM: 2-phase double-buffered LDS staging ------------
// RT row-tiles per wave: block tile = RT*64 rows x NT*16 cols; BK=32.
// stage(next) issued BEFORE compute(cur); single vmcnt(0)+s_barrier per K-step.
// Optional BN column stats (psum/psq[4][DH]) accumulated from the registers.
template<int NT, int RT>
__device__ __forceinline__ void gemm_body(
    const bf16_t* __restrict__ Ab, const bf16_t* __restrict__ Wp,
    const float* __restrict__ bias, float* __restrict__ Cf, bf16_t* __restrict__ Cb,
    int M, int K, int relu, int rstride, int bx,
    float* __restrict__ psum, float* __restrict__ psq)
{
  __shared__ bf16_t Atile[2][RT * 2048];   // 2 x RT*4 KB
  __shared__ bf16_t Btile[2][NT * 512];    // 2 x NT KB
  const int ACH = RT * 256;                // A 16B-chunks per kstep
  const int NCH = ACH + NT * 64;
  int tid = threadIdx.x;
  int lane = tid & 63, wv = tid >> 6;
  int base = bx * (RT * 64);
  f32x4 acc[RT][NT];
#pragma unroll
  for (int rt = 0; rt < RT; ++rt)
#pragma unroll
    for (int t = 0; t < NT; ++t) acc[rt][t] = (f32x4){0.f, 0.f, 0.f, 0.f};
  int arow = wv * (16 * RT) + (lane & 15);
  int aq = (lane >> 4) * 8;
  int nk = K >> 5;

  auto stage = [&](int buf, int ks) {
    for (int c = tid; c < NCH; c += 256) {
      if (c < ACH) {                       // A: row = c>>2, 16B sub-chunk q = c&3
        int r = c >> 2, qq = c & 3;
        async_copy16(Ab + (size_t)(base + r) * K + ks * 32 + qq * 8,
                     &Atile[buf][c * 8]);
      } else {                             // B: linear 16B chunks of the kstep block
        int cb = c - ACH;
        async_copy16(Wp + (size_t)ks * NT * 512 + cb * 8, &Btile[buf][cb * 8]);
      }
    }
  };

  stage(0, 0);
  asm volatile("s_waitcnt vmcnt(0)" ::: "memory");
  __builtin_amdgcn_s_barrier();
  int cur = 0;
  for (int ks = 0; ks < nk; ++ks) {
    if (ks + 1 < nk) stage(cur ^ 1, ks + 1);   // prefetch overlaps compute below
    bf16x8 a[RT];
#pragma unroll
    for (int rt = 0; rt < RT; ++rt)
      a[rt] = *(const bf16x8*)&Atile[cur][(arow + rt * 16) * 32 + aq];
#pragma unroll
    for (int t = 0; t < NT; ++t) {
      bf16x8 b = *(const bf16x8*)&Btile[cur][t * 512 + lane * 8];
#pragma unroll
      for (int rt = 0; rt < RT; ++rt)
        acc[rt][t] = __builtin_amdgcn_mfma_f32_16x16x32_bf16(a[rt], b, acc[rt][t], 0, 0, 0);
    }
    asm volatile("s_waitcnt vmcnt(0)" ::: "memory");  // next tile landed
    __builtin_amdgcn_s_barrier();                     // all waves done reading cur
    cur ^= 1;
  }
  int col_l = lane & 15;
#pragma unroll
  for (int rt = 0; rt < RT; ++rt) {
    int rbase = base + wv * (16 * RT) + rt * 16 + (lane >> 4) * 4;
#pragma unroll
    for (int t = 0; t < NT; ++t) {
      int col = t * 16 + col_l;
      float bv = bias ? bias[col] : 0.f;
#pragma unroll
      for (int r = 0; r < 4; ++r) {
        int row = rbase + r;
        if (row >= M) continue;
        float vv = acc[rt][t][r] + bv;
        if (relu) vv = fmaxf(vv, 0.f);
        if (Cf) Cf[(size_t)row * rstride + col] = vv;
        if (Cb) Cb[(size_t)row * rstride + col] = (bf16_t)vv;
      }
    }
  }
  if (psum) {                           // fused BN column stats (GIN y1 only)
#pragma unroll
    for (int t = 0; t < NT; ++t) {
      float sc = 0.f, sq = 0.f;
      float bv = bias[t * 16 + col_l];
#pragma unroll
      for (int rt = 0; rt < RT; ++rt) {
        int rbase = base + wv * (16 * RT) + rt * 16 + (lane >> 4) * 4;
#pragma unroll
        for (int r = 0; r < 4; ++r) {
          if (rbase + r >= M) continue;
          float vv = acc[rt][t][r] + bv;
          sc += vv; sq += vv * vv;
        }
      }
      sc += __shfl_xor(sc, 16, 64); sc += __shfl_xor(sc, 32, 64);
      sq += __shfl_xor(sq, 16, 64); sq += __shfl_xor(sq, 32, 64);
      if (lane < 16) {
        int col = t * 16 + lane;
        atomicAdd(&psum[wv * DH + col], sc);
        atomicAdd(&psq[wv * DH + col], sq);
      }
    }
  }
}

template<int NT>
__global__ __launch_bounds__(256, 3) void gemm_r1(
    const bf16_t* __restrict__ Ab, const bf16_t* __restrict__ Wp,
    const float* __restrict__ bias, float* __restrict__ Cf, bf16_t* __restrict__ Cb,
    int M, int K, int relu, int rstride, float* psum, float* psq)
{
  gemm_body<NT, 1>(Ab, Wp, bias, Cf, Cb, M, K, relu, rstride, blockIdx.x, psum, psq);
}

// 4 GEMMs sharing A (q,k,v,s) in one dispatch: grid.y selects the weight set.
struct QkvsArgs { const bf16_t* w[4]; const float* bias[4]; bf16_t* outp[4]; };
__global__ __launch_bounds__(256, 3) void gemm_qkvs(
    const bf16_t* __restrict__ Ab, QkvsArgs qa, int M, int K)
{
  int which = blockIdx.y;
  gemm_body<16, 2>(Ab, qa.w[which], qa.bias[which], nullptr, qa.outp[which], M, K, 0, 1024,
                   blockIdx.x, nullptr, nullptr);
}

// ---------------- fused edge softmax-aggregate: ONE NODE PER WAVE -----------
// Halves process even/odd edges of the SAME node (wave-uniform trip counts).
// v4: register double-buffered gather pipeline — load chunk c+1's k/v/ea while
// computing chunk c (hides ~500cy LLC latency under ~640cy of VALU).
__global__ __launch_bounds__(256) void conv_edge_fused(
    const int* __restrict__ rowptr, const int* __restrict__ esrc,
    const bf16_t* __restrict__ qkvs, const bf16_t* __restrict__ eac,
    const float* __restrict__ QEf,
    bf16_t* __restrict__ AGGn, bf16_t* __restrict__ EAn)
{
  int l = threadIdx.x & 31;
  int half = (threadIdx.x >> 5) & 1;
  int n = blockIdx.x * 4 + (threadIdx.x >> 6);
  if (n >= NN) return;
  float q[8];
  {
    bf16x8 t = __builtin_nontemporal_load((const bf16x8*)&qkvs[(size_t)n * 1024 + l * 8]);
#pragma unroll
    for (int j = 0; j < 8; ++j) q[j] = (float)t[j];
  }
  float qe[8];
#pragma unroll
  for (int j = 0; j < 8; ++j) qe[j] = 0.f;
  if (l < 4) {
    const f32x4* p = (const f32x4*)&QEf[(size_t)n * DED + l * 8];
    f32x4 qa = __builtin_nontemporal_load(p);
    f32x4 qb = __builtin_nontemporal_load(p + 1);
#pragma unroll
    for (int j = 0; j < 4; ++j) { qe[j] = qa[j]; qe[j + 4] = qb[j]; }
  }
  float s = 0.f;
  float acc[8], eacc[8];
#pragma unroll
  for (int j = 0; j < 8; ++j) { acc[j] = 0.f; eacc[j] = 0.f; }
  int i0 = rowptr[n], i1 = rowptr[n + 1];
  for (int wb = i0; wb < i1; wb += 32) {
    int wcnt = min(32, i1 - wb);
    int widx = (l < wcnt) ? esrc[wb + l] : 0;

    // issue 4 edges (this half) of window-chunk at relative pos e..e+7
    auto loadc = [&](int e, bf16x8 (&kk)[4], bf16x8 (&vv)[4], bf16x8 (&tt)[4]) {
#pragma unroll
      for (int u = 0; u < 4; ++u) {
        int sN = __shfl(widx, e + u * 2 + half, 32);
        const bf16_t* bp = &qkvs[(size_t)sN * 1024 + 256 + l * 8];
        kk[u] = *(const bf16x8*)bp;
        vv[u] = *(const bf16x8*)(bp + 256);
      }
      if (l < 4) {
        const bf16_t* ep = &eac[(size_t)(wb + e + half) * DED + l * 8];
#pragma unroll
        for (int u = 0; u < 4; ++u)
          tt[u] = __builtin_nontemporal_load((const bf16x8*)(ep + u * 2 * DED));
      } else {
#pragma unroll
        for (int u = 0; u < 4; ++u) tt[u] = (bf16x8){};
      }
    };
    auto computec = [&](const bf16x8 (&kk)[4], const bf16x8 (&vv)[4],
                        const bf16x8 (&tt)[4]) {
      float p[4] = {0.f, 0.f, 0.f, 0.f};
#pragma unroll
      for (int u = 0; u < 4; ++u) {
#pragma unroll
        for (int j = 0; j < 8; ++j) p[u] = fmaf(q[j], (float)kk[u][j], p[u]);
#pragma unroll
        for (int j = 0; j < 8; ++j) p[u] = fmaf(qe[j], (float)tt[u][j], p[u]);
      }
#pragma unroll
      for (int off = 16; off > 0; off >>= 1) {
#pragma unroll
        for (int u = 0; u < 4; ++u) p[u] += __shfl_xor(p[u], off, 32);
      }
      float ex[4];
#pragma unroll
      for (int u = 0; u < 4; ++u) { ex[u] = __expf(p[u] * 0.0625f); s += ex[u]; }
#pragma unroll
      for (int u = 0; u < 4; ++u) {
#pragma unroll
        for (int j = 0; j < 8; ++j) acc[j] = fmaf(ex[u], (float)vv[u][j], acc[j]);
#pragma unroll
        for (int j = 0; j < 8; ++j) eacc[j] = fmaf(ex[u], (float)tt[u][j], eacc[j]);
      }
    };

    int nfull = wcnt >> 3;   // 8-window-edge chunks (4 per half)
    bf16x8 kA[4], vA[4], tA[4], kB[4], vB[4], tB[4];
    if (nfull > 0) loadc(0, kA, vA, tA);
    int c = 0;
    for (; c + 2 <= nfull; c += 2) {
      loadc((c + 1) * 8, kB, vB, tB);
      computec(kA, vA, tA);
      if (c + 2 < nfull) loadc((c + 2) * 8, kA, vA, tA);
      computec(kB, vB, tB);
    }
    if (c < nfull) computec(kA, vA, tA);

    for (int e = nfull * 8; e < wcnt; e += 2) {   // tail: 1 edge per half, masked
      int eh = e + half;
      bool act = eh < wcnt;
      int s1 = __shfl(widx, act ? eh : e, 32);
      const bf16_t* b1 = &qkvs[(size_t)s1 * 1024 + 256 + l * 8];
      bf16x8 k1 = *(const bf16x8*)b1;
      bf16x8 v1 = *(const bf16x8*)(b1 + 256);
      bf16x8 t1 = {};
      if (act && l < 4)
        t1 = __builtin_nontemporal_load((const bf16x8*)&eac[(size_t)(wb + eh) * DED + l * 8]);
      float p1 = 0.f;
#pragma unroll
      for (int j = 0; j < 8; ++j) p1 = fmaf(q[j], (float)k1[j], p1);
#pragma unroll
      for (int j = 0; j < 8; ++j) p1 = fmaf(qe[j], (float)t1[j], p1);
#pragma unroll
      for (int off = 16; off > 0; off >>= 1) p1 += __shfl_xor(p1, off, 32);
      float ex1 = act ? __expf(p1 * 0.0625f) : 0.f;
      s += ex1;
#pragma unroll
      for (int j = 0; j < 8; ++j) acc[j] = fmaf(ex1, (float)v1[j], acc[j]);
#pragma unroll
      for (int j = 0; j < 8; ++j) eacc[j] = fmaf(ex1, (float)t1[j], eacc[j]);
    }
  }
  // combine halves (same node)
  s += __shfl_xor(s, 32, 64);
#pragma unroll
  for (int j = 0; j < 8; ++j) acc[j] += __shfl_xor(acc[j], 32, 64);
#pragma unroll
  for (int j = 0; j < 8; ++j) eacc[j] += __shfl_xor(eacc[j], 32, 64);
  float inv = 1.f / (s + 1e-16f);
  if (half == 0) {
    bf16x8 o;
#pragma unroll
    for (int j = 0; j < 8; ++j) o[j] = (bf16_t)(acc[j] * inv);
    __builtin_nontemporal_store(o, (bf16x8*)&AGGn[(size_t)n * DH + l * 8]);
    if (l < 4) {
      bf16x8 eo;
#pragma unroll
      for (int j = 0; j < 8; ++j) eo[j] = (bf16_t)(eacc[j] * inv);
      __builtin_nontemporal_store(eo, (bf16x8*)&EAn[(size_t)n * DED + l * 8]);
    }
  }
}

// out = LN( leaky_relu( AGGn + E2N + S ) ) * g + b ; S = qkvs[:,768:1024]
__global__ __launch_bounds__(256) void conv_epilogue(
    const bf16_t* __restrict__ AGGn, const bf16_t* __restrict__ E2N,
    const bf16_t* __restrict__ qkvs, const float* __restrict__ g,
    const float* __restrict__ b, bf16_t* __restrict__ out)
{
  int wv = threadIdx.x >> 6, lane = threadIdx.x & 63;
  int n = blockIdx.x * 4 + wv;
  if (n >= NN) return;
  size_t base = (size_t)n * DH + lane * 4;
  bf16x4 a = __builtin_nontemporal_load((const bf16x4*)&AGGn[base]);
  bf16x4 e2 = __builtin_nontemporal_load((const bf16x4*)&E2N[base]);
  bf16x4 sv = __builtin_nontemporal_load(
      (const bf16x4*)&qkvs[(size_t)n * 1024 + 768 + lane * 4]);
  float v[4];
#pragma unroll
  for (int j = 0; j < 4; ++j) {
    float t = (float)a[j] + (float)e2[j] + (float)sv[j];
    v[j] = (t > 0.f) ? t : 0.01f * t;
  }
  float sum = v[0] + v[1] + v[2] + v[3];
  float sq = v[0]*v[0] + v[1]*v[1] + v[2]*v[2] + v[3]*v[3];
#pragma unroll
  for (int off = 32; off > 0; off >>= 1) {
    sum += __shfl_xor(sum, off, 64);
    sq  += __shfl_xor(sq, off, 64);
  }
  float mu = sum * (1.f / DH);
  float var = sq * (1.f / DH) - mu * mu;
  float rstd = rsqrtf(var + 1e-5f);
  bf16x4 o;
#pragma unroll
  for (int j = 0; j < 4; ++j)
    o[j] = (bf16_t)((v[j] - mu) * rstd * g[lane * 4 + j] + b[lane * 4 + j]);
  *(bf16x4*)&out[base] = o;
}

// ---------------- GIN gather: one node per wave, pipelined gathers ----------
__global__ __launch_bounds__(256) void gin_gather(
    const int* __restrict__ rowptr, const int* __restrict__ esrc,
    const bf16_t* __restrict__ h, bf16_t* __restrict__ out)
{
  int l = threadIdx.x & 31;
  int half = (threadIdx.x >> 5) & 1;
  int n = blockIdx.x * 4 + (threadIdx.x >> 6);
  if (n >= NN) return;
  size_t co = (size_t)n * DH + l * 8;
  float acc[8];
  {
    bf16x8 hv = *(const bf16x8*)&h[co];
    float w0 = (half == 0) ? 1.f : 0.f;      // self term counted once
#pragma unroll
    for (int j = 0; j < 8; ++j) acc[j] = w0 * (float)hv[j];
  }
  int i0 = rowptr[n], i1 = rowptr[n + 1];
  for (int wb = i0; wb < i1; wb += 32) {
    int wcnt = min(32, i1 - wb);
    int widx = (l < wcnt) ? esrc[wb + l] : 0;

    auto loadg = [&](int e, bf16x8 (&hh)[4]) {
#pragma unroll
      for (int u = 0; u < 4; ++u) {
        int sN = __shfl(widx, e + u * 2 + half, 32);
        hh[u] = *(const bf16x8*)&h[(size_t)sN * DH + l * 8];
      }
    };
    auto computeg = [&](const bf16x8 (&hh)[4]) {
#pragma unroll
      for (int u = 0; u < 4; ++u)
#pragma unroll
        for (int j = 0; j < 8; ++j) acc[j] += (float)hh[u][j];
    };

    int nfull = wcnt >> 3;
    bf16x8 hA[4], hB[4];
    if (nfull > 0) loadg(0, hA);
    int c = 0;
    for (; c + 2 <= nfull; c += 2) {
      loadg((c + 1) * 8, hB);
      computeg(hA);
      if (c + 2 < nfull) loadg((c + 2) * 8, hA);
      computeg(hB);
    }
    if (c < nfull) computeg(hA);

    for (int e = nfull * 8; e < wcnt; e += 2) {
      int eh = e + half;
      bool act = eh < wcnt;
      int s1 = __shfl(widx, act ? eh : e, 32);
      bf16x8 t1 = *(const bf16x8*)&h[(size_t)s1 * DH + l * 8];
      float w = act ? 1.f : 0.f;
#pragma unroll
      for (int j = 0; j < 8; ++j) acc[j] += w * (float)t1[j];
    }
  }
#pragma unroll
  for (int j = 0; j < 8; ++j) acc[j] += __shfl_xor(acc[j], 32, 64);
  if (half == 0) {
    bf16x8 o;
#pragma unroll
    for (int j = 0; j < 8; ++j) o[j] = (bf16_t)acc[j];
    __builtin_nontemporal_store(o, (bf16x8*)&out[co]);
  }
}

// ---------------- BN (partials produced by GEMM epilogue) ----------------
__global__ void bn_final_na(const float* __restrict__ psum, const float* __restrict__ psq,
                            const float* __restrict__ bng, const float* __restrict__ bnb,
                            float* __restrict__ scale, float* __restrict__ shift) {
  int c = threadIdx.x;
  float s = 0.f, ss = 0.f;
  for (int b = 0; b < 4; ++b) { s += psum[b * DH + c]; ss += psq[b * DH + c]; }
  float mu = s * (1.f / NN);
  float var = ss * (1.f / NN) - mu * mu;
  float rstd = rsqrtf(var + 1e-5f);
  float sc = bng[c] * rstd;
  scale[c] = sc;
  shift[c] = bnb[c] - mu * sc;
}
__global__ void bn_apply_relu8(const bf16_t* __restrict__ y, const float* __restrict__ scale,
                               const float* __restrict__ shift, bf16_t* __restrict__ o, int n8) {
  int i = blockIdx.x * 256 + threadIdx.x;
  if (i >= n8) return;
  bf16x8 v = __builtin_nontemporal_load((const bf16x8*)&y[(size_t)i * 8]);
  int c = (i * 8) & (DH - 1);
  bf16x8 r;
#pragma unroll
  for (int j = 0; j < 8; ++j)
    r[j] = (bf16_t)fmaxf((float)v[j] * scale[c + j] + shift[c + j], 0.f);
  *(bf16x8*)&o[(size_t)i * 8] = r;
}

// ---------------- pooling over sorted batch (bf16 input) ----------------
__global__ __launch_bounds__(256) void pool_sorted(
    const int* __restrict__ batch, const bf16_t* __restrict__ h, float* __restrict__ pooled)
{
  __shared__ int s0, s1;
  int g = blockIdx.x;
  if (threadIdx.x == 0) {
    int lo = 0, hi = NN;
    while (lo < hi) { int mid = (lo + hi) >> 1; if (batch[mid] < g) lo = mid + 1; else hi = mid; }
    s0 = lo;
  }
  if (threadIdx.x == 1) {
    int lo = 0, hi = NN;
    while (lo < hi) { int mid = (lo + hi) >> 1; if (batch[mid] < g + 1) lo = mid + 1; else hi = mid; }
    s1 = lo;
  }
  __syncthreads();
  int c = threadIdx.x;
  float acc = 0.f;
  for (int r = s0; r < s1; ++r)
    acc += (float)__builtin_nontemporal_load(&h[(size_t)r * DH + c]);
  pooled[(size_t)g * DH + c] = acc;
}

// ---------------- small fp32 GEMM (head only) ----------------
__global__ __launch_bounds__(256) void gemm_bias_act(
    const float* __restrict__ A, const float* __restrict__ Wm,
    const float* __restrict__ bias, float* __restrict__ C,
    int M, int K, int Ncol, int act)
{
  __shared__ __align__(16) float As[16][68];
  __shared__ __align__(16) float Bs[16][68];
  int tid = threadIdx.x;
  int tx = tid & 15, ty = tid >> 4;
  int row0 = blockIdx.y * 64 + ty * 4;
  int col0 = blockIdx.x * 64 + tx * 4;
  float acc[4][4] = {{0.f}};
  for (int k0 = 0; k0 < K; k0 += 16) {
#pragma unroll
    for (int l = 0; l < 4; ++l) {
      int e = tid + l * 256;
      int r = e >> 4, kk = e & 15;
      int gr = blockIdx.y * 64 + r;
      As[kk][r] = (gr < M) ? A[(size_t)gr * K + k0 + kk] : 0.f;
    }
#pragma unroll
    for (int l = 0; l < 4; ++l) {
      int e = tid + l * 256;
      int kk = e >> 6, c = e & 63;
      int gc = blockIdx.x * 64 + c;
      Bs[kk][c] = (gc < Ncol) ? Wm[(size_t)(k0 + kk) * Ncol + gc] : 0.f;
    }
    __syncthreads();
#pragma unroll
    for (int kk = 0; kk < 16; ++kk) {
      float4 a4 = *(const float4*)&As[kk][ty * 4];
      float4 b4 = *(const float4*)&Bs[kk][tx * 4];
      float a[4] = {a4.x, a4.y, a4.z, a4.w};
      float b[4] = {b4.x, b4.y, b4.z, b4.w};
#pragma unroll
      for (int i = 0; i < 4; ++i)
#pragma unroll
        for (int j = 0; j < 4; ++j)
          acc[i][j] = fmaf(a[i], b[j], acc[i][j]);
    }
    __syncthreads();
  }
#pragma unroll
  for (int i = 0; i < 4; ++i) {
    int r = row0 + i;
    if (r >= M) continue;
#pragma unroll
    for (int j = 0; j < 4; ++j) {
      int c = col0 + j;
      if (c >= Ncol) continue;
      float val = acc[i][j];
      if (bias) val += bias[c];
      if (act == 1) val = fmaxf(val, 0.f);
      C[(size_t)r * Ncol + c] = val;
    }
  }
}

// ---------------- host ----------------
static inline void launch_filli(hipStream_t st, int* p, int v, long n) {
  fill_i32<<<dim3((unsigned)((n + 255) / 256)), dim3(256), 0, st>>>(p, v, (int)n);
}

extern "C" void kernel_launch(void* const* d_in, const int* in_sizes, int n_in,
                              void* d_out, int out_size, void* d_ws, size_t ws_size,
                              hipStream_t stream) {
  const float* x  = (const float*)d_in[0];
  const int* ei   = (const int*)d_in[1];
  const float* ea = (const float*)d_in[2];
  const int* batch = (const int*)d_in[3];
  const int* src = ei;
  const int* dst = ei + NE;

  const float* c1[9]; for (int i = 0; i < 9; ++i) c1[i] = (const float*)d_in[4 + i];
  const float* ln1g = (const float*)d_in[13]; const float* ln1b = (const float*)d_in[14];
  const float* c2[9]; for (int i = 0; i < 9; ++i) c2[i] = (const float*)d_in[15 + i];
  const float* ln2g = (const float*)d_in[24]; const float* ln2b = (const float*)d_in[25];
  const float* g1[6]; for (int i = 0; i < 6; ++i) g1[i] = (const float*)d_in[26 + i];
  const float* g2[6]; for (int i = 0; i < 6; ++i) g2[i] = (const float*)d_in[32 + i];
  const float* linW = (const float*)d_in[38]; const float* linb = (const float*)d_in[39];
  const float* clfW = (const float*)d_in[40]; const float* clfb = (const float*)d_in[41];
  float* out = (float*)d_out;

  // ---- bump allocator over d_ws (256B aligned) ----
  size_t off = 0;
  auto alloc = [&](size_t bytes) -> void* {
    void* r = (char*)d_ws + off;
    off += (bytes + 255) & ~(size_t)255;
    return r;
  };
  int* deg    = (int*)alloc(NN * 4);
  int* cursor = (int*)alloc(NN * 4);   // contiguous after deg (one merged zero-fill)
  int* rowptr = (int*)alloc((NN + 1) * 4);
  int* esrc   = (int*)alloc((size_t)NE * 4);
  int* epos   = (int*)alloc((size_t)NE * 4);
  int* bsum   = (int*)alloc(1024);
  int* boff   = (int*)alloc(1024);
  float* QEf   = (float*)alloc((size_t)NN * DED * 4);
  float* pooled = (float*)alloc((size_t)NG * DH * 4);
  float* zbuf   = (float*)alloc((size_t)NG * DH * 4);
  float* psum  = (float*)alloc(4 * DH * 4);    // per-wave-group BN partials
  float* psq   = (float*)alloc(4 * DH * 4);    // contiguous after psum
  float* bnscale = (float*)alloc(DH * 4);
  float* bnshift = (float*)alloc(DH * 4);
  float* wqe_tmp1 = (float*)alloc((size_t)DIN * DED * 4);
  float* wqe_tmp2 = (float*)alloc((size_t)DH * DED * 4);
  float* bqe1 = (float*)alloc(DED * 4);
  float* bqe2 = (float*)alloc(DED * 4);
  bf16_t* qkvsb = (bf16_t*)alloc((size_t)NN * 1024 * 2);  // q|k|v|s interleaved
  bf16_t* h_b = (bf16_t*)alloc((size_t)NN * DH * 2);
  bf16_t* g_b = (bf16_t*)alloc((size_t)NN * DH * 2);
  bf16_t* Yb  = (bf16_t*)alloc((size_t)NN * DH * 2);      // GIN y1 (pre-BN), bf16
  bf16_t* AGGb = (bf16_t*)alloc((size_t)NN * DH * 2);
  bf16_t* E2Nb = (bf16_t*)alloc((size_t)NN * DH * 2);
  bf16_t* EAn = (bf16_t*)alloc((size_t)NN * DED * 2);
  bf16_t* xb  = (bf16_t*)alloc((size_t)NN * DIN * 2);
  bf16_t* eac = (bf16_t*)alloc((size_t)NE * DED * 2);     // edge_attr, CSR order
  bf16_t* Hb = (bf16_t*)qkvsb;  // final GIN output bf16, aliases qkvs region
  bf16_t* pk1q = (bf16_t*)alloc(DIN * DH * 2);
  bf16_t* pk1k = (bf16_t*)alloc(DIN * DH * 2);
  bf16_t* pk1v = (bf16_t*)alloc(DIN * DH * 2);
  bf16_t* pk1s = (bf16_t*)alloc(DIN * DH * 2);
  bf16_t* pk1qe = (bf16_t*)alloc(DIN * DED * 2);
  bf16_t* pk1we = (bf16_t*)alloc(DED * DH * 2);
  bf16_t* pk2q = (bf16_t*)alloc(DH * DH * 2);
  bf16_t* pk2k = (bf16_t*)alloc(DH * DH * 2);
  bf16_t* pk2v = (bf16_t*)alloc(DH * DH * 2);
  bf16_t* pk2s = (bf16_t*)alloc(DH * DH * 2);
  bf16_t* pk2qe = (bf16_t*)alloc(DH * DED * 2);
  bf16_t* pk2we = (bf16_t*)alloc(DED * DH * 2);
  bf16_t* pkg1a = (bf16_t*)alloc(DH * DH * 2);
  bf16_t* pkg1b = (bf16_t*)alloc(DH * DH * 2);
  bf16_t* pkg2a = (bf16_t*)alloc(DH * DH * 2);
  bf16_t* pkg2b = (bf16_t*)alloc(DH * DH * 2);
  if (ws_size < off) return;

  const int GRID_M  = (NN + 127) / 128;   // RT=2 (qkvs, grid.y=4)
  const int GRID_M1 = (NN + 63) / 64;     // RT=1 (single-output GEMMs)

  cast_bf16x8_k<<<dim3((unsigned)(((long)NN * DIN / 8 + 255) / 256)), dim3(256), 0, stream>>>(
      x, xb, (long)NN * DIN / 8);
  wqe_k<<<dim3((DIN * 32 + 255) / 256), dim3(256), 0, stream>>>(c1[0], c1[6], c1[1], wqe_tmp1, bqe1, DIN);
  wqe_k<<<dim3((DH * 32 + 255) / 256), dim3(256), 0, stream>>>(c2[0], c2[6], c2[1], wqe_tmp2, bqe2, DH);
  PackArgs pa;
  pa.e[0]  = {c1[0], pk1q, DIN, DH};
  pa.e[1]  = {c1[2], pk1k, DIN, DH};
  pa.e[2]  = {c1[4], pk1v, DIN, DH};
  pa.e[3]  = {c1[7], pk1s, DIN, DH};
  pa.e[4]  = {c1[6], pk1we, DED, DH};
  pa.e[5]  = {wqe_tmp1, pk1qe, DIN, DED};
  pa.e[6]  = {c2[0], pk2q, DH, DH};
  pa.e[7]  = {c2[2], pk2k, DH, DH};
  pa.e[8]  = {c2[4], pk2v, DH, DH};
  pa.e[9]  = {c2[7], pk2s, DH, DH};
  pa.e[10] = {c2[6], pk2we, DED, DH};
  pa.e[11] = {wqe_tmp2, pk2qe, DH, DED};
  pa.e[12] = {g1[0], pkg1a, DH, DH};
  pa.e[13] = {g1[4], pkg1b, DH, DH};
  pa.e[14] = {g2[0], pkg2a, DH, DH};
  pa.e[15] = {g2[4], pkg2b, DH, DH};
  pack_all<<<dim3(256, 16), dim3(256), 0, stream>>>(pa);

  const int nb1 = (NN + SCAN_T - 1) / SCAN_T;
  // deg and cursor are contiguous 256B-aligned allocations: one merged zero-fill
  launch_filli(stream, deg, 0, 2 * ((NN * 4 + 255) & ~255) / 4);
  count_k<<<dim3((NE + 255) / 256), dim3(256), 0, stream>>>(dst, deg);
  scan1<<<dim3(nb1), dim3(SCAN_T), 0, stream>>>(deg, rowptr, bsum, NN);
  scan2<<<dim3(1), dim3(SCAN_T), 0, stream>>>(bsum, boff, nb1);
  scan3<<<dim3(nb1), dim3(SCAN_T), 0, stream>>>(rowptr, boff, NN);
  scatter_k<<<dim3((NE + 255) / 256), dim3(256), 0, stream>>>(dst, src, rowptr, cursor, esrc, epos);
  permute_ea<<<dim3((unsigned)(((long)NE * 4 + 255) / 256)), dim3(256), 0, stream>>>(epos, ea, eac);

  auto conv = [&](const bf16_t* Ain, int K,
                  const bf16_t* pq, const bf16_t* pk, const bf16_t* pv, const bf16_t* ps,
                  const bf16_t* pqe, const bf16_t* pwe,
                  const float* const* P, const float* bqe,
                  const float* lng, const float* lnb, bf16_t* outb) {
    QkvsArgs qa;
    qa.w[0] = pq; qa.w[1] = pk; qa.w[2] = pv; qa.w[3] = ps;
    qa.bias[0] = P[1]; qa.bias[1] = P[3]; qa.bias[2] = P[5]; qa.bias[3] = P[8];
    qa.outp[0] = qkvsb + 0; qa.outp[1] = qkvsb + 256;
    qa.outp[2] = qkvsb + 512; qa.outp[3] = qkvsb + 768;
    gemm_qkvs<<<dim3(GRID_M, 4), dim3(256), 0, stream>>>(Ain, qa, NN, K);
    gemm_r1<2><<<dim3(GRID_M1), dim3(256), 0, stream>>>(
        Ain, pqe, bqe, QEf, nullptr, NN, K, 0, 32, nullptr, nullptr);
    conv_edge_fused<<<dim3((NN + 3) / 4), dim3(256), 0, stream>>>(
        rowptr, esrc, qkvsb, eac, QEf, AGGb, EAn);
    gemm_r1<16><<<dim3(GRID_M1), dim3(256), 0, stream>>>(
        EAn, pwe, nullptr, nullptr, E2Nb, NN, DED, 0, 256, nullptr, nullptr);
    conv_epilogue<<<dim3((NN + 3) / 4), dim3(256), 0, stream>>>(
        AGGb, E2Nb, qkvsb, lng, lnb, outb);
  };

  auto gin = [&](const bf16_t* hin, const bf16_t* pw1, const bf16_t* pw2,
                 const float* const* P, int relu_out, bf16_t* outb) {
    gin_gather<<<dim3((NN + 3) / 4), dim3(256), 0, stream>>>(rowptr, esrc, hin, g_b);
    launch_filli(stream, (int*)psum, 0, 2 * 4 * DH);  // zero psum+psq (contiguous)
    gemm_r1<16><<<dim3(GRID_M1), dim3(256), 0, stream>>>(
        g_b, pw1, P[1], nullptr, Yb, NN, DH, 0, 256, psum, psq);
    bn_final_na<<<dim3(1), dim3(256), 0, stream>>>(psum, psq, P[2], P[3], bnscale, bnshift);
    bn_apply_relu8<<<dim3((NN * DH / 8 + 255) / 256), dim3(256), 0, stream>>>(
        Yb, bnscale, bnshift, g_b, NN * DH / 8);
    gemm_r1<16><<<dim3(GRID_M1), dim3(256), 0, stream>>>(
        g_b, pw2, P[5], nullptr, outb, NN, DH, relu_out, 256, nullptr, nullptr);
  };

  conv(xb, DIN, pk1q, pk1k, pk1v, pk1s, pk1qe, pk1we, c1, bqe1, ln1g, ln1b, h_b);
  conv(h_b, DH, pk2q, pk2k, pk2v, pk2s, pk2qe, pk2we, c2, bqe2, ln2g, ln2b, h_b);
  gin(h_b, pkg1a, pkg1b, g1, 1, h_b);
  gin(h_b, pkg2a, pkg2b, g2, 0, Hb);

  pool_sorted<<<dim3(NG), dim3(256), 0, stream>>>(batch, Hb, pooled);
  gemm_bias_act<<<dim3(4, 8), dim3(256), 0, stream>>>(pooled, linW, linb, zbuf, NG, DH, DH, 1);
  gemm_bias_act<<<dim3(1, 8), dim3(256), 0, stream>>>(zbuf, clfW, clfb, out, NG, DH, DOUT, 0);
}

// Round 5
// 1341.853 us; speedup vs baseline: 1.0203x; 1.0203x over previous
//
#include <hip/hip_runtime.h>
#include <math.h>

#define NN 50000
#define NE 800000
#define DIN 128
#define DH 256
#define DED 32
#define NG 500
#define DOUT 16
#define SCAN_T 256

typedef __bf16 bf16_t;
typedef __bf16 bf16x4 __attribute__((ext_vector_type(4)));
typedef __bf16 bf16x8 __attribute__((ext_vector_type(8)));
typedef float f32x4 __attribute__((ext_vector_type(4)));

// async global->LDS, 16B per lane (global_load_lds_dwordx4)
__device__ __forceinline__ void async_copy16(const bf16_t* g, bf16_t* l) {
  __builtin_amdgcn_global_load_lds(
      (const __attribute__((address_space(1))) void*)g,
      (__attribute__((address_space(3))) void*)l, 16, 0, 0);
}

// ---------------- utility ----------------
__global__ void fill_i32(int* __restrict__ p, int v, int n) {
  int i = blockIdx.x * 256 + threadIdx.x;
  if (i < n) p[i] = v;
}
__global__ void cast_bf16x8_k(const float* __restrict__ in, bf16_t* __restrict__ o, long n8) {
  long i = (long)blockIdx.x * 256 + threadIdx.x;
  if (i >= n8) return;
  const f32x4* sp = (const f32x4*)&in[i * 8];
  f32x4 a = __builtin_nontemporal_load(sp);
  f32x4 b = __builtin_nontemporal_load(sp + 1);
  bf16x8 r;
#pragma unroll
  for (int j = 0; j < 4; ++j) { r[j] = (bf16_t)a[j]; r[j + 4] = (bf16_t)b[j]; }
  *(bf16x8*)&o[i * 8] = r;
}

// ---------------- CSR build (by dst) ----------------
__global__ void count_k(const int* __restrict__ dst, int* __restrict__ deg) {
  int e = blockIdx.x * 256 + threadIdx.x;
  if (e < NE) atomicAdd(&deg[dst[e]], 1);
}
__global__ void scan1(const int* __restrict__ deg, int* __restrict__ rowptr,
                      int* __restrict__ bsum, int n) {
  __shared__ int s[SCAN_T];
  int t = threadIdx.x, i = blockIdx.x * SCAN_T + t;
  int v = (i < n) ? deg[i] : 0;
  s[t] = v; __syncthreads();
  for (int off = 1; off < SCAN_T; off <<= 1) {
    int add = (t >= off) ? s[t - off] : 0;
    __syncthreads(); s[t] += add; __syncthreads();
  }
  if (i < n) rowptr[i + 1] = s[t];
  if (t == SCAN_T - 1) bsum[blockIdx.x] = s[t];
}
__global__ void scan2(const int* __restrict__ bsum, int* __restrict__ boff, int nb) {
  __shared__ int s[SCAN_T];
  int t = threadIdx.x;
  int v = (t < nb) ? bsum[t] : 0;
  s[t] = v; __syncthreads();
  for (int off = 1; off < SCAN_T; off <<= 1) {
    int add = (t >= off) ? s[t - off] : 0;
    __syncthreads(); s[t] += add; __syncthreads();
  }
  boff[t] = s[t] - v;
}
__global__ void scan3(int* __restrict__ rowptr, const int* __restrict__ boff, int n) {
  int i = blockIdx.x * 256 + threadIdx.x;
  if (i < n) rowptr[i + 1] += boff[i >> 8];
  if (i == 0) rowptr[0] = 0;
}
// records epos[e] = CSR slot of edge e (inverse permutation) so edge_attr can be
// stream-read / scatter-written instead of gather-read.
__global__ void scatter_k(const int* __restrict__ dst, const int* __restrict__ src,
                          const int* __restrict__ rowptr, int* __restrict__ cursor,
                          int* __restrict__ esrc, int* __restrict__ epos) {
  int e = blockIdx.x * 256 + threadIdx.x;
  if (e < NE) {
    int d = dst[e];
    int pos = rowptr[d] + atomicAdd(&cursor[d], 1);
    esrc[pos] = src[e];
    epos[e] = pos;
  }
}
// cast + permute edge_attr into CSR order: sequential fp32 reads (stream),
// scattered 64B bf16 writes (write path tolerates randomness far better).
__global__ void permute_ea(const int* __restrict__ epos, const float* __restrict__ ea,
                           bf16_t* __restrict__ eac) {
  long t = (long)blockIdx.x * 256 + threadIdx.x;
  if (t >= (long)NE * 4) return;
  int e = (int)(t >> 2), c8 = ((int)t & 3) * 8;
  int pos = epos[e];
  const f32x4* sp = (const f32x4*)&ea[(size_t)e * DED + c8];
  f32x4 a = __builtin_nontemporal_load(sp);
  f32x4 b = __builtin_nontemporal_load(sp + 1);
  bf16x8 o;
#pragma unroll
  for (int j = 0; j < 4; ++j) { o[j] = (bf16_t)a[j]; o[j + 4] = (bf16_t)b[j]; }
  __builtin_nontemporal_store(o, (bf16x8*)&eac[(size_t)pos * DED + c8]);
}

// ---------------- weight fragment packing (all weights, one dispatch) ----------------
struct PackEnt { const float* src; bf16_t* dst; int K; int N; };
struct PackArgs { PackEnt e[16]; };
__global__ void pack_all(PackArgs pa) {
  PackEnt en = pa.e[blockIdx.y];
  int i = blockIdx.x * 256 + threadIdx.x;
  if (i >= en.K * en.N) return;
  int el = i & 511, f = i >> 9;
  int ntiles = en.N >> 4;
  int ks = f / ntiles, t = f - ks * ntiles;
  int lane = el >> 3, j = el & 7;
  int k = ks * 32 + (lane >> 4) * 8 + j;
  int n = t * 16 + (lane & 15);
  en.dst[i] = (bf16_t)en.src[(size_t)k * en.N + n];
}

// Wqe[d][j] = sum_h Wq[d][h]*We[j][h]; bqe[j] = sum_h bq[h]*We[j][h]
__global__ void wqe_k(const float* __restrict__ Wq, const float* __restrict__ We,
                      const float* __restrict__ bq, float* __restrict__ Wqe,
                      float* __restrict__ bqe, int din) {
  int idx = blockIdx.x * 256 + threadIdx.x;
  if (idx < din * 32) {
    int d = idx >> 5, j = idx & 31;
    float s = 0.f;
    for (int h = 0; h < DH; ++h) s += Wq[(size_t)d * DH + h] * We[(size_t)j * DH + h];
    Wqe[idx] = s;
  }
  if (idx < 32) {
    float s = 0.f;
    for (int h = 0; h < DH; ++h) s += bq[h] * We[(size_t)idx * DH + h];
    bqe[idx] = s;
  }
}

// ---------------- MFMA GEMM: 2-phase double-buffered LDS staging ------------
// RT row-tiles per wave: block tile = RT*64 rows x NT*16 cols; BK=32.
// stage(next) issued BEFORE compute(cur); single vmcnt(0)+s_barrier per K-step.
// Optional BN column stats (psum/psq[4][DH]) accumulated from the registers.
// Optional fused A-side BN+ReLU: a := max(a*ascale[c]+ashift[c], 0) per channel
// c = ks*32+aq+j, applied on the LDS->reg fragment (identical rounding chain to
// the old standalone bn_apply kernel). scale/shift staged in LDS (broadcast reads).
template<int NT, int RT>
__device__ __forceinline__ void gemm_body(
    const bf16_t* __restrict__ Ab, const bf16_t* __restrict__ Wp,
    const float* __restrict__ bias, float* __restrict__ Cf, bf16_t* __restrict__ Cb,
    int M, int K, int relu, int rstride, int bx,
    float* __restrict__ psum, float* __restrict__ psq,
    const float* __restrict__ ascale, const float* __restrict__ ashift)
{
  __shared__ bf16_t Atile[2][RT * 2048];   // 2 x RT*4 KB
  __shared__ bf16_t Btile[2][NT * 512];    // 2 x NT KB
  __shared__ float bnS[256];
  __shared__ float bnH[256];
  const int ACH = RT * 256;                // A 16B-chunks per kstep
  const int NCH = ACH + NT * 64;
  int tid = threadIdx.x;
  int lane = tid & 63, wv = tid >> 6;
  int base = bx * (RT * 64);
  f32x4 acc[RT][NT];
#pragma unroll
  for (int rt = 0; rt < RT; ++rt)
#pragma unroll
    for (int t = 0; t < NT; ++t) acc[rt][t] = (f32x4){0.f, 0.f, 0.f, 0.f};
  int arow = wv * (16 * RT) + (lane & 15);
  int aq = (lane >> 4) * 8;
  int nk = K >> 5;

  if (ascale) {
    for (int i = tid; i < K; i += 256) { bnS[i] = ascale[i]; bnH[i] = ashift[i]; }
    __syncthreads();
  }

  auto stage = [&](int buf, int ks) {
    for (int c = tid; c < NCH; c += 256) {
      if (c < ACH) {                       // A: row = c>>2, 16B sub-chunk q = c&3
        int r = c >> 2, qq = c & 3;
        async_copy16(Ab + (size_t)(base + r) * K + ks * 32 + qq * 8,
                     &Atile[buf][c * 8]);
      } else {                             // B: linear 16B chunks of the kstep block
        int cb = c - ACH;
        async_copy16(Wp + (size_t)ks * NT * 512 + cb * 8, &Btile[buf][cb * 8]);
      }
    }
  };

  stage(0, 0);
  asm volatile("s_waitcnt vmcnt(0)" ::: "memory");
  __builtin_amdgcn_s_barrier();
  int cur = 0;
  for (int ks = 0; ks < nk; ++ks) {
    if (ks + 1 < nk) stage(cur ^ 1, ks + 1);   // prefetch overlaps compute below
    bf16x8 a[RT];
#pragma unroll
    for (int rt = 0; rt < RT; ++rt)
      a[rt] = *(const bf16x8*)&Atile[cur][(arow + rt * 16) * 32 + aq];
    if (ascale) {                              // fused BN+ReLU on the A fragment
      int c0 = ks * 32 + aq;
      f32x4 sc0 = *(const f32x4*)&bnS[c0];
      f32x4 sc1 = *(const f32x4*)&bnS[c0 + 4];
      f32x4 sh0 = *(const f32x4*)&bnH[c0];
      f32x4 sh1 = *(const f32x4*)&bnH[c0 + 4];
#pragma unroll
      for (int rt = 0; rt < RT; ++rt) {
        bf16x8 an = a[rt];
#pragma unroll
        for (int j = 0; j < 4; ++j) {
          an[j]     = (bf16_t)fmaxf((float)an[j]     * sc0[j] + sh0[j], 0.f);
          an[j + 4] = (bf16_t)fmaxf((float)an[j + 4] * sc1[j] + sh1[j], 0.f);
        }
        a[rt] = an;
      }
    }
#pragma unroll
    for (int t = 0; t < NT; ++t) {
      bf16x8 b = *(const bf16x8*)&Btile[cur][t * 512 + lane * 8];
#pragma unroll
      for (int rt = 0; rt < RT; ++rt)
        acc[rt][t] = __builtin_amdgcn_mfma_f32_16x16x32_bf16(a[rt], b, acc[rt][t], 0, 0, 0);
    }
    asm volatile("s_waitcnt vmcnt(0)" ::: "memory");  // next tile landed
    __builtin_amdgcn_s_barrier();                     // all waves done reading cur
    cur ^= 1;
  }
  int col_l = lane & 15;
#pragma unroll
  for (int rt = 0; rt < RT; ++rt) {
    int rbase = base + wv * (16 * RT) + rt * 16 + (lane >> 4) * 4;
#pragma unroll
    for (int t = 0; t < NT; ++t) {
      int col = t * 16 + col_l;
      float bv = bias ? bias[col] : 0.f;
#pragma unroll
      for (int r = 0; r < 4; ++r) {
        int row = rbase + r;
        if (row >= M) continue;
        float vv = acc[rt][t][r] + bv;
        if (relu) vv = fmaxf(vv, 0.f);
        if (Cf) Cf[(size_t)row * rstride + col] = vv;
        if (Cb) Cb[(size_t)row * rstride + col] = (bf16_t)vv;
      }
    }
  }
  if (psum) {                           // fused BN column stats (GIN y1 only)
#pragma unroll
    for (int t = 0; t < NT; ++t) {
      float sc = 0.f, sq = 0.f;
      float bv = bias[t * 16 + col_l];
#pragma unroll
      for (int rt = 0; rt < RT; ++rt) {
        int rbase = base + wv * (16 * RT) + rt * 16 + (lane >> 4) * 4;
#pragma unroll
        for (int r = 0; r < 4; ++r) {
          if (rbase + r >= M) continue;
          float vv = acc[rt][t][r] + bv;
          sc += vv; sq += vv * vv;
        }
      }
      sc += __shfl_xor(sc, 16, 64); sc += __shfl_xor(sc, 32, 64);
      sq += __shfl_xor(sq, 16, 64); sq += __shfl_xor(sq, 32, 64);
      if (lane < 16) {
        int col = t * 16 + lane;
        atomicAdd(&psum[wv * DH + col], sc);
        atomicAdd(&psq[wv * DH + col], sq);
      }
    }
  }
}

template<int NT>
__global__ __launch_bounds__(256, 3) void gemm_r1(
    const bf16_t* __restrict__ Ab, const bf16_t* __restrict__ Wp,
    const float* __restrict__ bias, float* __restrict__ Cf, bf16_t* __restrict__ Cb,
    int M, int K, int relu, int rstride, float* psum, float* psq,
    const float* ascale, const float* ashift)
{
  gemm_body<NT, 1>(Ab, Wp, bias, Cf, Cb, M, K, relu, rstride, blockIdx.x, psum, psq,
                   ascale, ashift);
}

// 4 GEMMs sharing A (q,k,v,s) in one dispatch: grid.y selects the weight set.
struct QkvsArgs { const bf16_t* w[4]; const float* bias[4]; bf16_t* outp[4]; };
__global__ __launch_bounds__(256, 3) void gemm_qkvs(
    const bf16_t* __restrict__ Ab, QkvsArgs qa, int M, int K)
{
  int which = blockIdx.y;
  gemm_body<16, 2>(Ab, qa.w[which], qa.bias[which], nullptr, qa.outp[which], M, K, 0, 1024,
                   blockIdx.x, nullptr, nullptr, nullptr, nullptr);
}

// ---------------- fused edge softmax-aggregate: ONE NODE PER WAVE ----------
// Halves of the wave process even/odd edges of the SAME node -> wave-uniform
// trip counts. TLP (8 waves/SIMD at VGPR=64) hides gather latency — do NOT
// register-pipeline this loop (R4 post-mortem: VGPR 112 -> occupancy cliff).
__global__ __launch_bounds__(256) void conv_edge_fused(
    const int* __restrict__ rowptr, const int* __restrict__ esrc,
    const bf16_t* __restrict__ qkvs, const bf16_t* __restrict__ eac,
    const float* __restrict__ QEf,
    bf16_t* __restrict__ AGGn, bf16_t* __restrict__ EAn)
{
  int l = threadIdx.x & 31;
  int half = (threadIdx.x >> 5) & 1;
  int n = blockIdx.x * 4 + (threadIdx.x >> 6);
  if (n >= NN) return;
  float q[8];
  {
    bf16x8 t = __builtin_nontemporal_load((const bf16x8*)&qkvs[(size_t)n * 1024 + l * 8]);
#pragma unroll
    for (int j = 0; j < 8; ++j) q[j] = (float)t[j];
  }
  float qe[8];
#pragma unroll
  for (int j = 0; j < 8; ++j) qe[j] = 0.f;
  if (l < 4) {
    const f32x4* p = (const f32x4*)&QEf[(size_t)n * DED + l * 8];
    f32x4 qa = __builtin_nontemporal_load(p);
    f32x4 qb = __builtin_nontemporal_load(p + 1);
#pragma unroll
    for (int j = 0; j < 4; ++j) { qe[j] = qa[j]; qe[j + 4] = qb[j]; }
  }
  float s = 0.f;
  float acc[8], eacc[8];
#pragma unroll
  for (int j = 0; j < 8; ++j) { acc[j] = 0.f; eacc[j] = 0.f; }
  int i0 = rowptr[n], i1 = rowptr[n + 1];
  for (int wb = i0; wb < i1; wb += 32) {
    int wcnt = min(32, i1 - wb);
    int widx = (l < wcnt) ? esrc[wb + l] : 0;
    int e = 0;
    for (; e + 8 <= wcnt; e += 8) {          // 4 edges per half per step
      int s1 = __shfl(widx, e + half, 32);
      int s2 = __shfl(widx, e + 2 + half, 32);
      int s3 = __shfl(widx, e + 4 + half, 32);
      int s4 = __shfl(widx, e + 6 + half, 32);
      const bf16_t* b1 = &qkvs[(size_t)s1 * 1024 + 256 + l * 8];
      const bf16_t* b2 = &qkvs[(size_t)s2 * 1024 + 256 + l * 8];
      const bf16_t* b3 = &qkvs[(size_t)s3 * 1024 + 256 + l * 8];
      const bf16_t* b4 = &qkvs[(size_t)s4 * 1024 + 256 + l * 8];
      bf16x8 k1 = *(const bf16x8*)b1;
      bf16x8 k2 = *(const bf16x8*)b2;
      bf16x8 k3 = *(const bf16x8*)b3;
      bf16x8 k4 = *(const bf16x8*)b4;
      bf16x8 v1 = *(const bf16x8*)(b1 + 256);
      bf16x8 v2 = *(const bf16x8*)(b2 + 256);
      bf16x8 v3 = *(const bf16x8*)(b3 + 256);
      bf16x8 v4 = *(const bf16x8*)(b4 + 256);
      bf16x8 t1 = {}, t2 = {}, t3 = {}, t4 = {};
      if (l < 4) {
        const bf16_t* ep = &eac[(size_t)(wb + e + half) * DED + l * 8];
        t1 = __builtin_nontemporal_load((const bf16x8*)ep);
        t2 = __builtin_nontemporal_load((const bf16x8*)(ep + 2 * DED));
        t3 = __builtin_nontemporal_load((const bf16x8*)(ep + 4 * DED));
        t4 = __builtin_nontemporal_load((const bf16x8*)(ep + 6 * DED));
      }
      float p1 = 0.f, p2 = 0.f, p3 = 0.f, p4 = 0.f;
#pragma unroll
      for (int j = 0; j < 8; ++j) {
        p1 = fmaf(q[j], (float)k1[j], p1);
        p2 = fmaf(q[j], (float)k2[j], p2);
        p3 = fmaf(q[j], (float)k3[j], p3);
        p4 = fmaf(q[j], (float)k4[j], p4);
      }
#pragma unroll
      for (int j = 0; j < 8; ++j) {
        p1 = fmaf(qe[j], (float)t1[j], p1);
        p2 = fmaf(qe[j], (float)t2[j], p2);
        p3 = fmaf(qe[j], (float)t3[j], p3);
        p4 = fmaf(qe[j], (float)t4[j], p4);
      }
#pragma unroll
      for (int off = 16; off > 0; off >>= 1) {
        p1 += __shfl_xor(p1, off, 32);
        p2 += __shfl_xor(p2, off, 32);
        p3 += __shfl_xor(p3, off, 32);
        p4 += __shfl_xor(p4, off, 32);
      }
      float ex1 = __expf(p1 * 0.0625f);   // scores O(1); exp without max-shift is safe
      float ex2 = __expf(p2 * 0.0625f);
      float ex3 = __expf(p3 * 0.0625f);
      float ex4 = __expf(p4 * 0.0625f);
      s += (ex1 + ex2) + (ex3 + ex4);
#pragma unroll
      for (int j = 0; j < 8; ++j) {
        acc[j] = fmaf(ex1, (float)v1[j], acc[j]);
        acc[j] = fmaf(ex2, (float)v2[j], acc[j]);
        acc[j] = fmaf(ex3, (float)v3[j], acc[j]);
        acc[j] = fmaf(ex4, (float)v4[j], acc[j]);
      }
#pragma unroll
      for (int j = 0; j < 8; ++j) {
        eacc[j] = fmaf(ex1, (float)t1[j], eacc[j]);
        eacc[j] = fmaf(ex2, (float)t2[j], eacc[j]);
        eacc[j] = fmaf(ex3, (float)t3[j], eacc[j]);
        eacc[j] = fmaf(ex4, (float)t4[j], eacc[j]);
      }
    }
    for (; e < wcnt; e += 2) {               // tail: 1 edge per half, masked
      int eh = e + half;
      bool act = eh < wcnt;
      int s1 = __shfl(widx, act ? eh : e, 32);
      const bf16_t* b1 = &qkvs[(size_t)s1 * 1024 + 256 + l * 8];
      bf16x8 k1 = *(const bf16x8*)b1;
      bf16x8 v1 = *(const bf16x8*)(b1 + 256);
      bf16x8 t1 = {};
      if (act && l < 4)
        t1 = __builtin_nontemporal_load((const bf16x8*)&eac[(size_t)(wb + eh) * DED + l * 8]);
      float p1 = 0.f;
#pragma unroll
      for (int j = 0; j < 8; ++j) p1 = fmaf(q[j], (float)k1[j], p1);
#pragma unroll
      for (int j = 0; j < 8; ++j) p1 = fmaf(qe[j], (float)t1[j], p1);
#pragma unroll
      for (int off = 16; off > 0; off >>= 1) p1 += __shfl_xor(p1, off, 32);
      float ex1 = act ? __expf(p1 * 0.0625f) : 0.f;
      s += ex1;
#pragma unroll
      for (int j = 0; j < 8; ++j) acc[j] = fmaf(ex1, (float)v1[j], acc[j]);
#pragma unroll
      for (int j = 0; j < 8; ++j) eacc[j] = fmaf(ex1, (float)t1[j], eacc[j]);
    }
  }
  // combine halves (same node)
  s += __shfl_xor(s, 32, 64);
#pragma unroll
  for (int j = 0; j < 8; ++j) acc[j] += __shfl_xor(acc[j], 32, 64);
#pragma unroll
  for (int j = 0; j < 8; ++j) eacc[j] += __shfl_xor(eacc[j], 32, 64);
  float inv = 1.f / (s + 1e-16f);
  if (half == 0) {
    bf16x8 o;
#pragma unroll
    for (int j = 0; j < 8; ++j) o[j] = (bf16_t)(acc[j] * inv);
    __builtin_nontemporal_store(o, (bf16x8*)&AGGn[(size_t)n * DH + l * 8]);
    if (l < 4) {
      bf16x8 eo;
#pragma unroll
      for (int j = 0; j < 8; ++j) eo[j] = (bf16_t)(eacc[j] * inv);
      __builtin_nontemporal_store(eo, (bf16x8*)&EAn[(size_t)n * DED + l * 8]);
    }
  }
}

// out = LN( leaky_relu( AGGn + E2N + S ) ) * g + b ; S = qkvs[:,768:1024]
__global__ __launch_bounds__(256) void conv_epilogue(
    const bf16_t* __restrict__ AGGn, const bf16_t* __restrict__ E2N,
    const bf16_t* __restrict__ qkvs, const float* __restrict__ g,
    const float* __restrict__ b, bf16_t* __restrict__ out)
{
  int wv = threadIdx.x >> 6, lane = threadIdx.x & 63;
  int n = blockIdx.x * 4 + wv;
  if (n >= NN) return;
  size_t base = (size_t)n * DH + lane * 4;
  bf16x4 a = __builtin_nontemporal_load((const bf16x4*)&AGGn[base]);
  bf16x4 e2 = __builtin_nontemporal_load((const bf16x4*)&E2N[base]);
  bf16x4 sv = __builtin_nontemporal_load(
      (const bf16x4*)&qkvs[(size_t)n * 1024 + 768 + lane * 4]);
  float v[4];
#pragma unroll
  for (int j = 0; j < 4; ++j) {
    float t = (float)a[j] + (float)e2[j] + (float)sv[j];
    v[j] = (t > 0.f) ? t : 0.01f * t;
  }
  float sum = v[0] + v[1] + v[2] + v[3];
  float sq = v[0]*v[0] + v[1]*v[1] + v[2]*v[2] + v[3]*v[3];
#pragma unroll
  for (int off = 32; off > 0; off >>= 1) {
    sum += __shfl_xor(sum, off, 64);
    sq  += __shfl_xor(sq, off, 64);
  }
  float mu = sum * (1.f / DH);
  float var = sq * (1.f / DH) - mu * mu;
  float rstd = rsqrtf(var + 1e-5f);
  bf16x4 o;
#pragma unroll
  for (int j = 0; j < 4; ++j)
    o[j] = (bf16_t)((v[j] - mu) * rstd * g[lane * 4 + j] + b[lane * 4 + j]);
  *(bf16x4*)&out[base] = o;
}

// ---------------- GIN gather: one node per wave ----------------
__global__ __launch_bounds__(256) void gin_gather(
    const int* __restrict__ rowptr, const int* __restrict__ esrc,
    const bf16_t* __restrict__ h, bf16_t* __restrict__ out)
{
  int l = threadIdx.x & 31;
  int half = (threadIdx.x >> 5) & 1;
  int n = blockIdx.x * 4 + (threadIdx.x >> 6);
  if (n >= NN) return;
  size_t co = (size_t)n * DH + l * 8;
  float acc[8];
  {
    bf16x8 hv = *(const bf16x8*)&h[co];
    float w0 = (half == 0) ? 1.f : 0.f;      // self term counted once
#pragma unroll
    for (int j = 0; j < 8; ++j) acc[j] = w0 * (float)hv[j];
  }
  int i0 = rowptr[n], i1 = rowptr[n + 1];
  for (int wb = i0; wb < i1; wb += 32) {
    int wcnt = min(32, i1 - wb);
    int widx = (l < wcnt) ? esrc[wb + l] : 0;
    int e = 0;
    for (; e + 8 <= wcnt; e += 8) {
      int s1 = __shfl(widx, e + half, 32);
      int s2 = __shfl(widx, e + 2 + half, 32);
      int s3 = __shfl(widx, e + 4 + half, 32);
      int s4 = __shfl(widx, e + 6 + half, 32);
      bf16x8 t1 = *(const bf16x8*)&h[(size_t)s1 * DH + l * 8];
      bf16x8 t2 = *(const bf16x8*)&h[(size_t)s2 * DH + l * 8];
      bf16x8 t3 = *(const bf16x8*)&h[(size_t)s3 * DH + l * 8];
      bf16x8 t4 = *(const bf16x8*)&h[(size_t)s4 * DH + l * 8];
#pragma unroll
      for (int j = 0; j < 8; ++j)
        acc[j] += ((float)t1[j] + (float)t2[j]) + ((float)t3[j] + (float)t4[j]);
    }
    for (; e < wcnt; e += 2) {
      int eh = e + half;
      bool act = eh < wcnt;
      int s1 = __shfl(widx, act ? eh : e, 32);
      bf16x8 t1 = *(const bf16x8*)&h[(size_t)s1 * DH + l * 8];
      float w = act ? 1.f : 0.f;
#pragma unroll
      for (int j = 0; j < 8; ++j) acc[j] += w * (float)t1[j];
    }
  }
#pragma unroll
  for (int j = 0; j < 8; ++j) acc[j] += __shfl_xor(acc[j], 32, 64);
  if (half == 0) {
    bf16x8 o;
#pragma unroll
    for (int j = 0; j < 8; ++j) o[j] = (bf16_t)acc[j];
    __builtin_nontemporal_store(o, (bf16x8*)&out[co]);
  }
}

// ---------------- BN (partials produced by GEMM epilogue) ----------------
__global__ void bn_final_na(const float* __restrict__ psum, const float* __restrict__ psq,
                            const float* __restrict__ bng, const float* __restrict__ bnb,
                            float* __restrict__ scale, float* __restrict__ shift) {
  int c = threadIdx.x;
  float s = 0.f, ss = 0.f;
  for (int b = 0; b < 4; ++b) { s += psum[b * DH + c]; ss += psq[b * DH + c]; }
  float mu = s * (1.f / NN);
  float var = ss * (1.f / NN) - mu * mu;
  float rstd = rsqrtf(var + 1e-5f);
  float sc = bng[c] * rstd;
  scale[c] = sc;
  shift[c] = bnb[c] - mu * sc;
}

// ---------------- pooling over sorted batch (bf16 input) ----------------
__global__ __launch_bounds__(256) void pool_sorted(
    const int* __restrict__ batch, const bf16_t* __restrict__ h, float* __restrict__ pooled)
{
  __shared__ int s0, s1;
  int g = blockIdx.x;
  if (threadIdx.x == 0) {
    int lo = 0, hi = NN;
    while (lo < hi) { int mid = (lo + hi) >> 1; if (batch[mid] < g) lo = mid + 1; else hi = mid; }
    s0 = lo;
  }
  if (threadIdx.x == 1) {
    int lo = 0, hi = NN;
    while (lo < hi) { int mid = (lo + hi) >> 1; if (batch[mid] < g + 1) lo = mid + 1; else hi = mid; }
    s1 = lo;
  }
  __syncthreads();
  int c = threadIdx.x;
  float acc = 0.f;
  for (int r = s0; r < s1; ++r)
    acc += (float)__builtin_nontemporal_load(&h[(size_t)r * DH + c]);
  pooled[(size_t)g * DH + c] = acc;
}

// ---------------- small fp32 GEMM (head only) ----------------
__global__ __launch_bounds__(256) void gemm_bias_act(
    const float* __restrict__ A, const float* __restrict__ Wm,
    const float* __restrict__ bias, float* __restrict__ C,
    int M, int K, int Ncol, int act)
{
  __shared__ __align__(16) float As[16][68];
  __shared__ __align__(16) float Bs[16][68];
  int tid = threadIdx.x;
  int tx = tid & 15, ty = tid >> 4;
  int row0 = blockIdx.y * 64 + ty * 4;
  int col0 = blockIdx.x * 64 + tx * 4;
  float acc[4][4] = {{0.f}};
  for (int k0 = 0; k0 < K; k0 += 16) {
#pragma unroll
    for (int l = 0; l < 4; ++l) {
      int e = tid + l * 256;
      int r = e >> 4, kk = e & 15;
      int gr = blockIdx.y * 64 + r;
      As[kk][r] = (gr < M) ? A[(size_t)gr * K + k0 + kk] : 0.f;
    }
#pragma unroll
    for (int l = 0; l < 4; ++l) {
      int e = tid + l * 256;
      int kk = e >> 6, c = e & 63;
      int gc = blockIdx.x * 64 + c;
      Bs[kk][c] = (gc < Ncol) ? Wm[(size_t)(k0 + kk) * Ncol + gc] : 0.f;
    }
    __syncthreads();
#pragma unroll
    for (int kk = 0; kk < 16; ++kk) {
      float4 a4 = *(const float4*)&As[kk][ty * 4];
      float4 b4 = *(const float4*)&Bs[kk][tx * 4];
      float a[4] = {a4.x, a4.y, a4.z, a4.w};
      float b[4] = {b4.x, b4.y, b4.z, b4.w};
#pragma unroll
      for (int i = 0; i < 4; ++i)
#pragma unroll
        for (int j = 0; j < 4; ++j)
          acc[i][j] = fmaf(a[i], b[j], acc[i][j]);
    }
    __syncthreads();
  }
#pragma unroll
  for (int i = 0; i < 4; ++i) {
    int r = row0 + i;
    if (r >= M) continue;
#pragma unroll
    for (int j = 0; j < 4; ++j) {
      int c = col0 + j;
      if (c >= Ncol) continue;
      float val = acc[i][j];
      if (bias) val += bias[c];
      if (act == 1) val = fmaxf(val, 0.f);
      C[(size_t)r * Ncol + c] = val;
    }
  }
}

// ---------------- host ----------------
static inline void launch_filli(hipStream_t st, int* p, int v, long n) {
  fill_i32<<<dim3((unsigned)((n + 255) / 256)), dim3(256), 0, st>>>(p, v, (int)n);
}

extern "C" void kernel_launch(void* const* d_in, const int* in_sizes, int n_in,
                              void* d_out, int out_size, void* d_ws, size_t ws_size,
                              hipStream_t stream) {
  const float* x  = (const float*)d_in[0];
  const int* ei   = (const int*)d_in[1];
  const float* ea = (const float*)d_in[2];
  const int* batch = (const int*)d_in[3];
  const int* src = ei;
  const int* dst = ei + NE;

  const float* c1[9]; for (int i = 0; i < 9; ++i) c1[i] = (const float*)d_in[4 + i];
  const float* ln1g = (const float*)d_in[13]; const float* ln1b = (const float*)d_in[14];
  const float* c2[9]; for (int i = 0; i < 9; ++i) c2[i] = (const float*)d_in[15 + i];
  const float* ln2g = (const float*)d_in[24]; const float* ln2b = (const float*)d_in[25];
  const float* g1[6]; for (int i = 0; i < 6; ++i) g1[i] = (const float*)d_in[26 + i];
  const float* g2[6]; for (int i = 0; i < 6; ++i) g2[i] = (const float*)d_in[32 + i];
  const float* linW = (const float*)d_in[38]; const float* linb = (const float*)d_in[39];
  const float* clfW = (const float*)d_in[40]; const float* clfb = (const float*)d_in[41];
  float* out = (float*)d_out;

  // ---- bump allocator over d_ws (256B aligned) ----
  size_t off = 0;
  auto alloc = [&](size_t bytes) -> void* {
    void* r = (char*)d_ws + off;
    off += (bytes + 255) & ~(size_t)255;
    return r;
  };
  int* deg    = (int*)alloc(NN * 4);
  int* cursor = (int*)alloc(NN * 4);   // contiguous after deg (one merged zero-fill)
  int* rowptr = (int*)alloc((NN + 1) * 4);
  int* esrc   = (int*)alloc((size_t)NE * 4);
  int* epos   = (int*)alloc((size_t)NE * 4);
  int* bsum   = (int*)alloc(1024);
  int* boff   = (int*)alloc(1024);
  float* QEf   = (float*)alloc((size_t)NN * DED * 4);
  float* pooled = (float*)alloc((size_t)NG * DH * 4);
  float* zbuf   = (float*)alloc((size_t)NG * DH * 4);
  float* psum  = (float*)alloc(4 * DH * 4);    // per-wave-group BN partials
  float* psq   = (float*)alloc(4 * DH * 4);    // contiguous after psum
  float* bnscale = (float*)alloc(DH * 4);
  float* bnshift = (float*)alloc(DH * 4);
  float* wqe_tmp1 = (float*)alloc((size_t)DIN * DED * 4);
  float* wqe_tmp2 = (float*)alloc((size_t)DH * DED * 4);
  float* bqe1 = (float*)alloc(DED * 4);
  float* bqe2 = (float*)alloc(DED * 4);
  bf16_t* qkvsb = (bf16_t*)alloc((size_t)NN * 1024 * 2);  // q|k|v|s interleaved
  bf16_t* h_b = (bf16_t*)alloc((size_t)NN * DH * 2);
  bf16_t* g_b = (bf16_t*)alloc((size_t)NN * DH * 2);
  bf16_t* Yb  = (bf16_t*)alloc((size_t)NN * DH * 2);      // GIN y1 (pre-BN), bf16
  bf16_t* AGGb = (bf16_t*)alloc((size_t)NN * DH * 2);
  bf16_t* E2Nb = (bf16_t*)alloc((size_t)NN * DH * 2);
  bf16_t* EAn = (bf16_t*)alloc((size_t)NN * DED * 2);
  bf16_t* xb  = (bf16_t*)alloc((size_t)NN * DIN * 2);
  bf16_t* eac = (bf16_t*)alloc((size_t)NE * DED * 2);     // edge_attr, CSR order
  bf16_t* Hb = (bf16_t*)qkvsb;  // final GIN output bf16, aliases qkvs region
  bf16_t* pk1q = (bf16_t*)alloc(DIN * DH * 2);
  bf16_t* pk1k = (bf16_t*)alloc(DIN * DH * 2);
  bf16_t* pk1v = (bf16_t*)alloc(DIN * DH * 2);
  bf16_t* pk1s = (bf16_t*)alloc(DIN * DH * 2);
  bf16_t* pk1qe = (bf16_t*)alloc(DIN * DED * 2);
  bf16_t* pk1we = (bf16_t*)alloc(DED * DH * 2);
  bf16_t* pk2q = (bf16_t*)alloc(DH * DH * 2);
  bf16_t* pk2k = (bf16_t*)alloc(DH * DH * 2);
  bf16_t* pk2v = (bf16_t*)alloc(DH * DH * 2);
  bf16_t* pk2s = (bf16_t*)alloc(DH * DH * 2);
  bf16_t* pk2qe = (bf16_t*)alloc(DH * DED * 2);
  bf16_t* pk2we = (bf16_t*)alloc(DED * DH * 2);
  bf16_t* pkg1a = (bf16_t*)alloc(DH * DH * 2);
  bf16_t* pkg1b = (bf16_t*)alloc(DH * DH * 2);
  bf16_t* pkg2a = (bf16_t*)alloc(DH * DH * 2);
  bf16_t* pkg2b = (bf16_t*)alloc(DH * DH * 2);
  if (ws_size < off) return;

  const int GRID_M  = (NN + 127) / 128;   // RT=2 (qkvs, grid.y=4)
  const int GRID_M1 = (NN + 63) / 64;     // RT=1 (single-output GEMMs)

  cast_bf16x8_k<<<dim3((unsigned)(((long)NN * DIN / 8 + 255) / 256)), dim3(256), 0, stream>>>(
      x, xb, (long)NN * DIN / 8);
  wqe_k<<<dim3((DIN * 32 + 255) / 256), dim3(256), 0, stream>>>(c1[0], c1[6], c1[1], wqe_tmp1, bqe1, DIN);
  wqe_k<<<dim3((DH * 32 + 255) / 256), dim3(256), 0, stream>>>(c2[0], c2[6], c2[1], wqe_tmp2, bqe2, DH);
  PackArgs pa;
  pa.e[0]  = {c1[0], pk1q, DIN, DH};
  pa.e[1]  = {c1[2], pk1k, DIN, DH};
  pa.e[2]  = {c1[4], pk1v, DIN, DH};
  pa.e[3]  = {c1[7], pk1s, DIN, DH};
  pa.e[4]  = {c1[6], pk1we, DED, DH};
  pa.e[5]  = {wqe_tmp1, pk1qe, DIN, DED};
  pa.e[6]  = {c2[0], pk2q, DH, DH};
  pa.e[7]  = {c2[2], pk2k, DH, DH};
  pa.e[8]  = {c2[4], pk2v, DH, DH};
  pa.e[9]  = {c2[7], pk2s, DH, DH};
  pa.e[10] = {c2[6], pk2we, DED, DH};
  pa.e[11] = {wqe_tmp2, pk2qe, DH, DED};
  pa.e[12] = {g1[0], pkg1a, DH, DH};
  pa.e[13] = {g1[4], pkg1b, DH, DH};
  pa.e[14] = {g2[0], pkg2a, DH, DH};
  pa.e[15] = {g2[4], pkg2b, DH, DH};
  pack_all<<<dim3(256, 16), dim3(256), 0, stream>>>(pa);

  const int nb1 = (NN + SCAN_T - 1) / SCAN_T;
  // deg and cursor are contiguous 256B-aligned allocations: one merged zero-fill
  launch_filli(stream, deg, 0, 2 * ((NN * 4 + 255) & ~255) / 4);
  count_k<<<dim3((NE + 255) / 256), dim3(256), 0, stream>>>(dst, deg);
  scan1<<<dim3(nb1), dim3(SCAN_T), 0, stream>>>(deg, rowptr, bsum, NN);
  scan2<<<dim3(1), dim3(SCAN_T), 0, stream>>>(bsum, boff, nb1);
  scan3<<<dim3(nb1), dim3(SCAN_T), 0, stream>>>(rowptr, boff, NN);
  scatter_k<<<dim3((NE + 255) / 256), dim3(256), 0, stream>>>(dst, src, rowptr, cursor, esrc, epos);
  permute_ea<<<dim3((unsigned)(((long)NE * 4 + 255) / 256)), dim3(256), 0, stream>>>(epos, ea, eac);

  auto conv = [&](const bf16_t* Ain, int K,
                  const bf16_t* pq, const bf16_t* pk, const bf16_t* pv, const bf16_t* ps,
                  const bf16_t* pqe, const bf16_t* pwe,
                  const float* const* P, const float* bqe,
                  const float* lng, const float* lnb, bf16_t* outb) {
    QkvsArgs qa;
    qa.w[0] = pq; qa.w[1] = pk; qa.w[2] = pv; qa.w[3] = ps;
    qa.bias[0] = P[1]; qa.bias[1] = P[3]; qa.bias[2] = P[5]; qa.bias[3] = P[8];
    qa.outp[0] = qkvsb + 0; qa.outp[1] = qkvsb + 256;
    qa.outp[2] = qkvsb + 512; qa.outp[3] = qkvsb + 768;
    gemm_qkvs<<<dim3(GRID_M, 4), dim3(256), 0, stream>>>(Ain, qa, NN, K);
    gemm_r1<2><<<dim3(GRID_M1), dim3(256), 0, stream>>>(
        Ain, pqe, bqe, QEf, nullptr, NN, K, 0, 32, nullptr, nullptr, nullptr, nullptr);
    conv_edge_fused<<<dim3((NN + 3) / 4), dim3(256), 0, stream>>>(
        rowptr, esrc, qkvsb, eac, QEf, AGGb, EAn);
    gemm_r1<16><<<dim3(GRID_M1), dim3(256), 0, stream>>>(
        EAn, pwe, nullptr, nullptr, E2Nb, NN, DED, 0, 256, nullptr, nullptr, nullptr, nullptr);
    conv_epilogue<<<dim3((NN + 3) / 4), dim3(256), 0, stream>>>(
        AGGb, E2Nb, qkvsb, lng, lnb, outb);
  };

  auto gin = [&](const bf16_t* hin, const bf16_t* pw1, const bf16_t* pw2,
                 const float* const* P, int relu_out, bf16_t* outb) {
    gin_gather<<<dim3((NN + 3) / 4), dim3(256), 0, stream>>>(rowptr, esrc, hin, g_b);
    launch_filli(stream, (int*)psum, 0, 2 * 4 * DH);  // zero psum+psq (contiguous)
    gemm_r1<16><<<dim3(GRID_M1), dim3(256), 0, stream>>>(
        g_b, pw1, P[1], nullptr, Yb, NN, DH, 0, 256, psum, psq, nullptr, nullptr);
    bn_final_na<<<dim3(1), dim3(256), 0, stream>>>(psum, psq, P[2], P[3], bnscale, bnshift);
    // second GEMM applies BN+ReLU to A on the fly (no bn_apply pass, no g_b round trip)
    gemm_r1<16><<<dim3(GRID_M1), dim3(256), 0, stream>>>(
        Yb, pw2, P[5], nullptr, outb, NN, DH, relu_out, 256, nullptr, nullptr,
        bnscale, bnshift);
  };

  conv(xb, DIN, pk1q, pk1k, pk1v, pk1s, pk1qe, pk1we, c1, bqe1, ln1g, ln1b, h_b);
  conv(h_b, DH, pk2q, pk2k, pk2v, pk2s, pk2qe, pk2we, c2, bqe2, ln2g, ln2b, h_b);
  gin(h_b, pkg1a, pkg1b, g1, 1, h_b);
  gin(h_b, pkg2a, pkg2b, g2, 0, Hb);

  pool_sorted<<<dim3(NG), dim3(256), 0, stream>>>(batch, Hb, pooled);
  gemm_bias_act<<<dim3(4, 8), dim3(256), 0, stream>>>(pooled, linW, linb, zbuf, NG, DH, DH, 1);
  gemm_bias_act<<<dim3(1, 8), dim3(256), 0, stream>>>(zbuf, clfW, clfb, out, NG, DH, DOUT, 0);
}

// Round 6
// 1295.452 us; speedup vs baseline: 1.0569x; 1.0358x over previous
//
#include <hip/hip_runtime.h>
#include <math.h>

#define NN 50000
#define NE 800000
#define DIN 128
#define DH 256
#define DED 32
#define NG 500
#define DOUT 16
#define SCAN_T 256

typedef __bf16 bf16_t;
typedef __bf16 bf16x4 __attribute__((ext_vector_type(4)));
typedef __bf16 bf16x8 __attribute__((ext_vector_type(8)));
typedef float f32x4 __attribute__((ext_vector_type(4)));

// async global->LDS, 16B per lane (global_load_lds_dwordx4)
__device__ __forceinline__ void async_copy16(const bf16_t* g, bf16_t* l) {
  __builtin_amdgcn_global_load_lds(
      (const __attribute__((address_space(1))) void*)g,
      (__attribute__((address_space(3))) void*)l, 16, 0, 0);
}

// ---------------- utility ----------------
__global__ void fill_i32(int* __restrict__ p, int v, int n) {
  int i = blockIdx.x * 256 + threadIdx.x;
  if (i < n) p[i] = v;
}
__global__ void cast_bf16x8_k(const float* __restrict__ in, bf16_t* __restrict__ o, long n8) {
  long i = (long)blockIdx.x * 256 + threadIdx.x;
  if (i >= n8) return;
  const f32x4* sp = (const f32x4*)&in[i * 8];
  f32x4 a = __builtin_nontemporal_load(sp);
  f32x4 b = __builtin_nontemporal_load(sp + 1);
  bf16x8 r;
#pragma unroll
  for (int j = 0; j < 4; ++j) { r[j] = (bf16_t)a[j]; r[j + 4] = (bf16_t)b[j]; }
  *(bf16x8*)&o[i * 8] = r;
}

// ---------------- CSR build (by dst) ----------------
__global__ void count_k(const int* __restrict__ dst, int* __restrict__ deg) {
  int e = blockIdx.x * 256 + threadIdx.x;
  if (e < NE) atomicAdd(&deg[dst[e]], 1);
}
__global__ void scan1(const int* __restrict__ deg, int* __restrict__ rowptr,
                      int* __restrict__ bsum, int n) {
  __shared__ int s[SCAN_T];
  int t = threadIdx.x, i = blockIdx.x * SCAN_T + t;
  int v = (i < n) ? deg[i] : 0;
  s[t] = v; __syncthreads();
  for (int off = 1; off < SCAN_T; off <<= 1) {
    int add = (t >= off) ? s[t - off] : 0;
    __syncthreads(); s[t] += add; __syncthreads();
  }
  if (i < n) rowptr[i + 1] = s[t];
  if (t == SCAN_T - 1) bsum[blockIdx.x] = s[t];
}
__global__ void scan2(const int* __restrict__ bsum, int* __restrict__ boff, int nb) {
  __shared__ int s[SCAN_T];
  int t = threadIdx.x;
  int v = (t < nb) ? bsum[t] : 0;
  s[t] = v; __syncthreads();
  for (int off = 1; off < SCAN_T; off <<= 1) {
    int add = (t >= off) ? s[t - off] : 0;
    __syncthreads(); s[t] += add; __syncthreads();
  }
  boff[t] = s[t] - v;
}
__global__ void scan3(int* __restrict__ rowptr, const int* __restrict__ boff, int n) {
  int i = blockIdx.x * 256 + threadIdx.x;
  if (i < n) rowptr[i + 1] += boff[i >> 8];
  if (i == 0) rowptr[0] = 0;
}
// records epos[e] = CSR slot of edge e (inverse permutation) so edge_attr can be
// stream-read / scatter-written instead of gather-read.
__global__ void scatter_k(const int* __restrict__ dst, const int* __restrict__ src,
                          const int* __restrict__ rowptr, int* __restrict__ cursor,
                          int* __restrict__ esrc, int* __restrict__ epos) {
  int e = blockIdx.x * 256 + threadIdx.x;
  if (e < NE) {
    int d = dst[e];
    int pos = rowptr[d] + atomicAdd(&cursor[d], 1);
    esrc[pos] = src[e];
    epos[e] = pos;
  }
}
// cast + permute edge_attr into CSR order: sequential fp32 reads (stream),
// scattered 64B bf16 writes (write path tolerates randomness far better).
__global__ void permute_ea(const int* __restrict__ epos, const float* __restrict__ ea,
                           bf16_t* __restrict__ eac) {
  long t = (long)blockIdx.x * 256 + threadIdx.x;
  if (t >= (long)NE * 4) return;
  int e = (int)(t >> 2), c8 = ((int)t & 3) * 8;
  int pos = epos[e];
  const f32x4* sp = (const f32x4*)&ea[(size_t)e * DED + c8];
  f32x4 a = __builtin_nontemporal_load(sp);
  f32x4 b = __builtin_nontemporal_load(sp + 1);
  bf16x8 o;
#pragma unroll
  for (int j = 0; j < 4; ++j) { o[j] = (bf16_t)a[j]; o[j + 4] = (bf16_t)b[j]; }
  __builtin_nontemporal_store(o, (bf16x8*)&eac[(size_t)pos * DED + c8]);
}

// ---------------- weight fragment packing (all weights, one dispatch) ----------------
struct PackEnt { const float* src; bf16_t* dst; int K; int N; };
struct PackArgs { PackEnt e[16]; };
__global__ void pack_all(PackArgs pa) {
  PackEnt en = pa.e[blockIdx.y];
  int i = blockIdx.x * 256 + threadIdx.x;
  if (i >= en.K * en.N) return;
  int el = i & 511, f = i >> 9;
  int ntiles = en.N >> 4;
  int ks = f / ntiles, t = f - ks * ntiles;
  int lane = el >> 3, j = el & 7;
  int k = ks * 32 + (lane >> 4) * 8 + j;
  int n = t * 16 + (lane & 15);
  en.dst[i] = (bf16_t)en.src[(size_t)k * en.N + n];
}

// Wqe[d][j] = sum_h Wq[d][h]*We[j][h]; bqe[j] = sum_h bq[h]*We[j][h]
__global__ void wqe_k(const float* __restrict__ Wq, const float* __restrict__ We,
                      const float* __restrict__ bq, float* __restrict__ Wqe,
                      float* __restrict__ bqe, int din) {
  int idx = blockIdx.x * 256 + threadIdx.x;
  if (idx < din * 32) {
    int d = idx >> 5, j = idx & 31;
    float s = 0.f;
    for (int h = 0; h < DH; ++h) s += Wq[(size_t)d * DH + h] * We[(size_t)j * DH + h];
    Wqe[idx] = s;
  }
  if (idx < 32) {
    float s = 0.f;
    for (int h = 0; h < DH; ++h) s += bq[h] * We[(size_t)idx * DH + h];
    bqe[idx] = s;
  }
}

// ---------------- MFMA GEMM: 2-phase double-buffered LDS staging ------------
// RT row-tiles per wave: block tile = RT*64 rows x NT*16 cols; BK=32.
// stage(next) issued BEFORE compute(cur); single vmcnt(0)+s_barrier per K-step.
// FBN is a COMPILE-TIME flag (R5 post-mortem: a runtime flag added +2KB LDS and
// BN codegen to every instantiation, dropping gemm_r1<16> from 4 to 3 blocks/CU).
// FBN=true adds fused A-side BN+ReLU: a := max(a*ascale[c]+ashift[c],0),
// c = ks*32+aq+j, applied on the LDS->reg fragment (identical rounding chain to
// the old standalone bn_apply kernel).
template<int NT, int RT, bool FBN>
__device__ __forceinline__ void gemm_body(
    const bf16_t* __restrict__ Ab, const bf16_t* __restrict__ Wp,
    const float* __restrict__ bias, float* __restrict__ Cf, bf16_t* __restrict__ Cb,
    int M, int K, int relu, int rstride, int bx,
    float* __restrict__ psum, float* __restrict__ psq,
    const float* __restrict__ ascale, const float* __restrict__ ashift)
{
  __shared__ bf16_t Atile[2][RT * 2048];   // 2 x RT*4 KB
  __shared__ bf16_t Btile[2][NT * 512];    // 2 x NT KB
  __shared__ float bnS[FBN ? 256 : 1];
  __shared__ float bnH[FBN ? 256 : 1];
  const int ACH = RT * 256;                // A 16B-chunks per kstep
  const int NCH = ACH + NT * 64;
  int tid = threadIdx.x;
  int lane = tid & 63, wv = tid >> 6;
  int base = bx * (RT * 64);
  f32x4 acc[RT][NT];
#pragma unroll
  for (int rt = 0; rt < RT; ++rt)
#pragma unroll
    for (int t = 0; t < NT; ++t) acc[rt][t] = (f32x4){0.f, 0.f, 0.f, 0.f};
  int arow = wv * (16 * RT) + (lane & 15);
  int aq = (lane >> 4) * 8;
  int nk = K >> 5;

  if constexpr (FBN) {
    for (int i = tid; i < K; i += 256) { bnS[i] = ascale[i]; bnH[i] = ashift[i]; }
    __syncthreads();
  }

  auto stage = [&](int buf, int ks) {
    for (int c = tid; c < NCH; c += 256) {
      if (c < ACH) {                       // A: row = c>>2, 16B sub-chunk q = c&3
        int r = c >> 2, qq = c & 3;
        async_copy16(Ab + (size_t)(base + r) * K + ks * 32 + qq * 8,
                     &Atile[buf][c * 8]);
      } else {                             // B: linear 16B chunks of the kstep block
        int cb = c - ACH;
        async_copy16(Wp + (size_t)ks * NT * 512 + cb * 8, &Btile[buf][cb * 8]);
      }
    }
  };

  stage(0, 0);
  asm volatile("s_waitcnt vmcnt(0)" ::: "memory");
  __builtin_amdgcn_s_barrier();
  int cur = 0;
  for (int ks = 0; ks < nk; ++ks) {
    if (ks + 1 < nk) stage(cur ^ 1, ks + 1);   // prefetch overlaps compute below
    bf16x8 a[RT];
#pragma unroll
    for (int rt = 0; rt < RT; ++rt)
      a[rt] = *(const bf16x8*)&Atile[cur][(arow + rt * 16) * 32 + aq];
    if constexpr (FBN) {                       // fused BN+ReLU on the A fragment
      int c0 = ks * 32 + aq;
      f32x4 sc0 = *(const f32x4*)&bnS[c0];
      f32x4 sc1 = *(const f32x4*)&bnS[c0 + 4];
      f32x4 sh0 = *(const f32x4*)&bnH[c0];
      f32x4 sh1 = *(const f32x4*)&bnH[c0 + 4];
#pragma unroll
      for (int rt = 0; rt < RT; ++rt) {
        bf16x8 an = a[rt];
#pragma unroll
        for (int j = 0; j < 4; ++j) {
          an[j]     = (bf16_t)fmaxf((float)an[j]     * sc0[j] + sh0[j], 0.f);
          an[j + 4] = (bf16_t)fmaxf((float)an[j + 4] * sc1[j] + sh1[j], 0.f);
        }
        a[rt] = an;
      }
    }
#pragma unroll
    for (int t = 0; t < NT; ++t) {
      bf16x8 b = *(const bf16x8*)&Btile[cur][t * 512 + lane * 8];
#pragma unroll
      for (int rt = 0; rt < RT; ++rt)
        acc[rt][t] = __builtin_amdgcn_mfma_f32_16x16x32_bf16(a[rt], b, acc[rt][t], 0, 0, 0);
    }
    asm volatile("s_waitcnt vmcnt(0)" ::: "memory");  // next tile landed
    __builtin_amdgcn_s_barrier();                     // all waves done reading cur
    cur ^= 1;
  }
  int col_l = lane & 15;
#pragma unroll
  for (int rt = 0; rt < RT; ++rt) {
    int rbase = base + wv * (16 * RT) + rt * 16 + (lane >> 4) * 4;
#pragma unroll
    for (int t = 0; t < NT; ++t) {
      int col = t * 16 + col_l;
      float bv = bias ? bias[col] : 0.f;
#pragma unroll
      for (int r = 0; r < 4; ++r) {
        int row = rbase + r;
        if (row >= M) continue;
        float vv = acc[rt][t][r] + bv;
        if (relu) vv = fmaxf(vv, 0.f);
        if (Cf) Cf[(size_t)row * rstride + col] = vv;
        if (Cb) Cb[(size_t)row * rstride + col] = (bf16_t)vv;
      }
    }
  }
  if (psum) {                           // fused BN column stats (GIN y1 only)
#pragma unroll
    for (int t = 0; t < NT; ++t) {
      float sc = 0.f, sq = 0.f;
      float bv = bias[t * 16 + col_l];
#pragma unroll
      for (int rt = 0; rt < RT; ++rt) {
        int rbase = base + wv * (16 * RT) + rt * 16 + (lane >> 4) * 4;
#pragma unroll
        for (int r = 0; r < 4; ++r) {
          if (rbase + r >= M) continue;
          float vv = acc[rt][t][r] + bv;
          sc += vv; sq += vv * vv;
        }
      }
      sc += __shfl_xor(sc, 16, 64); sc += __shfl_xor(sc, 32, 64);
      sq += __shfl_xor(sq, 16, 64); sq += __shfl_xor(sq, 32, 64);
      if (lane < 16) {
        int col = t * 16 + lane;
        atomicAdd(&psum[wv * DH + col], sc);
        atomicAdd(&psq[wv * DH + col], sq);
      }
    }
  }
}

template<int NT>
__global__ __launch_bounds__(256, 3) void gemm_r1(
    const bf16_t* __restrict__ Ab, const bf16_t* __restrict__ Wp,
    const float* __restrict__ bias, float* __restrict__ Cf, bf16_t* __restrict__ Cb,
    int M, int K, int relu, int rstride, float* psum, float* psq)
{
  gemm_body<NT, 1, false>(Ab, Wp, bias, Cf, Cb, M, K, relu, rstride, blockIdx.x,
                          psum, psq, nullptr, nullptr);
}

// BN+ReLU fused on A (GIN second GEMM only) — separate instantiation so the
// plain GEMMs keep their 40KB/4-block occupancy.
template<int NT>
__global__ __launch_bounds__(256, 3) void gemm_r1_bn(
    const bf16_t* __restrict__ Ab, const bf16_t* __restrict__ Wp,
    const float* __restrict__ bias, float* __restrict__ Cf, bf16_t* __restrict__ Cb,
    int M, int K, int relu, int rstride,
    const float* ascale, const float* ashift)
{
  gemm_body<NT, 1, true>(Ab, Wp, bias, Cf, Cb, M, K, relu, rstride, blockIdx.x,
                         nullptr, nullptr, ascale, ashift);
}

// 4 GEMMs sharing A (q,k,v,s) in one dispatch: grid.y selects the weight set.
struct QkvsArgs { const bf16_t* w[4]; const float* bias[4]; bf16_t* outp[4]; };
__global__ __launch_bounds__(256, 3) void gemm_qkvs(
    const bf16_t* __restrict__ Ab, QkvsArgs qa, int M, int K)
{
  int which = blockIdx.y;
  gemm_body<16, 2, false>(Ab, qa.w[which], qa.bias[which], nullptr, qa.outp[which],
                          M, K, 0, 1024, blockIdx.x, nullptr, nullptr, nullptr, nullptr);
}

// ---------------- fused edge softmax-aggregate: ONE NODE PER WAVE ----------
// Halves of the wave process even/odd edges of the SAME node -> wave-uniform
// trip counts. TLP (8 waves/SIMD at VGPR=64) hides gather latency — do NOT
// register-pipeline this loop (R4 post-mortem: VGPR 112 -> occupancy cliff).
__global__ __launch_bounds__(256) void conv_edge_fused(
    const int* __restrict__ rowptr, const int* __restrict__ esrc,
    const bf16_t* __restrict__ qkvs, const bf16_t* __restrict__ eac,
    const float* __restrict__ QEf,
    bf16_t* __restrict__ AGGn, bf16_t* __restrict__ EAn)
{
  int l = threadIdx.x & 31;
  int half = (threadIdx.x >> 5) & 1;
  int n = blockIdx.x * 4 + (threadIdx.x >> 6);
  if (n >= NN) return;
  float q[8];
  {
    bf16x8 t = __builtin_nontemporal_load((const bf16x8*)&qkvs[(size_t)n * 1024 + l * 8]);
#pragma unroll
    for (int j = 0; j < 8; ++j) q[j] = (float)t[j];
  }
  float qe[8];
#pragma unroll
  for (int j = 0; j < 8; ++j) qe[j] = 0.f;
  if (l < 4) {
    const f32x4* p = (const f32x4*)&QEf[(size_t)n * DED + l * 8];
    f32x4 qa = __builtin_nontemporal_load(p);
    f32x4 qb = __builtin_nontemporal_load(p + 1);
#pragma unroll
    for (int j = 0; j < 4; ++j) { qe[j] = qa[j]; qe[j + 4] = qb[j]; }
  }
  float s = 0.f;
  float acc[8], eacc[8];
#pragma unroll
  for (int j = 0; j < 8; ++j) { acc[j] = 0.f; eacc[j] = 0.f; }
  int i0 = rowptr[n], i1 = rowptr[n + 1];
  for (int wb = i0; wb < i1; wb += 32) {
    int wcnt = min(32, i1 - wb);
    int widx = (l < wcnt) ? esrc[wb + l] : 0;
    int e = 0;
    for (; e + 8 <= wcnt; e += 8) {          // 4 edges per half per step
      int s1 = __shfl(widx, e + half, 32);
      int s2 = __shfl(widx, e + 2 + half, 32);
      int s3 = __shfl(widx, e + 4 + half, 32);
      int s4 = __shfl(widx, e + 6 + half, 32);
      const bf16_t* b1 = &qkvs[(size_t)s1 * 1024 + 256 + l * 8];
      const bf16_t* b2 = &qkvs[(size_t)s2 * 1024 + 256 + l * 8];
      const bf16_t* b3 = &qkvs[(size_t)s3 * 1024 + 256 + l * 8];
      const bf16_t* b4 = &qkvs[(size_t)s4 * 1024 + 256 + l * 8];
      bf16x8 k1 = *(const bf16x8*)b1;
      bf16x8 k2 = *(const bf16x8*)b2;
      bf16x8 k3 = *(const bf16x8*)b3;
      bf16x8 k4 = *(const bf16x8*)b4;
      bf16x8 v1 = *(const bf16x8*)(b1 + 256);
      bf16x8 v2 = *(const bf16x8*)(b2 + 256);
      bf16x8 v3 = *(const bf16x8*)(b3 + 256);
      bf16x8 v4 = *(const bf16x8*)(b4 + 256);
      bf16x8 t1 = {}, t2 = {}, t3 = {}, t4 = {};
      if (l < 4) {
        const bf16_t* ep = &eac[(size_t)(wb + e + half) * DED + l * 8];
        t1 = __builtin_nontemporal_load((const bf16x8*)ep);
        t2 = __builtin_nontemporal_load((const bf16x8*)(ep + 2 * DED));
        t3 = __builtin_nontemporal_load((const bf16x8*)(ep + 4 * DED));
        t4 = __builtin_nontemporal_load((const bf16x8*)(ep + 6 * DED));
      }
      float p1 = 0.f, p2 = 0.f, p3 = 0.f, p4 = 0.f;
#pragma unroll
      for (int j = 0; j < 8; ++j) {
        p1 = fmaf(q[j], (float)k1[j], p1);
        p2 = fmaf(q[j], (float)k2[j], p2);
        p3 = fmaf(q[j], (float)k3[j], p3);
        p4 = fmaf(q[j], (float)k4[j], p4);
      }
#pragma unroll
      for (int j = 0; j < 8; ++j) {
        p1 = fmaf(qe[j], (float)t1[j], p1);
        p2 = fmaf(qe[j], (float)t2[j], p2);
        p3 = fmaf(qe[j], (float)t3[j], p3);
        p4 = fmaf(qe[j], (float)t4[j], p4);
      }
#pragma unroll
      for (int off = 16; off > 0; off >>= 1) {
        p1 += __shfl_xor(p1, off, 32);
        p2 += __shfl_xor(p2, off, 32);
        p3 += __shfl_xor(p3, off, 32);
        p4 += __shfl_xor(p4, off, 32);
      }
      float ex1 = __expf(p1 * 0.0625f);   // scores O(1); exp without max-shift is safe
      float ex2 = __expf(p2 * 0.0625f);
      float ex3 = __expf(p3 * 0.0625f);
      float ex4 = __expf(p4 * 0.0625f);
      s += (ex1 + ex2) + (ex3 + ex4);
#pragma unroll
      for (int j = 0; j < 8; ++j) {
        acc[j] = fmaf(ex1, (float)v1[j], acc[j]);
        acc[j] = fmaf(ex2, (float)v2[j], acc[j]);
        acc[j] = fmaf(ex3, (float)v3[j], acc[j]);
        acc[j] = fmaf(ex4, (float)v4[j], acc[j]);
      }
#pragma unroll
      for (int j = 0; j < 8; ++j) {
        eacc[j] = fmaf(ex1, (float)t1[j], eacc[j]);
        eacc[j] = fmaf(ex2, (float)t2[j], eacc[j]);
        eacc[j] = fmaf(ex3, (float)t3[j], eacc[j]);
        eacc[j] = fmaf(ex4, (float)t4[j], eacc[j]);
      }
    }
    for (; e < wcnt; e += 2) {               // tail: 1 edge per half, masked
      int eh = e + half;
      bool act = eh < wcnt;
      int s1 = __shfl(widx, act ? eh : e, 32);
      const bf16_t* b1 = &qkvs[(size_t)s1 * 1024 + 256 + l * 8];
      bf16x8 k1 = *(const bf16x8*)b1;
      bf16x8 v1 = *(const bf16x8*)(b1 + 256);
      bf16x8 t1 = {};
      if (act && l < 4)
        t1 = __builtin_nontemporal_load((const bf16x8*)&eac[(size_t)(wb + eh) * DED + l * 8]);
      float p1 = 0.f;
#pragma unroll
      for (int j = 0; j < 8; ++j) p1 = fmaf(q[j], (float)k1[j], p1);
#pragma unroll
      for (int j = 0; j < 8; ++j) p1 = fmaf(qe[j], (float)t1[j], p1);
#pragma unroll
      for (int off = 16; off > 0; off >>= 1) p1 += __shfl_xor(p1, off, 32);
      float ex1 = act ? __expf(p1 * 0.0625f) : 0.f;
      s += ex1;
#pragma unroll
      for (int j = 0; j < 8; ++j) acc[j] = fmaf(ex1, (float)v1[j], acc[j]);
#pragma unroll
      for (int j = 0; j < 8; ++j) eacc[j] = fmaf(ex1, (float)t1[j], eacc[j]);
    }
  }
  // combine halves (same node)
  s += __shfl_xor(s, 32, 64);
#pragma unroll
  for (int j = 0; j < 8; ++j) acc[j] += __shfl_xor(acc[j], 32, 64);
#pragma unroll
  for (int j = 0; j < 8; ++j) eacc[j] += __shfl_xor(eacc[j], 32, 64);
  float inv = 1.f / (s + 1e-16f);
  if (half == 0) {
    bf16x8 o;
#pragma unroll
    for (int j = 0; j < 8; ++j) o[j] = (bf16_t)(acc[j] * inv);
    __builtin_nontemporal_store(o, (bf16x8*)&AGGn[(size_t)n * DH + l * 8]);
    if (l < 4) {
      bf16x8 eo;
#pragma unroll
      for (int j = 0; j < 8; ++j) eo[j] = (bf16_t)(eacc[j] * inv);
      __builtin_nontemporal_store(eo, (bf16x8*)&EAn[(size_t)n * DED + l * 8]);
    }
  }
}

// out = LN( leaky_relu( AGGn + E2N + S ) ) * g + b ; S = qkvs[:,768:1024]
__global__ __launch_bounds__(256) void conv_epilogue(
    const bf16_t* __restrict__ AGGn, const bf16_t* __restrict__ E2N,
    const bf16_t* __restrict__ qkvs, const float* __restrict__ g,
    const float* __restrict__ b, bf16_t* __restrict__ out)
{
  int wv = threadIdx.x >> 6, lane = threadIdx.x & 63;
  int n = blockIdx.x * 4 + wv;
  if (n >= NN) return;
  size_t base = (size_t)n * DH + lane * 4;
  bf16x4 a = __builtin_nontemporal_load((const bf16x4*)&AGGn[base]);
  bf16x4 e2 = __builtin_nontemporal_load((const bf16x4*)&E2N[base]);
  bf16x4 sv = __builtin_nontemporal_load(
      (const bf16x4*)&qkvs[(size_t)n * 1024 + 768 + lane * 4]);
  float v[4];
#pragma unroll
  for (int j = 0; j < 4; ++j) {
    float t = (float)a[j] + (float)e2[j] + (float)sv[j];
    v[j] = (t > 0.f) ? t : 0.01f * t;
  }
  float sum = v[0] + v[1] + v[2] + v[3];
  float sq = v[0]*v[0] + v[1]*v[1] + v[2]*v[2] + v[3]*v[3];
#pragma unroll
  for (int off = 32; off > 0; off >>= 1) {
    sum += __shfl_xor(sum, off, 64);
    sq  += __shfl_xor(sq, off, 64);
  }
  float mu = sum * (1.f / DH);
  float var = sq * (1.f / DH) - mu * mu;
  float rstd = rsqrtf(var + 1e-5f);
  bf16x4 o;
#pragma unroll
  for (int j = 0; j < 4; ++j)
    o[j] = (bf16_t)((v[j] - mu) * rstd * g[lane * 4 + j] + b[lane * 4 + j]);
  *(bf16x4*)&out[base] = o;
}

// ---------------- GIN gather: one node per wave ----------------
__global__ __launch_bounds__(256) void gin_gather(
    const int* __restrict__ rowptr, const int* __restrict__ esrc,
    const bf16_t* __restrict__ h, bf16_t* __restrict__ out)
{
  int l = threadIdx.x & 31;
  int half = (threadIdx.x >> 5) & 1;
  int n = blockIdx.x * 4 + (threadIdx.x >> 6);
  if (n >= NN) return;
  size_t co = (size_t)n * DH + l * 8;
  float acc[8];
  {
    bf16x8 hv = *(const bf16x8*)&h[co];
    float w0 = (half == 0) ? 1.f : 0.f;      // self term counted once
#pragma unroll
    for (int j = 0; j < 8; ++j) acc[j] = w0 * (float)hv[j];
  }
  int i0 = rowptr[n], i1 = rowptr[n + 1];
  for (int wb = i0; wb < i1; wb += 32) {
    int wcnt = min(32, i1 - wb);
    int widx = (l < wcnt) ? esrc[wb + l] : 0;
    int e = 0;
    for (; e + 8 <= wcnt; e += 8) {
      int s1 = __shfl(widx, e + half, 32);
      int s2 = __shfl(widx, e + 2 + half, 32);
      int s3 = __shfl(widx, e + 4 + half, 32);
      int s4 = __shfl(widx, e + 6 + half, 32);
      bf16x8 t1 = *(const bf16x8*)&h[(size_t)s1 * DH + l * 8];
      bf16x8 t2 = *(const bf16x8*)&h[(size_t)s2 * DH + l * 8];
      bf16x8 t3 = *(const bf16x8*)&h[(size_t)s3 * DH + l * 8];
      bf16x8 t4 = *(const bf16x8*)&h[(size_t)s4 * DH + l * 8];
#pragma unroll
      for (int j = 0; j < 8; ++j)
        acc[j] += ((float)t1[j] + (float)t2[j]) + ((float)t3[j] + (float)t4[j]);
    }
    for (; e < wcnt; e += 2) {
      int eh = e + half;
      bool act = eh < wcnt;
      int s1 = __shfl(widx, act ? eh : e, 32);
      bf16x8 t1 = *(const bf16x8*)&h[(size_t)s1 * DH + l * 8];
      float w = act ? 1.f : 0.f;
#pragma unroll
      for (int j = 0; j < 8; ++j) acc[j] += w * (float)t1[j];
    }
  }
#pragma unroll
  for (int j = 0; j < 8; ++j) acc[j] += __shfl_xor(acc[j], 32, 64);
  if (half == 0) {
    bf16x8 o;
#pragma unroll
    for (int j = 0; j < 8; ++j) o[j] = (bf16_t)acc[j];
    __builtin_nontemporal_store(o, (bf16x8*)&out[co]);
  }
}

// ---------------- BN (partials produced by GEMM epilogue) ----------------
__global__ void bn_final_na(const float* __restrict__ psum, const float* __restrict__ psq,
                            const float* __restrict__ bng, const float* __restrict__ bnb,
                            float* __restrict__ scale, float* __restrict__ shift) {
  int c = threadIdx.x;
  float s = 0.f, ss = 0.f;
  for (int b = 0; b < 4; ++b) { s += psum[b * DH + c]; ss += psq[b * DH + c]; }
  float mu = s * (1.f / NN);
  float var = ss * (1.f / NN) - mu * mu;
  float rstd = rsqrtf(var + 1e-5f);
  float sc = bng[c] * rstd;
  scale[c] = sc;
  shift[c] = bnb[c] - mu * sc;
}

// ---------------- pooling over sorted batch (bf16 input) ----------------
__global__ __launch_bounds__(256) void pool_sorted(
    const int* __restrict__ batch, const bf16_t* __restrict__ h, float* __restrict__ pooled)
{
  __shared__ int s0, s1;
  int g = blockIdx.x;
  if (threadIdx.x == 0) {
    int lo = 0, hi = NN;
    while (lo < hi) { int mid = (lo + hi) >> 1; if (batch[mid] < g) lo = mid + 1; else hi = mid; }
    s0 = lo;
  }
  if (threadIdx.x == 1) {
    int lo = 0, hi = NN;
    while (lo < hi) { int mid = (lo + hi) >> 1; if (batch[mid] < g + 1) lo = mid + 1; else hi = mid; }
    s1 = lo;
  }
  __syncthreads();
  int c = threadIdx.x;
  float acc = 0.f;
  for (int r = s0; r < s1; ++r)
    acc += (float)__builtin_nontemporal_load(&h[(size_t)r * DH + c]);
  pooled[(size_t)g * DH + c] = acc;
}

// ---------------- small fp32 GEMM (head only) ----------------
__global__ __launch_bounds__(256) void gemm_bias_act(
    const float* __restrict__ A, const float* __restrict__ Wm,
    const float* __restrict__ bias, float* __restrict__ C,
    int M, int K, int Ncol, int act)
{
  __shared__ __align__(16) float As[16][68];
  __shared__ __align__(16) float Bs[16][68];
  int tid = threadIdx.x;
  int tx = tid & 15, ty = tid >> 4;
  int row0 = blockIdx.y * 64 + ty * 4;
  int col0 = blockIdx.x * 64 + tx * 4;
  float acc[4][4] = {{0.f}};
  for (int k0 = 0; k0 < K; k0 += 16) {
#pragma unroll
    for (int l = 0; l < 4; ++l) {
      int e = tid + l * 256;
      int r = e >> 4, kk = e & 15;
      int gr = blockIdx.y * 64 + r;
      As[kk][r] = (gr < M) ? A[(size_t)gr * K + k0 + kk] : 0.f;
    }
#pragma unroll
    for (int l = 0; l < 4; ++l) {
      int e = tid + l * 256;
      int kk = e >> 6, c = e & 63;
      int gc = blockIdx.x * 64 + c;
      Bs[kk][c] = (gc < Ncol) ? Wm[(size_t)(k0 + kk) * Ncol + gc] : 0.f;
    }
    __syncthreads();
#pragma unroll
    for (int kk = 0; kk < 16; ++kk) {
      float4 a4 = *(const float4*)&As[kk][ty * 4];
      float4 b4 = *(const float4*)&Bs[kk][tx * 4];
      float a[4] = {a4.x, a4.y, a4.z, a4.w};
      float b[4] = {b4.x, b4.y, b4.z, b4.w};
#pragma unroll
      for (int i = 0; i < 4; ++i)
#pragma unroll
        for (int j = 0; j < 4; ++j)
          acc[i][j] = fmaf(a[i], b[j], acc[i][j]);
    }
    __syncthreads();
  }
#pragma unroll
  for (int i = 0; i < 4; ++i) {
    int r = row0 + i;
    if (r >= M) continue;
#pragma unroll
    for (int j = 0; j < 4; ++j) {
      int c = col0 + j;
      if (c >= Ncol) continue;
      float val = acc[i][j];
      if (bias) val += bias[c];
      if (act == 1) val = fmaxf(val, 0.f);
      C[(size_t)r * Ncol + c] = val;
    }
  }
}

// ---------------- host ----------------
static inline void launch_filli(hipStream_t st, int* p, int v, long n) {
  fill_i32<<<dim3((unsigned)((n + 255) / 256)), dim3(256), 0, st>>>(p, v, (int)n);
}

extern "C" void kernel_launch(void* const* d_in, const int* in_sizes, int n_in,
                              void* d_out, int out_size, void* d_ws, size_t ws_size,
                              hipStream_t stream) {
  const float* x  = (const float*)d_in[0];
  const int* ei   = (const int*)d_in[1];
  const float* ea = (const float*)d_in[2];
  const int* batch = (const int*)d_in[3];
  const int* src = ei;
  const int* dst = ei + NE;

  const float* c1[9]; for (int i = 0; i < 9; ++i) c1[i] = (const float*)d_in[4 + i];
  const float* ln1g = (const float*)d_in[13]; const float* ln1b = (const float*)d_in[14];
  const float* c2[9]; for (int i = 0; i < 9; ++i) c2[i] = (const float*)d_in[15 + i];
  const float* ln2g = (const float*)d_in[24]; const float* ln2b = (const float*)d_in[25];
  const float* g1[6]; for (int i = 0; i < 6; ++i) g1[i] = (const float*)d_in[26 + i];
  const float* g2[6]; for (int i = 0; i < 6; ++i) g2[i] = (const float*)d_in[32 + i];
  const float* linW = (const float*)d_in[38]; const float* linb = (const float*)d_in[39];
  const float* clfW = (const float*)d_in[40]; const float* clfb = (const float*)d_in[41];
  float* out = (float*)d_out;

  // ---- bump allocator over d_ws (256B aligned) ----
  size_t off = 0;
  auto alloc = [&](size_t bytes) -> void* {
    void* r = (char*)d_ws + off;
    off += (bytes + 255) & ~(size_t)255;
    return r;
  };
  int* deg    = (int*)alloc(NN * 4);
  int* cursor = (int*)alloc(NN * 4);   // contiguous after deg (one merged zero-fill)
  int* rowptr = (int*)alloc((NN + 1) * 4);
  int* esrc   = (int*)alloc((size_t)NE * 4);
  int* epos   = (int*)alloc((size_t)NE * 4);
  int* bsum   = (int*)alloc(1024);
  int* boff   = (int*)alloc(1024);
  float* QEf   = (float*)alloc((size_t)NN * DED * 4);
  float* pooled = (float*)alloc((size_t)NG * DH * 4);
  float* zbuf   = (float*)alloc((size_t)NG * DH * 4);
  float* psum  = (float*)alloc(4 * DH * 4);    // per-wave-group BN partials
  float* psq   = (float*)alloc(4 * DH * 4);    // contiguous after psum
  float* bnscale = (float*)alloc(DH * 4);
  float* bnshift = (float*)alloc(DH * 4);
  float* wqe_tmp1 = (float*)alloc((size_t)DIN * DED * 4);
  float* wqe_tmp2 = (float*)alloc((size_t)DH * DED * 4);
  float* bqe1 = (float*)alloc(DED * 4);
  float* bqe2 = (float*)alloc(DED * 4);
  bf16_t* qkvsb = (bf16_t*)alloc((size_t)NN * 1024 * 2);  // q|k|v|s interleaved
  bf16_t* h_b = (bf16_t*)alloc((size_t)NN * DH * 2);
  bf16_t* g_b = (bf16_t*)alloc((size_t)NN * DH * 2);
  bf16_t* Yb  = (bf16_t*)alloc((size_t)NN * DH * 2);      // GIN y1 (pre-BN), bf16
  bf16_t* AGGb = (bf16_t*)alloc((size_t)NN * DH * 2);
  bf16_t* E2Nb = (bf16_t*)alloc((size_t)NN * DH * 2);
  bf16_t* EAn = (bf16_t*)alloc((size_t)NN * DED * 2);
  bf16_t* xb  = (bf16_t*)alloc((size_t)NN * DIN * 2);
  bf16_t* eac = (bf16_t*)alloc((size_t)NE * DED * 2);     // edge_attr, CSR order
  bf16_t* Hb = (bf16_t*)qkvsb;  // final GIN output bf16, aliases qkvs region
  bf16_t* pk1q = (bf16_t*)alloc(DIN * DH * 2);
  bf16_t* pk1k = (bf16_t*)alloc(DIN * DH * 2);
  bf16_t* pk1v = (bf16_t*)alloc(DIN * DH * 2);
  bf16_t* pk1s = (bf16_t*)alloc(DIN * DH * 2);
  bf16_t* pk1qe = (bf16_t*)alloc(DIN * DED * 2);
  bf16_t* pk1we = (bf16_t*)alloc(DED * DH * 2);
  bf16_t* pk2q = (bf16_t*)alloc(DH * DH * 2);
  bf16_t* pk2k = (bf16_t*)alloc(DH * DH * 2);
  bf16_t* pk2v = (bf16_t*)alloc(DH * DH * 2);
  bf16_t* pk2s = (bf16_t*)alloc(DH * DH * 2);
  bf16_t* pk2qe = (bf16_t*)alloc(DH * DED * 2);
  bf16_t* pk2we = (bf16_t*)alloc(DED * DH * 2);
  bf16_t* pkg1a = (bf16_t*)alloc(DH * DH * 2);
  bf16_t* pkg1b = (bf16_t*)alloc(DH * DH * 2);
  bf16_t* pkg2a = (bf16_t*)alloc(DH * DH * 2);
  bf16_t* pkg2b = (bf16_t*)alloc(DH * DH * 2);
  if (ws_size < off) return;

  const int GRID_M  = (NN + 127) / 128;   // RT=2 (qkvs, grid.y=4)
  const int GRID_M1 = (NN + 63) / 64;     // RT=1 (single-output GEMMs)

  cast_bf16x8_k<<<dim3((unsigned)(((long)NN * DIN / 8 + 255) / 256)), dim3(256), 0, stream>>>(
      x, xb, (long)NN * DIN / 8);
  wqe_k<<<dim3((DIN * 32 + 255) / 256), dim3(256), 0, stream>>>(c1[0], c1[6], c1[1], wqe_tmp1, bqe1, DIN);
  wqe_k<<<dim3((DH * 32 + 255) / 256), dim3(256), 0, stream>>>(c2[0], c2[6], c2[1], wqe_tmp2, bqe2, DH);
  PackArgs pa;
  pa.e[0]  = {c1[0], pk1q, DIN, DH};
  pa.e[1]  = {c1[2], pk1k, DIN, DH};
  pa.e[2]  = {c1[4], pk1v, DIN, DH};
  pa.e[3]  = {c1[7], pk1s, DIN, DH};
  pa.e[4]  = {c1[6], pk1we, DED, DH};
  pa.e[5]  = {wqe_tmp1, pk1qe, DIN, DED};
  pa.e[6]  = {c2[0], pk2q, DH, DH};
  pa.e[7]  = {c2[2], pk2k, DH, DH};
  pa.e[8]  = {c2[4], pk2v, DH, DH};
  pa.e[9]  = {c2[7], pk2s, DH, DH};
  pa.e[10] = {c2[6], pk2we, DED, DH};
  pa.e[11] = {wqe_tmp2, pk2qe, DH, DED};
  pa.e[12] = {g1[0], pkg1a, DH, DH};
  pa.e[13] = {g1[4], pkg1b, DH, DH};
  pa.e[14] = {g2[0], pkg2a, DH, DH};
  pa.e[15] = {g2[4], pkg2b, DH, DH};
  pack_all<<<dim3(256, 16), dim3(256), 0, stream>>>(pa);

  const int nb1 = (NN + SCAN_T - 1) / SCAN_T;
  // deg and cursor are contiguous 256B-aligned allocations: one merged zero-fill
  launch_filli(stream, deg, 0, 2 * ((NN * 4 + 255) & ~255) / 4);
  count_k<<<dim3((NE + 255) / 256), dim3(256), 0, stream>>>(dst, deg);
  scan1<<<dim3(nb1), dim3(SCAN_T), 0, stream>>>(deg, rowptr, bsum, NN);
  scan2<<<dim3(1), dim3(SCAN_T), 0, stream>>>(bsum, boff, nb1);
  scan3<<<dim3(nb1), dim3(SCAN_T), 0, stream>>>(rowptr, boff, NN);
  scatter_k<<<dim3((NE + 255) / 256), dim3(256), 0, stream>>>(dst, src, rowptr, cursor, esrc, epos);
  permute_ea<<<dim3((unsigned)(((long)NE * 4 + 255) / 256)), dim3(256), 0, stream>>>(epos, ea, eac);

  auto conv = [&](const bf16_t* Ain, int K,
                  const bf16_t* pq, const bf16_t* pk, const bf16_t* pv, const bf16_t* ps,
                  const bf16_t* pqe, const bf16_t* pwe,
                  const float* const* P, const float* bqe,
                  const float* lng, const float* lnb, bf16_t* outb) {
    QkvsArgs qa;
    qa.w[0] = pq; qa.w[1] = pk; qa.w[2] = pv; qa.w[3] = ps;
    qa.bias[0] = P[1]; qa.bias[1] = P[3]; qa.bias[2] = P[5]; qa.bias[3] = P[8];
    qa.outp[0] = qkvsb + 0; qa.outp[1] = qkvsb + 256;
    qa.outp[2] = qkvsb + 512; qa.outp[3] = qkvsb + 768;
    gemm_qkvs<<<dim3(GRID_M, 4), dim3(256), 0, stream>>>(Ain, qa, NN, K);
    gemm_r1<2><<<dim3(GRID_M1), dim3(256), 0, stream>>>(
        Ain, pqe, bqe, QEf, nullptr, NN, K, 0, 32, nullptr, nullptr);
    conv_edge_fused<<<dim3((NN + 3) / 4), dim3(256), 0, stream>>>(
        rowptr, esrc, qkvsb, eac, QEf, AGGb, EAn);
    gemm_r1<16><<<dim3(GRID_M1), dim3(256), 0, stream>>>(
        EAn, pwe, nullptr, nullptr, E2Nb, NN, DED, 0, 256, nullptr, nullptr);
    conv_epilogue<<<dim3((NN + 3) / 4), dim3(256), 0, stream>>>(
        AGGb, E2Nb, qkvsb, lng, lnb, outb);
  };

  auto gin = [&](const bf16_t* hin, const bf16_t* pw1, const bf16_t* pw2,
                 const float* const* P, int relu_out, bf16_t* outb) {
    gin_gather<<<dim3((NN + 3) / 4), dim3(256), 0, stream>>>(rowptr, esrc, hin, g_b);
    launch_filli(stream, (int*)psum, 0, 2 * 4 * DH);  // zero psum+psq (contiguous)
    gemm_r1<16><<<dim3(GRID_M1), dim3(256), 0, stream>>>(
        g_b, pw1, P[1], nullptr, Yb, NN, DH, 0, 256, psum, psq);
    bn_final_na<<<dim3(1), dim3(256), 0, stream>>>(psum, psq, P[2], P[3], bnscale, bnshift);
    // second GEMM applies BN+ReLU to A on the fly (separate FBN instantiation)
    gemm_r1_bn<16><<<dim3(GRID_M1), dim3(256), 0, stream>>>(
        Yb, pw2, P[5], nullptr, outb, NN, DH, relu_out, 256, bnscale, bnshift);
  };

  conv(xb, DIN, pk1q, pk1k, pk1v, pk1s, pk1qe, pk1we, c1, bqe1, ln1g, ln1b, h_b);
  conv(h_b, DH, pk2q, pk2k, pk2v, pk2s, pk2qe, pk2we, c2, bqe2, ln2g, ln2b, h_b);
  gin(h_b, pkg1a, pkg1b, g1, 1, h_b);
  gin(h_b, pkg2a, pkg2b, g2, 0, Hb);

  pool_sorted<<<dim3(NG), dim3(256), 0, stream>>>(batch, Hb, pooled);
  gemm_bias_act<<<dim3(4, 8), dim3(256), 0, stream>>>(pooled, linW, linb, zbuf, NG, DH, DH, 1);
  gemm_bias_act<<<dim3(1, 8), dim3(256), 0, stream>>>(zbuf, clfW, clfb, out, NG, DH, DOUT, 0);
}

// Round 7
// 1289.326 us; speedup vs baseline: 1.0619x; 1.0048x over previous
//
#include <hip/hip_runtime.h>
#include <math.h>

#define NN 50000
#define NE 800000
#define DIN 128
#define DH 256
#define DED 32
#define NG 500
#define DOUT 16
#define SCAN_T 256

typedef __bf16 bf16_t;
typedef __bf16 bf16x4 __attribute__((ext_vector_type(4)));
typedef __bf16 bf16x8 __attribute__((ext_vector_type(8)));
typedef float f32x4 __attribute__((ext_vector_type(4)));

// async global->LDS, 16B per lane (global_load_lds_dwordx4)
__device__ __forceinline__ void async_copy16(const bf16_t* g, bf16_t* l) {
  __builtin_amdgcn_global_load_lds(
      (const __attribute__((address_space(1))) void*)g,
      (__attribute__((address_space(3))) void*)l, 16, 0, 0);
}

// ---------------- utility ----------------
__global__ void fill_i32(int* __restrict__ p, int v, int n) {
  int i = blockIdx.x * 256 + threadIdx.x;
  if (i < n) p[i] = v;
}
__global__ void cast_bf16x8_k(const float* __restrict__ in, bf16_t* __restrict__ o, long n8) {
  long i = (long)blockIdx.x * 256 + threadIdx.x;
  if (i >= n8) return;
  const f32x4* sp = (const f32x4*)&in[i * 8];
  f32x4 a = __builtin_nontemporal_load(sp);
  f32x4 b = __builtin_nontemporal_load(sp + 1);
  bf16x8 r;
#pragma unroll
  for (int j = 0; j < 4; ++j) { r[j] = (bf16_t)a[j]; r[j + 4] = (bf16_t)b[j]; }
  *(bf16x8*)&o[i * 8] = r;
}

// ---------------- CSR build (by dst) ----------------
__global__ void count_k(const int* __restrict__ dst, int* __restrict__ deg) {
  int e = blockIdx.x * 256 + threadIdx.x;
  if (e < NE) atomicAdd(&deg[dst[e]], 1);
}
__global__ void scan1(const int* __restrict__ deg, int* __restrict__ rowptr,
                      int* __restrict__ bsum, int n) {
  __shared__ int s[SCAN_T];
  int t = threadIdx.x, i = blockIdx.x * SCAN_T + t;
  int v = (i < n) ? deg[i] : 0;
  s[t] = v; __syncthreads();
  for (int off = 1; off < SCAN_T; off <<= 1) {
    int add = (t >= off) ? s[t - off] : 0;
    __syncthreads(); s[t] += add; __syncthreads();
  }
  if (i < n) rowptr[i + 1] = s[t];
  if (t == SCAN_T - 1) bsum[blockIdx.x] = s[t];
}
__global__ void scan2(const int* __restrict__ bsum, int* __restrict__ boff, int nb) {
  __shared__ int s[SCAN_T];
  int t = threadIdx.x;
  int v = (t < nb) ? bsum[t] : 0;
  s[t] = v; __syncthreads();
  for (int off = 1; off < SCAN_T; off <<= 1) {
    int add = (t >= off) ? s[t - off] : 0;
    __syncthreads(); s[t] += add; __syncthreads();
  }
  boff[t] = s[t] - v;
}
__global__ void scan3(int* __restrict__ rowptr, const int* __restrict__ boff, int n) {
  int i = blockIdx.x * 256 + threadIdx.x;
  if (i < n) rowptr[i + 1] += boff[i >> 8];
  if (i == 0) rowptr[0] = 0;
}
// records epos[e] = CSR slot of edge e (inverse permutation) so edge_attr can be
// stream-read / scatter-written instead of gather-read.
__global__ void scatter_k(const int* __restrict__ dst, const int* __restrict__ src,
                          const int* __restrict__ rowptr, int* __restrict__ cursor,
                          int* __restrict__ esrc, int* __restrict__ epos) {
  int e = blockIdx.x * 256 + threadIdx.x;
  if (e < NE) {
    int d = dst[e];
    int pos = rowptr[d] + atomicAdd(&cursor[d], 1);
    esrc[pos] = src[e];
    epos[e] = pos;
  }
}
// cast + permute edge_attr into CSR order: sequential fp32 reads (stream),
// scattered 64B bf16 writes (write path tolerates randomness far better).
__global__ void permute_ea(const int* __restrict__ epos, const float* __restrict__ ea,
                           bf16_t* __restrict__ eac) {
  long t = (long)blockIdx.x * 256 + threadIdx.x;
  if (t >= (long)NE * 4) return;
  int e = (int)(t >> 2), c8 = ((int)t & 3) * 8;
  int pos = epos[e];
  const f32x4* sp = (const f32x4*)&ea[(size_t)e * DED + c8];
  f32x4 a = __builtin_nontemporal_load(sp);
  f32x4 b = __builtin_nontemporal_load(sp + 1);
  bf16x8 o;
#pragma unroll
  for (int j = 0; j < 4; ++j) { o[j] = (bf16_t)a[j]; o[j + 4] = (bf16_t)b[j]; }
  __builtin_nontemporal_store(o, (bf16x8*)&eac[(size_t)pos * DED + c8]);
}

// ---------------- weight fragment packing (all weights, one dispatch) ----------------
struct PackEnt { const float* src; bf16_t* dst; int K; int N; };
struct PackArgs { PackEnt e[16]; };
__global__ void pack_all(PackArgs pa) {
  PackEnt en = pa.e[blockIdx.y];
  int i = blockIdx.x * 256 + threadIdx.x;
  if (i >= en.K * en.N) return;
  int el = i & 511, f = i >> 9;
  int ntiles = en.N >> 4;
  int ks = f / ntiles, t = f - ks * ntiles;
  int lane = el >> 3, j = el & 7;
  int k = ks * 32 + (lane >> 4) * 8 + j;
  int n = t * 16 + (lane & 15);
  en.dst[i] = (bf16_t)en.src[(size_t)k * en.N + n];
}

// Wqe[d][j] = sum_h Wq[d][h]*We[j][h]; bqe[j] = sum_h bq[h]*We[j][h]
__global__ void wqe_k(const float* __restrict__ Wq, const float* __restrict__ We,
                      const float* __restrict__ bq, float* __restrict__ Wqe,
                      float* __restrict__ bqe, int din) {
  int idx = blockIdx.x * 256 + threadIdx.x;
  if (idx < din * 32) {
    int d = idx >> 5, j = idx & 31;
    float s = 0.f;
    for (int h = 0; h < DH; ++h) s += Wq[(size_t)d * DH + h] * We[(size_t)j * DH + h];
    Wqe[idx] = s;
  }
  if (idx < 32) {
    float s = 0.f;
    for (int h = 0; h < DH; ++h) s += bq[h] * We[(size_t)idx * DH + h];
    bqe[idx] = s;
  }
}

// ---------------- MFMA GEMM: 2-phase double-buffered LDS staging ------------
// RT row-tiles per wave: block tile = RT*64 rows x NT*16 cols; BK=32.
// stage(next) issued BEFORE compute(cur); single vmcnt(0)+s_barrier per K-step.
// No per-instantiation extras (R5/R6 post-mortem: even +2KB LDS or a runtime
// branch in this body drops 4->3 blocks/CU on the NT=16 variant).
// Optional BN column stats (psum/psq[4][DH]) accumulated from the registers.
template<int NT, int RT>
__device__ __forceinline__ void gemm_body(
    const bf16_t* __restrict__ Ab, const bf16_t* __restrict__ Wp,
    const float* __restrict__ bias, float* __restrict__ Cf, bf16_t* __restrict__ Cb,
    int M, int K, int relu, int rstride, int bx,
    float* __restrict__ psum, float* __restrict__ psq)
{
  __shared__ bf16_t Atile[2][RT * 2048];   // 2 x RT*4 KB
  __shared__ bf16_t Btile[2][NT * 512];    // 2 x NT KB
  const int ACH = RT * 256;                // A 16B-chunks per kstep
  const int NCH = ACH + NT * 64;
  int tid = threadIdx.x;
  int lane = tid & 63, wv = tid >> 6;
  int base = bx * (RT * 64);
  f32x4 acc[RT][NT];
#pragma unroll
  for (int rt = 0; rt < RT; ++rt)
#pragma unroll
    for (int t = 0; t < NT; ++t) acc[rt][t] = (f32x4){0.f, 0.f, 0.f, 0.f};
  int arow = wv * (16 * RT) + (lane & 15);
  int aq = (lane >> 4) * 8;
  int nk = K >> 5;

  auto stage = [&](int buf, int ks) {
    for (int c = tid; c < NCH; c += 256) {
      if (c < ACH) {                       // A: row = c>>2, 16B sub-chunk q = c&3
        int r = c >> 2, qq = c & 3;
        async_copy16(Ab + (size_t)(base + r) * K + ks * 32 + qq * 8,
                     &Atile[buf][c * 8]);
      } else {                             // B: linear 16B chunks of the kstep block
        int cb = c - ACH;
        async_copy16(Wp + (size_t)ks * NT * 512 + cb * 8, &Btile[buf][cb * 8]);
      }
    }
  };

  stage(0, 0);
  asm volatile("s_waitcnt vmcnt(0)" ::: "memory");
  __builtin_amdgcn_s_barrier();
  int cur = 0;
  for (int ks = 0; ks < nk; ++ks) {
    if (ks + 1 < nk) stage(cur ^ 1, ks + 1);   // prefetch overlaps compute below
    bf16x8 a[RT];
#pragma unroll
    for (int rt = 0; rt < RT; ++rt)
      a[rt] = *(const bf16x8*)&Atile[cur][(arow + rt * 16) * 32 + aq];
#pragma unroll
    for (int t = 0; t < NT; ++t) {
      bf16x8 b = *(const bf16x8*)&Btile[cur][t * 512 + lane * 8];
#pragma unroll
      for (int rt = 0; rt < RT; ++rt)
        acc[rt][t] = __builtin_amdgcn_mfma_f32_16x16x32_bf16(a[rt], b, acc[rt][t], 0, 0, 0);
    }
    asm volatile("s_waitcnt vmcnt(0)" ::: "memory");  // next tile landed
    __builtin_amdgcn_s_barrier();                     // all waves done reading cur
    cur ^= 1;
  }
  int col_l = lane & 15;
#pragma unroll
  for (int rt = 0; rt < RT; ++rt) {
    int rbase = base + wv * (16 * RT) + rt * 16 + (lane >> 4) * 4;
#pragma unroll
    for (int t = 0; t < NT; ++t) {
      int col = t * 16 + col_l;
      float bv = bias ? bias[col] : 0.f;
#pragma unroll
      for (int r = 0; r < 4; ++r) {
        int row = rbase + r;
        if (row >= M) continue;
        float vv = acc[rt][t][r] + bv;
        if (relu) vv = fmaxf(vv, 0.f);
        if (Cf) Cf[(size_t)row * rstride + col] = vv;
        if (Cb) Cb[(size_t)row * rstride + col] = (bf16_t)vv;
      }
    }
  }
  if (psum) {                           // fused BN column stats (GIN y1 only)
#pragma unroll
    for (int t = 0; t < NT; ++t) {
      float sc = 0.f, sq = 0.f;
      float bv = bias[t * 16 + col_l];
#pragma unroll
      for (int rt = 0; rt < RT; ++rt) {
        int rbase = base + wv * (16 * RT) + rt * 16 + (lane >> 4) * 4;
#pragma unroll
        for (int r = 0; r < 4; ++r) {
          if (rbase + r >= M) continue;
          float vv = acc[rt][t][r] + bv;
          sc += vv; sq += vv * vv;
        }
      }
      sc += __shfl_xor(sc, 16, 64); sc += __shfl_xor(sc, 32, 64);
      sq += __shfl_xor(sq, 16, 64); sq += __shfl_xor(sq, 32, 64);
      if (lane < 16) {
        int col = t * 16 + lane;
        atomicAdd(&psum[wv * DH + col], sc);
        atomicAdd(&psq[wv * DH + col], sq);
      }
    }
  }
}

template<int NT>
__global__ __launch_bounds__(256, 3) void gemm_r1(
    const bf16_t* __restrict__ Ab, const bf16_t* __restrict__ Wp,
    const float* __restrict__ bias, float* __restrict__ Cf, bf16_t* __restrict__ Cb,
    int M, int K, int relu, int rstride, float* psum, float* psq)
{
  gemm_body<NT, 1>(Ab, Wp, bias, Cf, Cb, M, K, relu, rstride, blockIdx.x, psum, psq);
}

// 4 GEMMs sharing A (q,k,v,s) in one dispatch. grid = (4, GRID_M): which-set is
// the FAST dimension so the 4 blocks reading the same A rows launch adjacently
// and share the A panel in L2 (x-major dispatch order).
struct QkvsArgs { const bf16_t* w[4]; const float* bias[4]; bf16_t* outp[4]; };
__global__ __launch_bounds__(256, 3) void gemm_qkvs(
    const bf16_t* __restrict__ Ab, QkvsArgs qa, int M, int K)
{
  int which = blockIdx.x;
  gemm_body<16, 2>(Ab, qa.w[which], qa.bias[which], nullptr, qa.outp[which], M, K, 0, 1024,
                   blockIdx.y, nullptr, nullptr);
}

// ---------------- fused edge softmax-aggregate: ONE NODE PER WAVE ----------
// Halves of the wave process even/odd edges of the SAME node -> wave-uniform
// trip counts. TLP (8 waves/SIMD at VGPR=64) hides gather latency — do NOT
// register-pipeline this loop (R4 post-mortem: VGPR 112 -> occupancy cliff).
__global__ __launch_bounds__(256) void conv_edge_fused(
    const int* __restrict__ rowptr, const int* __restrict__ esrc,
    const bf16_t* __restrict__ qkvs, const bf16_t* __restrict__ eac,
    const float* __restrict__ QEf,
    bf16_t* __restrict__ AGGn, bf16_t* __restrict__ EAn)
{
  int l = threadIdx.x & 31;
  int half = (threadIdx.x >> 5) & 1;
  int n = blockIdx.x * 4 + (threadIdx.x >> 6);
  if (n >= NN) return;
  float q[8];
  {
    bf16x8 t = __builtin_nontemporal_load((const bf16x8*)&qkvs[(size_t)n * 1024 + l * 8]);
#pragma unroll
    for (int j = 0; j < 8; ++j) q[j] = (float)t[j];
  }
  float qe[8];
#pragma unroll
  for (int j = 0; j < 8; ++j) qe[j] = 0.f;
  if (l < 4) {
    const f32x4* p = (const f32x4*)&QEf[(size_t)n * DED + l * 8];
    f32x4 qa = __builtin_nontemporal_load(p);
    f32x4 qb = __builtin_nontemporal_load(p + 1);
#pragma unroll
    for (int j = 0; j < 4; ++j) { qe[j] = qa[j]; qe[j + 4] = qb[j]; }
  }
  float s = 0.f;
  float acc[8], eacc[8];
#pragma unroll
  for (int j = 0; j < 8; ++j) { acc[j] = 0.f; eacc[j] = 0.f; }
  int i0 = rowptr[n], i1 = rowptr[n + 1];
  for (int wb = i0; wb < i1; wb += 32) {
    int wcnt = min(32, i1 - wb);
    int widx = (l < wcnt) ? esrc[wb + l] : 0;
    int e = 0;
    for (; e + 8 <= wcnt; e += 8) {          // 4 edges per half per step
      int s1 = __shfl(widx, e + half, 32);
      int s2 = __shfl(widx, e + 2 + half, 32);
      int s3 = __shfl(widx, e + 4 + half, 32);
      int s4 = __shfl(widx, e + 6 + half, 32);
      const bf16_t* b1 = &qkvs[(size_t)s1 * 1024 + 256 + l * 8];
      const bf16_t* b2 = &qkvs[(size_t)s2 * 1024 + 256 + l * 8];
      const bf16_t* b3 = &qkvs[(size_t)s3 * 1024 + 256 + l * 8];
      const bf16_t* b4 = &qkvs[(size_t)s4 * 1024 + 256 + l * 8];
      bf16x8 k1 = *(const bf16x8*)b1;
      bf16x8 k2 = *(const bf16x8*)b2;
      bf16x8 k3 = *(const bf16x8*)b3;
      bf16x8 k4 = *(const bf16x8*)b4;
      bf16x8 v1 = *(const bf16x8*)(b1 + 256);
      bf16x8 v2 = *(const bf16x8*)(b2 + 256);
      bf16x8 v3 = *(const bf16x8*)(b3 + 256);
      bf16x8 v4 = *(const bf16x8*)(b4 + 256);
      bf16x8 t1 = {}, t2 = {}, t3 = {}, t4 = {};
      if (l < 4) {
        const bf16_t* ep = &eac[(size_t)(wb + e + half) * DED + l * 8];
        t1 = __builtin_nontemporal_load((const bf16x8*)ep);
        t2 = __builtin_nontemporal_load((const bf16x8*)(ep + 2 * DED));
        t3 = __builtin_nontemporal_load((const bf16x8*)(ep + 4 * DED));
        t4 = __builtin_nontemporal_load((const bf16x8*)(ep + 6 * DED));
      }
      float p1 = 0.f, p2 = 0.f, p3 = 0.f, p4 = 0.f;
#pragma unroll
      for (int j = 0; j < 8; ++j) {
        p1 = fmaf(q[j], (float)k1[j], p1);
        p2 = fmaf(q[j], (float)k2[j], p2);
        p3 = fmaf(q[j], (float)k3[j], p3);
        p4 = fmaf(q[j], (float)k4[j], p4);
      }
#pragma unroll
      for (int j = 0; j < 8; ++j) {
        p1 = fmaf(qe[j], (float)t1[j], p1);
        p2 = fmaf(qe[j], (float)t2[j], p2);
        p3 = fmaf(qe[j], (float)t3[j], p3);
        p4 = fmaf(qe[j], (float)t4[j], p4);
      }
#pragma unroll
      for (int off = 16; off > 0; off >>= 1) {
        p1 += __shfl_xor(p1, off, 32);
        p2 += __shfl_xor(p2, off, 32);
        p3 += __shfl_xor(p3, off, 32);
        p4 += __shfl_xor(p4, off, 32);
      }
      float ex1 = __expf(p1 * 0.0625f);   // scores O(1); exp without max-shift is safe
      float ex2 = __expf(p2 * 0.0625f);
      float ex3 = __expf(p3 * 0.0625f);
      float ex4 = __expf(p4 * 0.0625f);
      s += (ex1 + ex2) + (ex3 + ex4);
#pragma unroll
      for (int j = 0; j < 8; ++j) {
        acc[j] = fmaf(ex1, (float)v1[j], acc[j]);
        acc[j] = fmaf(ex2, (float)v2[j], acc[j]);
        acc[j] = fmaf(ex3, (float)v3[j], acc[j]);
        acc[j] = fmaf(ex4, (float)v4[j], acc[j]);
      }
#pragma unroll
      for (int j = 0; j < 8; ++j) {
        eacc[j] = fmaf(ex1, (float)t1[j], eacc[j]);
        eacc[j] = fmaf(ex2, (float)t2[j], eacc[j]);
        eacc[j] = fmaf(ex3, (float)t3[j], eacc[j]);
        eacc[j] = fmaf(ex4, (float)t4[j], eacc[j]);
      }
    }
    for (; e < wcnt; e += 2) {               // tail: 1 edge per half, masked
      int eh = e + half;
      bool act = eh < wcnt;
      int s1 = __shfl(widx, act ? eh : e, 32);
      const bf16_t* b1 = &qkvs[(size_t)s1 * 1024 + 256 + l * 8];
      bf16x8 k1 = *(const bf16x8*)b1;
      bf16x8 v1 = *(const bf16x8*)(b1 + 256);
      bf16x8 t1 = {};
      if (act && l < 4)
        t1 = __builtin_nontemporal_load((const bf16x8*)&eac[(size_t)(wb + eh) * DED + l * 8]);
      float p1 = 0.f;
#pragma unroll
      for (int j = 0; j < 8; ++j) p1 = fmaf(q[j], (float)k1[j], p1);
#pragma unroll
      for (int j = 0; j < 8; ++j) p1 = fmaf(qe[j], (float)t1[j], p1);
#pragma unroll
      for (int off = 16; off > 0; off >>= 1) p1 += __shfl_xor(p1, off, 32);
      float ex1 = act ? __expf(p1 * 0.0625f) : 0.f;
      s += ex1;
#pragma unroll
      for (int j = 0; j < 8; ++j) acc[j] = fmaf(ex1, (float)v1[j], acc[j]);
#pragma unroll
      for (int j = 0; j < 8; ++j) eacc[j] = fmaf(ex1, (float)t1[j], eacc[j]);
    }
  }
  // combine halves (same node)
  s += __shfl_xor(s, 32, 64);
#pragma unroll
  for (int j = 0; j < 8; ++j) acc[j] += __shfl_xor(acc[j], 32, 64);
#pragma unroll
  for (int j = 0; j < 8; ++j) eacc[j] += __shfl_xor(eacc[j], 32, 64);
  float inv = 1.f / (s + 1e-16f);
  if (half == 0) {
    bf16x8 o;
#pragma unroll
    for (int j = 0; j < 8; ++j) o[j] = (bf16_t)(acc[j] * inv);
    __builtin_nontemporal_store(o, (bf16x8*)&AGGn[(size_t)n * DH + l * 8]);
    if (l < 4) {
      bf16x8 eo;
#pragma unroll
      for (int j = 0; j < 8; ++j) eo[j] = (bf16_t)(eacc[j] * inv);
      __builtin_nontemporal_store(eo, (bf16x8*)&EAn[(size_t)n * DED + l * 8]);
    }
  }
}

// out = LN( leaky_relu( AGG + EAn@We + S ) ) * g + b ; S = qkvs[:,768:1024]
// E2N is a 32x256 matvec per node (0.8 GFLOP total) — computed inline from an
// LDS-staged We (16KB bf16), killing the separate E2N GEMM + 50MB round trip.
// Grid-stride (1024 blocks) so the We staging amortizes over ~12 node-groups.
__global__ __launch_bounds__(256) void conv_epilogue(
    const bf16_t* __restrict__ AGGn, const bf16_t* __restrict__ EAn,
    const bf16_t* __restrict__ Web, const bf16_t* __restrict__ qkvs,
    const float* __restrict__ g, const float* __restrict__ b,
    bf16_t* __restrict__ out)
{
  __shared__ bf16_t We_s[DED * DH];   // 16 KB, natural [k][col] layout
  int tid = threadIdx.x;
  for (int i = tid; i < DED * DH / 8; i += 256)
    *(bf16x8*)&We_s[i * 8] = *(const bf16x8*)&Web[i * 8];
  __syncthreads();
  int wv = tid >> 6, lane = tid & 63;
  float gc[4], bc[4];
#pragma unroll
  for (int j = 0; j < 4; ++j) { gc[j] = g[lane * 4 + j]; bc[j] = b[lane * 4 + j]; }
  for (int n = blockIdx.x * 4 + wv; n < NN; n += gridDim.x * 4) {
    size_t base = (size_t)n * DH + lane * 4;
    bf16x4 a = __builtin_nontemporal_load((const bf16x4*)&AGGn[base]);
    bf16x4 sv = __builtin_nontemporal_load(
        (const bf16x4*)&qkvs[(size_t)n * 1024 + 768 + lane * 4]);
    // e2[j] = sum_k EAn[n][k] * We[k][lane*4+j]  (EAn row broadcast across lanes)
    float e2[4] = {0.f, 0.f, 0.f, 0.f};
    const bf16x8* ep = (const bf16x8*)&EAn[(size_t)n * DED];
#pragma unroll
    for (int kb = 0; kb < 4; ++kb) {
      bf16x8 ev = __builtin_nontemporal_load(ep + kb);
#pragma unroll
      for (int k = 0; k < 8; ++k) {
        float e = (float)ev[k];
        bf16x4 w = *(const bf16x4*)&We_s[(kb * 8 + k) * DH + lane * 4];
#pragma unroll
        for (int j = 0; j < 4; ++j) e2[j] = fmaf(e, (float)w[j], e2[j]);
      }
    }
    float v[4];
#pragma unroll
    for (int j = 0; j < 4; ++j) {
      float t = (float)a[j] + e2[j] + (float)sv[j];
      v[j] = (t > 0.f) ? t : 0.01f * t;
    }
    float sum = v[0] + v[1] + v[2] + v[3];
    float sq = v[0]*v[0] + v[1]*v[1] + v[2]*v[2] + v[3]*v[3];
#pragma unroll
    for (int off = 32; off > 0; off >>= 1) {
      sum += __shfl_xor(sum, off, 64);
      sq  += __shfl_xor(sq, off, 64);
    }
    float mu = sum * (1.f / DH);
    float var = sq * (1.f / DH) - mu * mu;
    float rstd = rsqrtf(var + 1e-5f);
    bf16x4 o;
#pragma unroll
    for (int j = 0; j < 4; ++j)
      o[j] = (bf16_t)((v[j] - mu) * rstd * gc[j] + bc[j]);
    *(bf16x4*)&out[base] = o;
  }
}

// ---------------- GIN gather: one node per wave ----------------
__global__ __launch_bounds__(256) void gin_gather(
    const int* __restrict__ rowptr, const int* __restrict__ esrc,
    const bf16_t* __restrict__ h, bf16_t* __restrict__ out)
{
  int l = threadIdx.x & 31;
  int half = (threadIdx.x >> 5) & 1;
  int n = blockIdx.x * 4 + (threadIdx.x >> 6);
  if (n >= NN) return;
  size_t co = (size_t)n * DH + l * 8;
  float acc[8];
  {
    bf16x8 hv = *(const bf16x8*)&h[co];
    float w0 = (half == 0) ? 1.f : 0.f;      // self term counted once
#pragma unroll
    for (int j = 0; j < 8; ++j) acc[j] = w0 * (float)hv[j];
  }
  int i0 = rowptr[n], i1 = rowptr[n + 1];
  for (int wb = i0; wb < i1; wb += 32) {
    int wcnt = min(32, i1 - wb);
    int widx = (l < wcnt) ? esrc[wb + l] : 0;
    int e = 0;
    for (; e + 8 <= wcnt; e += 8) {
      int s1 = __shfl(widx, e + half, 32);
      int s2 = __shfl(widx, e + 2 + half, 32);
      int s3 = __shfl(widx, e + 4 + half, 32);
      int s4 = __shfl(widx, e + 6 + half, 32);
      bf16x8 t1 = *(const bf16x8*)&h[(size_t)s1 * DH + l * 8];
      bf16x8 t2 = *(const bf16x8*)&h[(size_t)s2 * DH + l * 8];
      bf16x8 t3 = *(const bf16x8*)&h[(size_t)s3 * DH + l * 8];
      bf16x8 t4 = *(const bf16x8*)&h[(size_t)s4 * DH + l * 8];
#pragma unroll
      for (int j = 0; j < 8; ++j)
        acc[j] += ((float)t1[j] + (float)t2[j]) + ((float)t3[j] + (float)t4[j]);
    }
    for (; e < wcnt; e += 2) {
      int eh = e + half;
      bool act = eh < wcnt;
      int s1 = __shfl(widx, act ? eh : e, 32);
      bf16x8 t1 = *(const bf16x8*)&h[(size_t)s1 * DH + l * 8];
      float w = act ? 1.f : 0.f;
#pragma unroll
      for (int j = 0; j < 8; ++j) acc[j] += w * (float)t1[j];
    }
  }
#pragma unroll
  for (int j = 0; j < 8; ++j) acc[j] += __shfl_xor(acc[j], 32, 64);
  if (half == 0) {
    bf16x8 o;
#pragma unroll
    for (int j = 0; j < 8; ++j) o[j] = (bf16_t)acc[j];
    __builtin_nontemporal_store(o, (bf16x8*)&out[co]);
  }
}

// ---------------- BN (partials produced by GEMM epilogue) ----------------
__global__ void bn_final_na(const float* __restrict__ psum, const float* __restrict__ psq,
                            const float* __restrict__ bng, const float* __restrict__ bnb,
                            float* __restrict__ scale, float* __restrict__ shift) {
  int c = threadIdx.x;
  float s = 0.f, ss = 0.f;
  for (int b = 0; b < 4; ++b) { s += psum[b * DH + c]; ss += psq[b * DH + c]; }
  float mu = s * (1.f / NN);
  float var = ss * (1.f / NN) - mu * mu;
  float rstd = rsqrtf(var + 1e-5f);
  float sc = bng[c] * rstd;
  scale[c] = sc;
  shift[c] = bnb[c] - mu * sc;
}
__global__ void bn_apply_relu8(const bf16_t* __restrict__ y, const float* __restrict__ scale,
                               const float* __restrict__ shift, bf16_t* __restrict__ o, int n8) {
  int i = blockIdx.x * 256 + threadIdx.x;
  if (i >= n8) return;
  bf16x8 v = __builtin_nontemporal_load((const bf16x8*)&y[(size_t)i * 8]);
  int c = (i * 8) & (DH - 1);
  bf16x8 r;
#pragma unroll
  for (int j = 0; j < 8; ++j)
    r[j] = (bf16_t)fmaxf((float)v[j] * scale[c + j] + shift[c + j], 0.f);
  *(bf16x8*)&o[(size_t)i * 8] = r;
}

// ---------------- pooling over sorted batch (bf16 input) ----------------
__global__ __launch_bounds__(256) void pool_sorted(
    const int* __restrict__ batch, const bf16_t* __restrict__ h, float* __restrict__ pooled)
{
  __shared__ int s0, s1;
  int g = blockIdx.x;
  if (threadIdx.x == 0) {
    int lo = 0, hi = NN;
    while (lo < hi) { int mid = (lo + hi) >> 1; if (batch[mid] < g) lo = mid + 1; else hi = mid; }
    s0 = lo;
  }
  if (threadIdx.x == 1) {
    int lo = 0, hi = NN;
    while (lo < hi) { int mid = (lo + hi) >> 1; if (batch[mid] < g + 1) lo = mid + 1; else hi = mid; }
    s1 = lo;
  }
  __syncthreads();
  int c = threadIdx.x;
  float acc = 0.f;
  for (int r = s0; r < s1; ++r)
    acc += (float)__builtin_nontemporal_load(&h[(size_t)r * DH + c]);
  pooled[(size_t)g * DH + c] = acc;
}

// ---------------- small fp32 GEMM (head only) ----------------
__global__ __launch_bounds__(256) void gemm_bias_act(
    const float* __restrict__ A, const float* __restrict__ Wm,
    const float* __restrict__ bias, float* __restrict__ C,
    int M, int K, int Ncol, int act)
{
  __shared__ __align__(16) float As[16][68];
  __shared__ __align__(16) float Bs[16][68];
  int tid = threadIdx.x;
  int tx = tid & 15, ty = tid >> 4;
  int row0 = blockIdx.y * 64 + ty * 4;
  int col0 = blockIdx.x * 64 + tx * 4;
  float acc[4][4] = {{0.f}};
  for (int k0 = 0; k0 < K; k0 += 16) {
#pragma unroll
    for (int l = 0; l < 4; ++l) {
      int e = tid + l * 256;
      int r = e >> 4, kk = e & 15;
      int gr = blockIdx.y * 64 + r;
      As[kk][r] = (gr < M) ? A[(size_t)gr * K + k0 + kk] : 0.f;
    }
#pragma unroll
    for (int l = 0; l < 4; ++l) {
      int e = tid + l * 256;
      int kk = e >> 6, c = e & 63;
      int gc = blockIdx.x * 64 + c;
      Bs[kk][c] = (gc < Ncol) ? Wm[(size_t)(k0 + kk) * Ncol + gc] : 0.f;
    }
    __syncthreads();
#pragma unroll
    for (int kk = 0; kk < 16; ++kk) {
      float4 a4 = *(const float4*)&As[kk][ty * 4];
      float4 b4 = *(const float4*)&Bs[kk][tx * 4];
      float a[4] = {a4.x, a4.y, a4.z, a4.w};
      float b[4] = {b4.x, b4.y, b4.z, b4.w};
#pragma unroll
      for (int i = 0; i < 4; ++i)
#pragma unroll
        for (int j = 0; j < 4; ++j)
          acc[i][j] = fmaf(a[i], b[j], acc[i][j]);
    }
    __syncthreads();
  }
#pragma unroll
  for (int i = 0; i < 4; ++i) {
    int r = row0 + i;
    if (r >= M) continue;
#pragma unroll
    for (int j = 0; j < 4; ++j) {
      int c = col0 + j;
      if (c >= Ncol) continue;
      float val = acc[i][j];
      if (bias) val += bias[c];
      if (act == 1) val = fmaxf(val, 0.f);
      C[(size_t)r * Ncol + c] = val;
    }
  }
}

// ---------------- host ----------------
static inline void launch_filli(hipStream_t st, int* p, int v, long n) {
  fill_i32<<<dim3((unsigned)((n + 255) / 256)), dim3(256), 0, st>>>(p, v, (int)n);
}

extern "C" void kernel_launch(void* const* d_in, const int* in_sizes, int n_in,
                              void* d_out, int out_size, void* d_ws, size_t ws_size,
                              hipStream_t stream) {
  const float* x  = (const float*)d_in[0];
  const int* ei   = (const int*)d_in[1];
  const float* ea = (const float*)d_in[2];
  const int* batch = (const int*)d_in[3];
  const int* src = ei;
  const int* dst = ei + NE;

  const float* c1[9]; for (int i = 0; i < 9; ++i) c1[i] = (const float*)d_in[4 + i];
  const float* ln1g = (const float*)d_in[13]; const float* ln1b = (const float*)d_in[14];
  const float* c2[9]; for (int i = 0; i < 9; ++i) c2[i] = (const float*)d_in[15 + i];
  const float* ln2g = (const float*)d_in[24]; const float* ln2b = (const float*)d_in[25];
  const float* g1[6]; for (int i = 0; i < 6; ++i) g1[i] = (const float*)d_in[26 + i];
  const float* g2[6]; for (int i = 0; i < 6; ++i) g2[i] = (const float*)d_in[32 + i];
  const float* linW = (const float*)d_in[38]; const float* linb = (const float*)d_in[39];
  const float* clfW = (const float*)d_in[40]; const float* clfb = (const float*)d_in[41];
  float* out = (float*)d_out;

  // ---- bump allocator over d_ws (256B aligned) ----
  size_t off = 0;
  auto alloc = [&](size_t bytes) -> void* {
    void* r = (char*)d_ws + off;
    off += (bytes + 255) & ~(size_t)255;
    return r;
  };
  int* deg    = (int*)alloc(NN * 4);
  int* cursor = (int*)alloc(NN * 4);   // contiguous after deg (one merged zero-fill)
  int* rowptr = (int*)alloc((NN + 1) * 4);
  int* esrc   = (int*)alloc((size_t)NE * 4);
  int* epos   = (int*)alloc((size_t)NE * 4);
  int* bsum   = (int*)alloc(1024);
  int* boff   = (int*)alloc(1024);
  float* QEf   = (float*)alloc((size_t)NN * DED * 4);
  float* pooled = (float*)alloc((size_t)NG * DH * 4);
  float* zbuf   = (float*)alloc((size_t)NG * DH * 4);
  float* psum  = (float*)alloc(4 * DH * 4);    // per-wave-group BN partials
  float* psq   = (float*)alloc(4 * DH * 4);    // contiguous after psum
  float* bnscale = (float*)alloc(DH * 4);
  float* bnshift = (float*)alloc(DH * 4);
  float* wqe_tmp1 = (float*)alloc((size_t)DIN * DED * 4);
  float* wqe_tmp2 = (float*)alloc((size_t)DH * DED * 4);
  float* bqe1 = (float*)alloc(DED * 4);
  float* bqe2 = (float*)alloc(DED * 4);
  bf16_t* qkvsb = (bf16_t*)alloc((size_t)NN * 1024 * 2);  // q|k|v|s interleaved
  bf16_t* h_b = (bf16_t*)alloc((size_t)NN * DH * 2);
  bf16_t* g_b = (bf16_t*)alloc((size_t)NN * DH * 2);
  bf16_t* Yb  = (bf16_t*)alloc((size_t)NN * DH * 2);      // GIN y1 (pre-BN), bf16
  bf16_t* AGGb = (bf16_t*)alloc((size_t)NN * DH * 2);
  bf16_t* EAn = (bf16_t*)alloc((size_t)NN * DED * 2);
  bf16_t* xb  = (bf16_t*)alloc((size_t)NN * DIN * 2);
  bf16_t* eac = (bf16_t*)alloc((size_t)NE * DED * 2);     // edge_attr, CSR order
  bf16_t* Hb = (bf16_t*)qkvsb;  // final GIN output bf16, aliases qkvs region
  bf16_t* pk1q = (bf16_t*)alloc(DIN * DH * 2);
  bf16_t* pk1k = (bf16_t*)alloc(DIN * DH * 2);
  bf16_t* pk1v = (bf16_t*)alloc(DIN * DH * 2);
  bf16_t* pk1s = (bf16_t*)alloc(DIN * DH * 2);
  bf16_t* pk1qe = (bf16_t*)alloc(DIN * DED * 2);
  bf16_t* pk2q = (bf16_t*)alloc(DH * DH * 2);
  bf16_t* pk2k = (bf16_t*)alloc(DH * DH * 2);
  bf16_t* pk2v = (bf16_t*)alloc(DH * DH * 2);
  bf16_t* pk2s = (bf16_t*)alloc(DH * DH * 2);
  bf16_t* pk2qe = (bf16_t*)alloc(DH * DED * 2);
  bf16_t* pkg1a = (bf16_t*)alloc(DH * DH * 2);
  bf16_t* pkg1b = (bf16_t*)alloc(DH * DH * 2);
  bf16_t* pkg2a = (bf16_t*)alloc(DH * DH * 2);
  bf16_t* pkg2b = (bf16_t*)alloc(DH * DH * 2);
  bf16_t* web1 = (bf16_t*)alloc(DED * DH * 2);   // We natural-layout bf16 (epilogue)
  bf16_t* web2 = (bf16_t*)alloc(DED * DH * 2);
  if (ws_size < off) return;

  const int GRID_M  = (NN + 127) / 128;   // RT=2 (qkvs)
  const int GRID_M1 = (NN + 63) / 64;     // RT=1 (single-output GEMMs)

  cast_bf16x8_k<<<dim3((unsigned)(((long)NN * DIN / 8 + 255) / 256)), dim3(256), 0, stream>>>(
      x, xb, (long)NN * DIN / 8);
  cast_bf16x8_k<<<dim3(4), dim3(256), 0, stream>>>(c1[6], web1, DED * DH / 8);
  cast_bf16x8_k<<<dim3(4), dim3(256), 0, stream>>>(c2[6], web2, DED * DH / 8);
  wqe_k<<<dim3((DIN * 32 + 255) / 256), dim3(256), 0, stream>>>(c1[0], c1[6], c1[1], wqe_tmp1, bqe1, DIN);
  wqe_k<<<dim3((DH * 32 + 255) / 256), dim3(256), 0, stream>>>(c2[0], c2[6], c2[1], wqe_tmp2, bqe2, DH);
  PackArgs pa;
  pa.e[0]  = {c1[0], pk1q, DIN, DH};
  pa.e[1]  = {c1[2], pk1k, DIN, DH};
  pa.e[2]  = {c1[4], pk1v, DIN, DH};
  pa.e[3]  = {c1[7], pk1s, DIN, DH};
  pa.e[4]  = {wqe_tmp1, pk1qe, DIN, DED};
  pa.e[5]  = {c2[0], pk2q, DH, DH};
  pa.e[6]  = {c2[2], pk2k, DH, DH};
  pa.e[7]  = {c2[4], pk2v, DH, DH};
  pa.e[8]  = {c2[7], pk2s, DH, DH};
  pa.e[9]  = {wqe_tmp2, pk2qe, DH, DED};
  pa.e[10] = {g1[0], pkg1a, DH, DH};
  pa.e[11] = {g1[4], pkg1b, DH, DH};
  pa.e[12] = {g2[0], pkg2a, DH, DH};
  pa.e[13] = {g2[4], pkg2b, DH, DH};
  pa.e[14] = {nullptr, nullptr, 0, 0};
  pa.e[15] = {nullptr, nullptr, 0, 0};
  pack_all<<<dim3(256, 14), dim3(256), 0, stream>>>(pa);

  const int nb1 = (NN + SCAN_T - 1) / SCAN_T;
  // deg and cursor are contiguous 256B-aligned allocations: one merged zero-fill
  launch_filli(stream, deg, 0, 2 * ((NN * 4 + 255) & ~255) / 4);
  count_k<<<dim3((NE + 255) / 256), dim3(256), 0, stream>>>(dst, deg);
  scan1<<<dim3(nb1), dim3(SCAN_T), 0, stream>>>(deg, rowptr, bsum, NN);
  scan2<<<dim3(1), dim3(SCAN_T), 0, stream>>>(bsum, boff, nb1);
  scan3<<<dim3(nb1), dim3(SCAN_T), 0, stream>>>(rowptr, boff, NN);
  scatter_k<<<dim3((NE + 255) / 256), dim3(256), 0, stream>>>(dst, src, rowptr, cursor, esrc, epos);
  permute_ea<<<dim3((unsigned)(((long)NE * 4 + 255) / 256)), dim3(256), 0, stream>>>(epos, ea, eac);

  auto conv = [&](const bf16_t* Ain, int K,
                  const bf16_t* pq, const bf16_t* pk, const bf16_t* pv, const bf16_t* ps,
                  const bf16_t* pqe, const bf16_t* web,
                  const float* const* P, const float* bqe,
                  const float* lng, const float* lnb, bf16_t* outb) {
    QkvsArgs qa;
    qa.w[0] = pq; qa.w[1] = pk; qa.w[2] = pv; qa.w[3] = ps;
    qa.bias[0] = P[1]; qa.bias[1] = P[3]; qa.bias[2] = P[5]; qa.bias[3] = P[8];
    qa.outp[0] = qkvsb + 0; qa.outp[1] = qkvsb + 256;
    qa.outp[2] = qkvsb + 512; qa.outp[3] = qkvsb + 768;
    gemm_qkvs<<<dim3(4, GRID_M), dim3(256), 0, stream>>>(Ain, qa, NN, K);
    gemm_r1<2><<<dim3(GRID_M1), dim3(256), 0, stream>>>(
        Ain, pqe, bqe, QEf, nullptr, NN, K, 0, 32, nullptr, nullptr);
    conv_edge_fused<<<dim3((NN + 3) / 4), dim3(256), 0, stream>>>(
        rowptr, esrc, qkvsb, eac, QEf, AGGb, EAn);
    conv_epilogue<<<dim3(1024), dim3(256), 0, stream>>>(
        AGGb, EAn, web, qkvsb, lng, lnb, outb);
  };

  auto gin = [&](const bf16_t* hin, const bf16_t* pw1, const bf16_t* pw2,
                 const float* const* P, int relu_out, bf16_t* outb) {
    gin_gather<<<dim3((NN + 3) / 4), dim3(256), 0, stream>>>(rowptr, esrc, hin, g_b);
    launch_filli(stream, (int*)psum, 0, 2 * 4 * DH);  // zero psum+psq (contiguous)
    gemm_r1<16><<<dim3(GRID_M1), dim3(256), 0, stream>>>(
        g_b, pw1, P[1], nullptr, Yb, NN, DH, 0, 256, psum, psq);
    bn_final_na<<<dim3(1), dim3(256), 0, stream>>>(psum, psq, P[2], P[3], bnscale, bnshift);
    bn_apply_relu8<<<dim3((NN * DH / 8 + 255) / 256), dim3(256), 0, stream>>>(
        Yb, bnscale, bnshift, g_b, NN * DH / 8);
    gemm_r1<16><<<dim3(GRID_M1), dim3(256), 0, stream>>>(
        g_b, pw2, P[5], nullptr, outb, NN, DH, relu_out, 256, nullptr, nullptr);
  };

  conv(xb, DIN, pk1q, pk1k, pk1v, pk1s, pk1qe, web1, c1, bqe1, ln1g, ln1b, h_b);
  conv(h_b, DH, pk2q, pk2k, pk2v, pk2s, pk2qe, web2, c2, bqe2, ln2g, ln2b, h_b);
  gin(h_b, pkg1a, pkg1b, g1, 1, h_b);
  gin(h_b, pkg2a, pkg2b, g2, 0, Hb);

  pool_sorted<<<dim3(NG), dim3(256), 0, stream>>>(batch, Hb, pooled);
  gemm_bias_act<<<dim3(4, 8), dim3(256), 0, stream>>>(pooled, linW, linb, zbuf, NG, DH, DH, 1);
  gemm_bias_act<<<dim3(1, 8), dim3(256), 0, stream>>>(zbuf, clfW, clfb, out, NG, DH, DOUT, 0);
}

// Round 8
// 1230.361 us; speedup vs baseline: 1.1128x; 1.0479x over previous
//
#include <hip/hip_runtime.h>
#include <math.h>

#define NN 50000
#define NE 800000
#define DIN 128
#define DH 256
#define DED 32
#define NG 500
#define DOUT 16
#define SCAN_T 256

typedef __bf16 bf16_t;
typedef __bf16 bf16x4 __attribute__((ext_vector_type(4)));
typedef __bf16 bf16x8 __attribute__((ext_vector_type(8)));
typedef float f32x4 __attribute__((ext_vector_type(4)));
typedef float f32x2 __attribute__((ext_vector_type(2)));

// async global->LDS, 16B per lane (global_load_lds_dwordx4)
__device__ __forceinline__ void async_copy16(const bf16_t* g, bf16_t* l) {
  __builtin_amdgcn_global_load_lds(
      (const __attribute__((address_space(1))) void*)g,
      (__attribute__((address_space(3))) void*)l, 16, 0, 0);
}

// ---- fp8 (HW cvt ops; encode+decode use the same HW format so the
//      round-trip is self-consistent) ----
__device__ __forceinline__ unsigned char f32_to_fp8(float f) {
  return (unsigned char)__builtin_amdgcn_cvt_pk_fp8_f32(f, f, 0, 0);
}
// dot: p += sum_j q[j] * fp8dec(u)[j]   (u = 8 fp8 bytes, channels +0..+7)
__device__ __forceinline__ void fma_dot8(const float* q, uint2 u, float& p) {
  f32x2 d;
  d = __builtin_amdgcn_cvt_pk_f32_fp8(u.x, 0); p = fmaf(q[0], d[0], p); p = fmaf(q[1], d[1], p);
  d = __builtin_amdgcn_cvt_pk_f32_fp8(u.x, 1); p = fmaf(q[2], d[0], p); p = fmaf(q[3], d[1], p);
  d = __builtin_amdgcn_cvt_pk_f32_fp8(u.y, 0); p = fmaf(q[4], d[0], p); p = fmaf(q[5], d[1], p);
  d = __builtin_amdgcn_cvt_pk_f32_fp8(u.y, 1); p = fmaf(q[6], d[0], p); p = fmaf(q[7], d[1], p);
}
// axpy: acc[j] += ex * fp8dec(u)[j]
__device__ __forceinline__ void fma_axpy8(float ex, uint2 u, float* acc) {
  f32x2 d;
  d = __builtin_amdgcn_cvt_pk_f32_fp8(u.x, 0); acc[0] = fmaf(ex, d[0], acc[0]); acc[1] = fmaf(ex, d[1], acc[1]);
  d = __builtin_amdgcn_cvt_pk_f32_fp8(u.x, 1); acc[2] = fmaf(ex, d[0], acc[2]); acc[3] = fmaf(ex, d[1], acc[3]);
  d = __builtin_amdgcn_cvt_pk_f32_fp8(u.y, 0); acc[4] = fmaf(ex, d[0], acc[4]); acc[5] = fmaf(ex, d[1], acc[5]);
  d = __builtin_amdgcn_cvt_pk_f32_fp8(u.y, 1); acc[6] = fmaf(ex, d[0], acc[6]); acc[7] = fmaf(ex, d[1], acc[7]);
}

// ---------------- utility ----------------
__global__ void fill_i32(int* __restrict__ p, int v, int n) {
  int i = blockIdx.x * 256 + threadIdx.x;
  if (i < n) p[i] = v;
}
__global__ void cast_bf16x8_k(const float* __restrict__ in, bf16_t* __restrict__ o, long n8) {
  long i = (long)blockIdx.x * 256 + threadIdx.x;
  if (i >= n8) return;
  const f32x4* sp = (const f32x4*)&in[i * 8];
  f32x4 a = __builtin_nontemporal_load(sp);
  f32x4 b = __builtin_nontemporal_load(sp + 1);
  bf16x8 r;
#pragma unroll
  for (int j = 0; j < 4; ++j) { r[j] = (bf16_t)a[j]; r[j + 4] = (bf16_t)b[j]; }
  *(bf16x8*)&o[i * 8] = r;
}

// ---------------- CSR build (by dst) ----------------
__global__ void count_k(const int* __restrict__ dst, int* __restrict__ deg) {
  int e = blockIdx.x * 256 + threadIdx.x;
  if (e < NE) atomicAdd(&deg[dst[e]], 1);
}
__global__ void scan1(const int* __restrict__ deg, int* __restrict__ rowptr,
                      int* __restrict__ bsum, int n) {
  __shared__ int s[SCAN_T];
  int t = threadIdx.x, i = blockIdx.x * SCAN_T + t;
  int v = (i < n) ? deg[i] : 0;
  s[t] = v; __syncthreads();
  for (int off = 1; off < SCAN_T; off <<= 1) {
    int add = (t >= off) ? s[t - off] : 0;
    __syncthreads(); s[t] += add; __syncthreads();
  }
  if (i < n) rowptr[i + 1] = s[t];
  if (t == SCAN_T - 1) bsum[blockIdx.x] = s[t];
}
__global__ void scan2(const int* __restrict__ bsum, int* __restrict__ boff, int nb) {
  __shared__ int s[SCAN_T];
  int t = threadIdx.x;
  int v = (t < nb) ? bsum[t] : 0;
  s[t] = v; __syncthreads();
  for (int off = 1; off < SCAN_T; off <<= 1) {
    int add = (t >= off) ? s[t - off] : 0;
    __syncthreads(); s[t] += add; __syncthreads();
  }
  boff[t] = s[t] - v;
}
__global__ void scan3(int* __restrict__ rowptr, const int* __restrict__ boff, int n) {
  int i = blockIdx.x * 256 + threadIdx.x;
  if (i < n) rowptr[i + 1] += boff[i >> 8];
  if (i == 0) rowptr[0] = 0;
}
// records epos[e] = CSR slot of edge e (inverse permutation) so edge_attr can be
// stream-read / scatter-written instead of gather-read.
__global__ void scatter_k(const int* __restrict__ dst, const int* __restrict__ src,
                          const int* __restrict__ rowptr, int* __restrict__ cursor,
                          int* __restrict__ esrc, int* __restrict__ epos) {
  int e = blockIdx.x * 256 + threadIdx.x;
  if (e < NE) {
    int d = dst[e];
    int pos = rowptr[d] + atomicAdd(&cursor[d], 1);
    esrc[pos] = src[e];
    epos[e] = pos;
  }
}
// cast + permute edge_attr into CSR order: sequential fp32 reads (stream),
// scattered 64B bf16 writes (write path tolerates randomness far better).
__global__ void permute_ea(const int* __restrict__ epos, const float* __restrict__ ea,
                           bf16_t* __restrict__ eac) {
  long t = (long)blockIdx.x * 256 + threadIdx.x;
  if (t >= (long)NE * 4) return;
  int e = (int)(t >> 2), c8 = ((int)t & 3) * 8;
  int pos = epos[e];
  const f32x4* sp = (const f32x4*)&ea[(size_t)e * DED + c8];
  f32x4 a = __builtin_nontemporal_load(sp);
  f32x4 b = __builtin_nontemporal_load(sp + 1);
  bf16x8 o;
#pragma unroll
  for (int j = 0; j < 4; ++j) { o[j] = (bf16_t)a[j]; o[j + 4] = (bf16_t)b[j]; }
  __builtin_nontemporal_store(o, (bf16x8*)&eac[(size_t)pos * DED + c8]);
}

// ---------------- weight fragment packing (all weights, one dispatch) ----------------
struct PackEnt { const float* src; bf16_t* dst; int K; int N; };
struct PackArgs { PackEnt e[16]; };
__global__ void pack_all(PackArgs pa) {
  PackEnt en = pa.e[blockIdx.y];
  int i = blockIdx.x * 256 + threadIdx.x;
  if (i >= en.K * en.N) return;
  int el = i & 511, f = i >> 9;
  int ntiles = en.N >> 4;
  int ks = f / ntiles, t = f - ks * ntiles;
  int lane = el >> 3, j = el & 7;
  int k = ks * 32 + (lane >> 4) * 8 + j;
  int n = t * 16 + (lane & 15);
  en.dst[i] = (bf16_t)en.src[(size_t)k * en.N + n];
}

// Wqe[d][j] = sum_h Wq[d][h]*We[j][h]; bqe[j] = sum_h bq[h]*We[j][h]
__global__ void wqe_k(const float* __restrict__ Wq, const float* __restrict__ We,
                      const float* __restrict__ bq, float* __restrict__ Wqe,
                      float* __restrict__ bqe, int din) {
  int idx = blockIdx.x * 256 + threadIdx.x;
  if (idx < din * 32) {
    int d = idx >> 5, j = idx & 31;
    float s = 0.f;
    for (int h = 0; h < DH; ++h) s += Wq[(size_t)d * DH + h] * We[(size_t)j * DH + h];
    Wqe[idx] = s;
  }
  if (idx < 32) {
    float s = 0.f;
    for (int h = 0; h < DH; ++h) s += bq[h] * We[(size_t)idx * DH + h];
    bqe[idx] = s;
  }
}

// ---------------- MFMA GEMM: 2-phase double-buffered LDS staging ------------
// RT row-tiles per wave: block tile = RT*64 rows x NT*16 cols; BK=32.
// stage(next) issued BEFORE compute(cur); single vmcnt(0)+s_barrier per K-step.
// No per-instantiation extras in the hot loop (R5/R6 post-mortem). C8 (fp8
// output) is a literal nullptr in all non-qkvs instantiations -> DCE'd.
// Optional BN column stats (psum/psq[4][DH]) accumulated from the registers.
template<int NT, int RT>
__device__ __forceinline__ void gemm_body(
    const bf16_t* __restrict__ Ab, const bf16_t* __restrict__ Wp,
    const float* __restrict__ bias, float* __restrict__ Cf, bf16_t* __restrict__ Cb,
    unsigned char* __restrict__ C8,
    int M, int K, int relu, int rstride, int bx,
    float* __restrict__ psum, float* __restrict__ psq)
{
  __shared__ bf16_t Atile[2][RT * 2048];   // 2 x RT*4 KB
  __shared__ bf16_t Btile[2][NT * 512];    // 2 x NT KB
  const int ACH = RT * 256;                // A 16B-chunks per kstep
  const int NCH = ACH + NT * 64;
  int tid = threadIdx.x;
  int lane = tid & 63, wv = tid >> 6;
  int base = bx * (RT * 64);
  f32x4 acc[RT][NT];
#pragma unroll
  for (int rt = 0; rt < RT; ++rt)
#pragma unroll
    for (int t = 0; t < NT; ++t) acc[rt][t] = (f32x4){0.f, 0.f, 0.f, 0.f};
  int arow = wv * (16 * RT) + (lane & 15);
  int aq = (lane >> 4) * 8;
  int nk = K >> 5;

  auto stage = [&](int buf, int ks) {
    for (int c = tid; c < NCH; c += 256) {
      if (c < ACH) {                       // A: row = c>>2, 16B sub-chunk q = c&3
        int r = c >> 2, qq = c & 3;
        async_copy16(Ab + (size_t)(base + r) * K + ks * 32 + qq * 8,
                     &Atile[buf][c * 8]);
      } else {                             // B: linear 16B chunks of the kstep block
        int cb = c - ACH;
        async_copy16(Wp + (size_t)ks * NT * 512 + cb * 8, &Btile[buf][cb * 8]);
      }
    }
  };

  stage(0, 0);
  asm volatile("s_waitcnt vmcnt(0)" ::: "memory");
  __builtin_amdgcn_s_barrier();
  int cur = 0;
  for (int ks = 0; ks < nk; ++ks) {
    if (ks + 1 < nk) stage(cur ^ 1, ks + 1);   // prefetch overlaps compute below
    bf16x8 a[RT];
#pragma unroll
    for (int rt = 0; rt < RT; ++rt)
      a[rt] = *(const bf16x8*)&Atile[cur][(arow + rt * 16) * 32 + aq];
#pragma unroll
    for (int t = 0; t < NT; ++t) {
      bf16x8 b = *(const bf16x8*)&Btile[cur][t * 512 + lane * 8];
#pragma unroll
      for (int rt = 0; rt < RT; ++rt)
        acc[rt][t] = __builtin_amdgcn_mfma_f32_16x16x32_bf16(a[rt], b, acc[rt][t], 0, 0, 0);
    }
    asm volatile("s_waitcnt vmcnt(0)" ::: "memory");  // next tile landed
    __builtin_amdgcn_s_barrier();                     // all waves done reading cur
    cur ^= 1;
  }
  int col_l = lane & 15;
#pragma unroll
  for (int rt = 0; rt < RT; ++rt) {
    int rbase = base + wv * (16 * RT) + rt * 16 + (lane >> 4) * 4;
#pragma unroll
    for (int t = 0; t < NT; ++t) {
      int col = t * 16 + col_l;
      float bv = bias ? bias[col] : 0.f;
#pragma unroll
      for (int r = 0; r < 4; ++r) {
        int row = rbase + r;
        if (row >= M) continue;
        float vv = acc[rt][t][r] + bv;
        if (relu) vv = fmaxf(vv, 0.f);
        if (Cf) Cf[(size_t)row * rstride + col] = vv;
        if (Cb) Cb[(size_t)row * rstride + col] = (bf16_t)vv;
        if (C8) C8[(size_t)row * rstride + col] = f32_to_fp8(vv);
      }
    }
  }
  if (psum) {                           // fused BN column stats (GIN y1 only)
#pragma unroll
    for (int t = 0; t < NT; ++t) {
      float sc = 0.f, sq = 0.f;
      float bv = bias[t * 16 + col_l];
#pragma unroll
      for (int rt = 0; rt < RT; ++rt) {
        int rbase = base + wv * (16 * RT) + rt * 16 + (lane >> 4) * 4;
#pragma unroll
        for (int r = 0; r < 4; ++r) {
          if (rbase + r >= M) continue;
          float vv = acc[rt][t][r] + bv;
          sc += vv; sq += vv * vv;
        }
      }
      sc += __shfl_xor(sc, 16, 64); sc += __shfl_xor(sc, 32, 64);
      sq += __shfl_xor(sq, 16, 64); sq += __shfl_xor(sq, 32, 64);
      if (lane < 16) {
        int col = t * 16 + lane;
        atomicAdd(&psum[wv * DH + col], sc);
        atomicAdd(&psq[wv * DH + col], sq);
      }
    }
  }
}

template<int NT>
__global__ __launch_bounds__(256, 3) void gemm_r1(
    const bf16_t* __restrict__ Ab, const bf16_t* __restrict__ Wp,
    const float* __restrict__ bias, float* __restrict__ Cf, bf16_t* __restrict__ Cb,
    int M, int K, int relu, int rstride, float* psum, float* psq)
{
  gemm_body<NT, 1>(Ab, Wp, bias, Cf, Cb, nullptr, M, K, relu, rstride, blockIdx.x,
                   psum, psq);
}

// 4 GEMMs sharing A (q,k,v,s) in one dispatch; grid = (GRID_M, 4) (R7 swap
// reverted: adjacent-id blocks land on different XCDs, no L2 sharing).
// Sets 1,2 (k,v) write fp8 into kv8 (rs=512); sets 0,3 write bf16 (rs=1024).
struct QkvsArgs {
  const bf16_t* w[4]; const float* bias[4];
  bf16_t* outp[4]; unsigned char* out8[4]; int rs[4];
};
__global__ __launch_bounds__(256, 3) void gemm_qkvs(
    const bf16_t* __restrict__ Ab, QkvsArgs qa, int M, int K)
{
  int which = blockIdx.y;
  gemm_body<16, 2>(Ab, qa.w[which], qa.bias[which], nullptr, qa.outp[which],
                   qa.out8[which], M, K, 0, qa.rs[which], blockIdx.x,
                   nullptr, nullptr);
}

// ---------------- fused edge softmax-aggregate: ONE NODE PER WAVE ----------
// Halves of the wave process even/odd edges of the SAME node -> wave-uniform
// trip counts. TLP (8 waves/SIMD at VGPR~64) hides gather latency — do NOT
// register-pipeline this loop (R4 post-mortem: VGPR 112 -> occupancy cliff).
// v5: k/v gathered as fp8 (kv8[NN][512]: k|v) — halves the dominant HBM
// traffic (418MB -> ~230MB); HW cvt_pk decode keeps inner-loop VALU ~equal.
__global__ __launch_bounds__(256) void conv_edge_fused(
    const int* __restrict__ rowptr, const int* __restrict__ esrc,
    const bf16_t* __restrict__ qkvs, const unsigned char* __restrict__ kv8,
    const bf16_t* __restrict__ eac, const float* __restrict__ QEf,
    bf16_t* __restrict__ AGGn, bf16_t* __restrict__ EAn)
{
  int l = threadIdx.x & 31;
  int half = (threadIdx.x >> 5) & 1;
  int n = blockIdx.x * 4 + (threadIdx.x >> 6);
  if (n >= NN) return;
  float q[8];
  {
    bf16x8 t = __builtin_nontemporal_load((const bf16x8*)&qkvs[(size_t)n * 1024 + l * 8]);
#pragma unroll
    for (int j = 0; j < 8; ++j) q[j] = (float)t[j];
  }
  float qe[8];
#pragma unroll
  for (int j = 0; j < 8; ++j) qe[j] = 0.f;
  if (l < 4) {
    const f32x4* p = (const f32x4*)&QEf[(size_t)n * DED + l * 8];
    f32x4 qa = __builtin_nontemporal_load(p);
    f32x4 qb = __builtin_nontemporal_load(p + 1);
#pragma unroll
    for (int j = 0; j < 4; ++j) { qe[j] = qa[j]; qe[j + 4] = qb[j]; }
  }
  float s = 0.f;
  float acc[8], eacc[8];
#pragma unroll
  for (int j = 0; j < 8; ++j) { acc[j] = 0.f; eacc[j] = 0.f; }
  int i0 = rowptr[n], i1 = rowptr[n + 1];
  for (int wb = i0; wb < i1; wb += 32) {
    int wcnt = min(32, i1 - wb);
    int widx = (l < wcnt) ? esrc[wb + l] : 0;
    int e = 0;
    for (; e + 8 <= wcnt; e += 8) {          // 4 edges per half per step
      int s1 = __shfl(widx, e + half, 32);
      int s2 = __shfl(widx, e + 2 + half, 32);
      int s3 = __shfl(widx, e + 4 + half, 32);
      int s4 = __shfl(widx, e + 6 + half, 32);
      const unsigned char* c1p = &kv8[(size_t)s1 * 512 + l * 8];
      const unsigned char* c2p = &kv8[(size_t)s2 * 512 + l * 8];
      const unsigned char* c3p = &kv8[(size_t)s3 * 512 + l * 8];
      const unsigned char* c4p = &kv8[(size_t)s4 * 512 + l * 8];
      uint2 ku1 = *(const uint2*)c1p;
      uint2 ku2 = *(const uint2*)c2p;
      uint2 ku3 = *(const uint2*)c3p;
      uint2 ku4 = *(const uint2*)c4p;
      uint2 vu1 = *(const uint2*)(c1p + 256);
      uint2 vu2 = *(const uint2*)(c2p + 256);
      uint2 vu3 = *(const uint2*)(c3p + 256);
      uint2 vu4 = *(const uint2*)(c4p + 256);
      bf16x8 t1 = {}, t2 = {}, t3 = {}, t4 = {};
      if (l < 4) {
        const bf16_t* ep = &eac[(size_t)(wb + e + half) * DED + l * 8];
        t1 = __builtin_nontemporal_load((const bf16x8*)ep);
        t2 = __builtin_nontemporal_load((const bf16x8*)(ep + 2 * DED));
        t3 = __builtin_nontemporal_load((const bf16x8*)(ep + 4 * DED));
        t4 = __builtin_nontemporal_load((const bf16x8*)(ep + 6 * DED));
      }
      float p1 = 0.f, p2 = 0.f, p3 = 0.f, p4 = 0.f;
      fma_dot8(q, ku1, p1);
      fma_dot8(q, ku2, p2);
      fma_dot8(q, ku3, p3);
      fma_dot8(q, ku4, p4);
#pragma unroll
      for (int j = 0; j < 8; ++j) {
        p1 = fmaf(qe[j], (float)t1[j], p1);
        p2 = fmaf(qe[j], (float)t2[j], p2);
        p3 = fmaf(qe[j], (float)t3[j], p3);
        p4 = fmaf(qe[j], (float)t4[j], p4);
      }
#pragma unroll
      for (int off = 16; off > 0; off >>= 1) {
        p1 += __shfl_xor(p1, off, 32);
        p2 += __shfl_xor(p2, off, 32);
        p3 += __shfl_xor(p3, off, 32);
        p4 += __shfl_xor(p4, off, 32);
      }
      float ex1 = __expf(p1 * 0.0625f);   // scores O(1); exp without max-shift is safe
      float ex2 = __expf(p2 * 0.0625f);
      float ex3 = __expf(p3 * 0.0625f);
      float ex4 = __expf(p4 * 0.0625f);
      s += (ex1 + ex2) + (ex3 + ex4);
      fma_axpy8(ex1, vu1, acc);
      fma_axpy8(ex2, vu2, acc);
      fma_axpy8(ex3, vu3, acc);
      fma_axpy8(ex4, vu4, acc);
#pragma unroll
      for (int j = 0; j < 8; ++j) {
        eacc[j] = fmaf(ex1, (float)t1[j], eacc[j]);
        eacc[j] = fmaf(ex2, (float)t2[j], eacc[j]);
        eacc[j] = fmaf(ex3, (float)t3[j], eacc[j]);
        eacc[j] = fmaf(ex4, (float)t4[j], eacc[j]);
      }
    }
    for (; e < wcnt; e += 2) {               // tail: 1 edge per half, masked
      int eh = e + half;
      bool act = eh < wcnt;
      int s1 = __shfl(widx, act ? eh : e, 32);
      const unsigned char* c1p = &kv8[(size_t)s1 * 512 + l * 8];
      uint2 ku1 = *(const uint2*)c1p;
      uint2 vu1 = *(const uint2*)(c1p + 256);
      bf16x8 t1 = {};
      if (act && l < 4)
        t1 = __builtin_nontemporal_load((const bf16x8*)&eac[(size_t)(wb + eh) * DED + l * 8]);
      float p1 = 0.f;
      fma_dot8(q, ku1, p1);
#pragma unroll
      for (int j = 0; j < 8; ++j) p1 = fmaf(qe[j], (float)t1[j], p1);
#pragma unroll
      for (int off = 16; off > 0; off >>= 1) p1 += __shfl_xor(p1, off, 32);
      float ex1 = act ? __expf(p1 * 0.0625f) : 0.f;
      s += ex1;
      fma_axpy8(ex1, vu1, acc);
#pragma unroll
      for (int j = 0; j < 8; ++j) eacc[j] = fmaf(ex1, (float)t1[j], eacc[j]);
    }
  }
  // combine halves (same node)
  s += __shfl_xor(s, 32, 64);
#pragma unroll
  for (int j = 0; j < 8; ++j) acc[j] += __shfl_xor(acc[j], 32, 64);
#pragma unroll
  for (int j = 0; j < 8; ++j) eacc[j] += __shfl_xor(eacc[j], 32, 64);
  float inv = 1.f / (s + 1e-16f);
  if (half == 0) {
    bf16x8 o;
#pragma unroll
    for (int j = 0; j < 8; ++j) o[j] = (bf16_t)(acc[j] * inv);
    __builtin_nontemporal_store(o, (bf16x8*)&AGGn[(size_t)n * DH + l * 8]);
    if (l < 4) {
      bf16x8 eo;
#pragma unroll
      for (int j = 0; j < 8; ++j) eo[j] = (bf16_t)(eacc[j] * inv);
      __builtin_nontemporal_store(eo, (bf16x8*)&EAn[(size_t)n * DED + l * 8]);
    }
  }
}

// out = LN( leaky_relu( AGG + EAn@We + S ) ) * g + b ; S = qkvs[:,768:1024]
// E2N is a 32x256 matvec per node — computed inline from an LDS-staged We
// (16KB bf16). Grid-stride (1024 blocks) so the We staging amortizes.
__global__ __launch_bounds__(256) void conv_epilogue(
    const bf16_t* __restrict__ AGGn, const bf16_t* __restrict__ EAn,
    const bf16_t* __restrict__ Web, const bf16_t* __restrict__ qkvs,
    const float* __restrict__ g, const float* __restrict__ b,
    bf16_t* __restrict__ out)
{
  __shared__ bf16_t We_s[DED * DH];   // 16 KB, natural [k][col] layout
  int tid = threadIdx.x;
  for (int i = tid; i < DED * DH / 8; i += 256)
    *(bf16x8*)&We_s[i * 8] = *(const bf16x8*)&Web[i * 8];
  __syncthreads();
  int wv = tid >> 6, lane = tid & 63;
  float gc[4], bc[4];
#pragma unroll
  for (int j = 0; j < 4; ++j) { gc[j] = g[lane * 4 + j]; bc[j] = b[lane * 4 + j]; }
  for (int n = blockIdx.x * 4 + wv; n < NN; n += gridDim.x * 4) {
    size_t base = (size_t)n * DH + lane * 4;
    bf16x4 a = __builtin_nontemporal_load((const bf16x4*)&AGGn[base]);
    bf16x4 sv = __builtin_nontemporal_load(
        (const bf16x4*)&qkvs[(size_t)n * 1024 + 768 + lane * 4]);
    // e2[j] = sum_k EAn[n][k] * We[k][lane*4+j]  (EAn row broadcast across lanes)
    float e2[4] = {0.f, 0.f, 0.f, 0.f};
    const bf16x8* ep = (const bf16x8*)&EAn[(size_t)n * DED];
#pragma unroll
    for (int kb = 0; kb < 4; ++kb) {
      bf16x8 ev = __builtin_nontemporal_load(ep + kb);
#pragma unroll
      for (int k = 0; k < 8; ++k) {
        float e = (float)ev[k];
        bf16x4 w = *(const bf16x4*)&We_s[(kb * 8 + k) * DH + lane * 4];
#pragma unroll
        for (int j = 0; j < 4; ++j) e2[j] = fmaf(e, (float)w[j], e2[j]);
      }
    }
    float v[4];
#pragma unroll
    for (int j = 0; j < 4; ++j) {
      float t = (float)a[j] + e2[j] + (float)sv[j];
      v[j] = (t > 0.f) ? t : 0.01f * t;
    }
    float sum = v[0] + v[1] + v[2] + v[3];
    float sq = v[0]*v[0] + v[1]*v[1] + v[2]*v[2] + v[3]*v[3];
#pragma unroll
    for (int off = 32; off > 0; off >>= 1) {
      sum += __shfl_xor(sum, off, 64);
      sq  += __shfl_xor(sq, off, 64);
    }
    float mu = sum * (1.f / DH);
    float var = sq * (1.f / DH) - mu * mu;
    float rstd = rsqrtf(var + 1e-5f);
    bf16x4 o;
#pragma unroll
    for (int j = 0; j < 4; ++j)
      o[j] = (bf16_t)((v[j] - mu) * rstd * gc[j] + bc[j]);
    *(bf16x4*)&out[base] = o;
  }
}

// ---------------- GIN gather: one node per wave ----------------
__global__ __launch_bounds__(256) void gin_gather(
    const int* __restrict__ rowptr, const int* __restrict__ esrc,
    const bf16_t* __restrict__ h, bf16_t* __restrict__ out)
{
  int l = threadIdx.x & 31;
  int half = (threadIdx.x >> 5) & 1;
  int n = blockIdx.x * 4 + (threadIdx.x >> 6);
  if (n >= NN) return;
  size_t co = (size_t)n * DH + l * 8;
  float acc[8];
  {
    bf16x8 hv = *(const bf16x8*)&h[co];
    float w0 = (half == 0) ? 1.f : 0.f;      // self term counted once
#pragma unroll
    for (int j = 0; j < 8; ++j) acc[j] = w0 * (float)hv[j];
  }
  int i0 = rowptr[n], i1 = rowptr[n + 1];
  for (int wb = i0; wb < i1; wb += 32) {
    int wcnt = min(32, i1 - wb);
    int widx = (l < wcnt) ? esrc[wb + l] : 0;
    int e = 0;
    for (; e + 8 <= wcnt; e += 8) {
      int s1 = __shfl(widx, e + half, 32);
      int s2 = __shfl(widx, e + 2 + half, 32);
      int s3 = __shfl(widx, e + 4 + half, 32);
      int s4 = __shfl(widx, e + 6 + half, 32);
      bf16x8 t1 = *(const bf16x8*)&h[(size_t)s1 * DH + l * 8];
      bf16x8 t2 = *(const bf16x8*)&h[(size_t)s2 * DH + l * 8];
      bf16x8 t3 = *(const bf16x8*)&h[(size_t)s3 * DH + l * 8];
      bf16x8 t4 = *(const bf16x8*)&h[(size_t)s4 * DH + l * 8];
#pragma unroll
      for (int j = 0; j < 8; ++j)
        acc[j] += ((float)t1[j] + (float)t2[j]) + ((float)t3[j] + (float)t4[j]);
    }
    for (; e < wcnt; e += 2) {
      int eh = e + half;
      bool act = eh < wcnt;
      int s1 = __shfl(widx, act ? eh : e, 32);
      bf16x8 t1 = *(const bf16x8*)&h[(size_t)s1 * DH + l * 8];
      float w = act ? 1.f : 0.f;
#pragma unroll
      for (int j = 0; j < 8; ++j) acc[j] += w * (float)t1[j];
    }
  }
#pragma unroll
  for (int j = 0; j < 8; ++j) acc[j] += __shfl_xor(acc[j], 32, 64);
  if (half == 0) {
    bf16x8 o;
#pragma unroll
    for (int j = 0; j < 8; ++j) o[j] = (bf16_t)acc[j];
    __builtin_nontemporal_store(o, (bf16x8*)&out[co]);
  }
}

// ---------------- BN (partials produced by GEMM epilogue) ----------------
__global__ void bn_final_na(const float* __restrict__ psum, const float* __restrict__ psq,
                            const float* __restrict__ bng, const float* __restrict__ bnb,
                            float* __restrict__ scale, float* __restrict__ shift) {
  int c = threadIdx.x;
  float s = 0.f, ss = 0.f;
  for (int b = 0; b < 4; ++b) { s += psum[b * DH + c]; ss += psq[b * DH + c]; }
  float mu = s * (1.f / NN);
  float var = ss * (1.f / NN) - mu * mu;
  float rstd = rsqrtf(var + 1e-5f);
  float sc = bng[c] * rstd;
  scale[c] = sc;
  shift[c] = bnb[c] - mu * sc;
}
__global__ void bn_apply_relu8(const bf16_t* __restrict__ y, const float* __restrict__ scale,
                               const float* __restrict__ shift, bf16_t* __restrict__ o, int n8) {
  int i = blockIdx.x * 256 + threadIdx.x;
  if (i >= n8) return;
  bf16x8 v = __builtin_nontemporal_load((const bf16x8*)&y[(size_t)i * 8]);
  int c = (i * 8) & (DH - 1);
  bf16x8 r;
#pragma unroll
  for (int j = 0; j < 8; ++j)
    r[j] = (bf16_t)fmaxf((float)v[j] * scale[c + j] + shift[c + j], 0.f);
  *(bf16x8*)&o[(size_t)i * 8] = r;
}

// ---------------- pooling over sorted batch (bf16 input) ----------------
__global__ __launch_bounds__(256) void pool_sorted(
    const int* __restrict__ batch, const bf16_t* __restrict__ h, float* __restrict__ pooled)
{
  __shared__ int s0, s1;
  int g = blockIdx.x;
  if (threadIdx.x == 0) {
    int lo = 0, hi = NN;
    while (lo < hi) { int mid = (lo + hi) >> 1; if (batch[mid] < g) lo = mid + 1; else hi = mid; }
    s0 = lo;
  }
  if (threadIdx.x == 1) {
    int lo = 0, hi = NN;
    while (lo < hi) { int mid = (lo + hi) >> 1; if (batch[mid] < g + 1) lo = mid + 1; else hi = mid; }
    s1 = lo;
  }
  __syncthreads();
  int c = threadIdx.x;
  float acc = 0.f;
  for (int r = s0; r < s1; ++r)
    acc += (float)__builtin_nontemporal_load(&h[(size_t)r * DH + c]);
  pooled[(size_t)g * DH + c] = acc;
}

// ---------------- small fp32 GEMM (head only) ----------------
__global__ __launch_bounds__(256) void gemm_bias_act(
    const float* __restrict__ A, const float* __restrict__ Wm,
    const float* __restrict__ bias, float* __restrict__ C,
    int M, int K, int Ncol, int act)
{
  __shared__ __align__(16) float As[16][68];
  __shared__ __align__(16) float Bs[16][68];
  int tid = threadIdx.x;
  int tx = tid & 15, ty = tid >> 4;
  int row0 = blockIdx.y * 64 + ty * 4;
  int col0 = blockIdx.x * 64 + tx * 4;
  float acc[4][4] = {{0.f}};
  for (int k0 = 0; k0 < K; k0 += 16) {
#pragma unroll
    for (int l = 0; l < 4; ++l) {
      int e = tid + l * 256;
      int r = e >> 4, kk = e & 15;
      int gr = blockIdx.y * 64 + r;
      As[kk][r] = (gr < M) ? A[(size_t)gr * K + k0 + kk] : 0.f;
    }
#pragma unroll
    for (int l = 0; l < 4; ++l) {
      int e = tid + l * 256;
      int kk = e >> 6, c = e & 63;
      int gc = blockIdx.x * 64 + c;
      Bs[kk][c] = (gc < Ncol) ? Wm[(size_t)(k0 + kk) * Ncol + gc] : 0.f;
    }
    __syncthreads();
#pragma unroll
    for (int kk = 0; kk < 16; ++kk) {
      float4 a4 = *(const float4*)&As[kk][ty * 4];
      float4 b4 = *(const float4*)&Bs[kk][tx * 4];
      float a[4] = {a4.x, a4.y, a4.z, a4.w};
      float b[4] = {b4.x, b4.y, b4.z, b4.w};
#pragma unroll
      for (int i = 0; i < 4; ++i)
#pragma unroll
        for (int j = 0; j < 4; ++j)
          acc[i][j] = fmaf(a[i], b[j], acc[i][j]);
    }
    __syncthreads();
  }
#pragma unroll
  for (int i = 0; i < 4; ++i) {
    int r = row0 + i;
    if (r >= M) continue;
#pragma unroll
    for (int j = 0; j < 4; ++j) {
      int c = col0 + j;
      if (c >= Ncol) continue;
      float val = acc[i][j];
      if (bias) val += bias[c];
      if (act == 1) val = fmaxf(val, 0.f);
      C[(size_t)r * Ncol + c] = val;
    }
  }
}

// ---------------- host ----------------
static inline void launch_filli(hipStream_t st, int* p, int v, long n) {
  fill_i32<<<dim3((unsigned)((n + 255) / 256)), dim3(256), 0, st>>>(p, v, (int)n);
}

extern "C" void kernel_launch(void* const* d_in, const int* in_sizes, int n_in,
                              void* d_out, int out_size, void* d_ws, size_t ws_size,
                              hipStream_t stream) {
  const float* x  = (const float*)d_in[0];
  const int* ei   = (const int*)d_in[1];
  const float* ea = (const float*)d_in[2];
  const int* batch = (const int*)d_in[3];
  const int* src = ei;
  const int* dst = ei + NE;

  const float* c1[9]; for (int i = 0; i < 9; ++i) c1[i] = (const float*)d_in[4 + i];
  const float* ln1g = (const float*)d_in[13]; const float* ln1b = (const float*)d_in[14];
  const float* c2[9]; for (int i = 0; i < 9; ++i) c2[i] = (const float*)d_in[15 + i];
  const float* ln2g = (const float*)d_in[24]; const float* ln2b = (const float*)d_in[25];
  const float* g1[6]; for (int i = 0; i < 6; ++i) g1[i] = (const float*)d_in[26 + i];
  const float* g2[6]; for (int i = 0; i < 6; ++i) g2[i] = (const float*)d_in[32 + i];
  const float* linW = (const float*)d_in[38]; const float* linb = (const float*)d_in[39];
  const float* clfW = (const float*)d_in[40]; const float* clfb = (const float*)d_in[41];
  float* out = (float*)d_out;

  // ---- bump allocator over d_ws (256B aligned) ----
  size_t off = 0;
  auto alloc = [&](size_t bytes) -> void* {
    void* r = (char*)d_ws + off;
    off += (bytes + 255) & ~(size_t)255;
    return r;
  };
  int* deg    = (int*)alloc(NN * 4);
  int* cursor = (int*)alloc(NN * 4);   // contiguous after deg (one merged zero-fill)
  int* rowptr = (int*)alloc((NN + 1) * 4);
  int* esrc   = (int*)alloc((size_t)NE * 4);
  int* epos   = (int*)alloc((size_t)NE * 4);
  int* bsum   = (int*)alloc(1024);
  int* boff   = (int*)alloc(1024);
  float* QEf   = (float*)alloc((size_t)NN * DED * 4);
  float* pooled = (float*)alloc((size_t)NG * DH * 4);
  float* zbuf   = (float*)alloc((size_t)NG * DH * 4);
  float* psum  = (float*)alloc(4 * DH * 4);    // per-wave-group BN partials
  float* psq   = (float*)alloc(4 * DH * 4);    // contiguous after psum
  float* bnscale = (float*)alloc(DH * 4);
  float* bnshift = (float*)alloc(DH * 4);
  float* wqe_tmp1 = (float*)alloc((size_t)DIN * DED * 4);
  float* wqe_tmp2 = (float*)alloc((size_t)DH * DED * 4);
  float* bqe1 = (float*)alloc(DED * 4);
  float* bqe2 = (float*)alloc(DED * 4);
  bf16_t* qkvsb = (bf16_t*)alloc((size_t)NN * 1024 * 2);  // q|.|.|s (k,v now fp8)
  unsigned char* kv8 = (unsigned char*)alloc((size_t)NN * 512);  // k|v fp8
  bf16_t* h_b = (bf16_t*)alloc((size_t)NN * DH * 2);
  bf16_t* g_b = (bf16_t*)alloc((size_t)NN * DH * 2);
  bf16_t* Yb  = (bf16_t*)alloc((size_t)NN * DH * 2);      // GIN y1 (pre-BN), bf16
  bf16_t* AGGb = (bf16_t*)alloc((size_t)NN * DH * 2);
  bf16_t* EAn = (bf16_t*)alloc((size_t)NN * DED * 2);
  bf16_t* xb  = (bf16_t*)alloc((size_t)NN * DIN * 2);
  bf16_t* eac = (bf16_t*)alloc((size_t)NE * DED * 2);     // edge_attr, CSR order
  bf16_t* Hb = (bf16_t*)qkvsb;  // final GIN output bf16, aliases qkvs region
  bf16_t* pk1q = (bf16_t*)alloc(DIN * DH * 2);
  bf16_t* pk1k = (bf16_t*)alloc(DIN * DH * 2);
  bf16_t* pk1v = (bf16_t*)alloc(DIN * DH * 2);
  bf16_t* pk1s = (bf16_t*)alloc(DIN * DH * 2);
  bf16_t* pk1qe = (bf16_t*)alloc(DIN * DED * 2);
  bf16_t* pk2q = (bf16_t*)alloc(DH * DH * 2);
  bf16_t* pk2k = (bf16_t*)alloc(DH * DH * 2);
  bf16_t* pk2v = (bf16_t*)alloc(DH * DH * 2);
  bf16_t* pk2s = (bf16_t*)alloc(DH * DH * 2);
  bf16_t* pk2qe = (bf16_t*)alloc(DH * DED * 2);
  bf16_t* pkg1a = (bf16_t*)alloc(DH * DH * 2);
  bf16_t* pkg1b = (bf16_t*)alloc(DH * DH * 2);
  bf16_t* pkg2a = (bf16_t*)alloc(DH * DH * 2);
  bf16_t* pkg2b = (bf16_t*)alloc(DH * DH * 2);
  bf16_t* web1 = (bf16_t*)alloc(DED * DH * 2);   // We natural-layout bf16 (epilogue)
  bf16_t* web2 = (bf16_t*)alloc(DED * DH * 2);
  if (ws_size < off) return;

  const int GRID_M  = (NN + 127) / 128;   // RT=2 (qkvs)
  const int GRID_M1 = (NN + 63) / 64;     // RT=1 (single-output GEMMs)

  cast_bf16x8_k<<<dim3((unsigned)(((long)NN * DIN / 8 + 255) / 256)), dim3(256), 0, stream>>>(
      x, xb, (long)NN * DIN / 8);
  cast_bf16x8_k<<<dim3(4), dim3(256), 0, stream>>>(c1[6], web1, DED * DH / 8);
  cast_bf16x8_k<<<dim3(4), dim3(256), 0, stream>>>(c2[6], web2, DED * DH / 8);
  wqe_k<<<dim3((DIN * 32 + 255) / 256), dim3(256), 0, stream>>>(c1[0], c1[6], c1[1], wqe_tmp1, bqe1, DIN);
  wqe_k<<<dim3((DH * 32 + 255) / 256), dim3(256), 0, stream>>>(c2[0], c2[6], c2[1], wqe_tmp2, bqe2, DH);
  PackArgs pa;
  pa.e[0]  = {c1[0], pk1q, DIN, DH};
  pa.e[1]  = {c1[2], pk1k, DIN, DH};
  pa.e[2]  = {c1[4], pk1v, DIN, DH};
  pa.e[3]  = {c1[7], pk1s, DIN, DH};
  pa.e[4]  = {wqe_tmp1, pk1qe, DIN, DED};
  pa.e[5]  = {c2[0], pk2q, DH, DH};
  pa.e[6]  = {c2[2], pk2k, DH, DH};
  pa.e[7]  = {c2[4], pk2v, DH, DH};
  pa.e[8]  = {c2[7], pk2s, DH, DH};
  pa.e[9]  = {wqe_tmp2, pk2qe, DH, DED};
  pa.e[10] = {g1[0], pkg1a, DH, DH};
  pa.e[11] = {g1[4], pkg1b, DH, DH};
  pa.e[12] = {g2[0], pkg2a, DH, DH};
  pa.e[13] = {g2[4], pkg2b, DH, DH};
  pa.e[14] = {nullptr, nullptr, 0, 0};
  pa.e[15] = {nullptr, nullptr, 0, 0};
  pack_all<<<dim3(256, 14), dim3(256), 0, stream>>>(pa);

  const int nb1 = (NN + SCAN_T - 1) / SCAN_T;
  // deg and cursor are contiguous 256B-aligned allocations: one merged zero-fill
  launch_filli(stream, deg, 0, 2 * ((NN * 4 + 255) & ~255) / 4);
  count_k<<<dim3((NE + 255) / 256), dim3(256), 0, stream>>>(dst, deg);
  scan1<<<dim3(nb1), dim3(SCAN_T), 0, stream>>>(deg, rowptr, bsum, NN);
  scan2<<<dim3(1), dim3(SCAN_T), 0, stream>>>(bsum, boff, nb1);
  scan3<<<dim3(nb1), dim3(SCAN_T), 0, stream>>>(rowptr, boff, NN);
  scatter_k<<<dim3((NE + 255) / 256), dim3(256), 0, stream>>>(dst, src, rowptr, cursor, esrc, epos);
  permute_ea<<<dim3((unsigned)(((long)NE * 4 + 255) / 256)), dim3(256), 0, stream>>>(epos, ea, eac);

  auto conv = [&](const bf16_t* Ain, int K,
                  const bf16_t* pq, const bf16_t* pk, const bf16_t* pv, const bf16_t* ps,
                  const bf16_t* pqe, const bf16_t* web,
                  const float* const* P, const float* bqe,
                  const float* lng, const float* lnb, bf16_t* outb) {
    QkvsArgs qa;
    qa.w[0] = pq; qa.w[1] = pk; qa.w[2] = pv; qa.w[3] = ps;
    qa.bias[0] = P[1]; qa.bias[1] = P[3]; qa.bias[2] = P[5]; qa.bias[3] = P[8];
    qa.outp[0] = qkvsb + 0; qa.outp[1] = nullptr;
    qa.outp[2] = nullptr;   qa.outp[3] = qkvsb + 768;
    qa.out8[0] = nullptr;   qa.out8[1] = kv8;
    qa.out8[2] = kv8 + 256; qa.out8[3] = nullptr;
    qa.rs[0] = 1024; qa.rs[1] = 512; qa.rs[2] = 512; qa.rs[3] = 1024;
    gemm_qkvs<<<dim3(GRID_M, 4), dim3(256), 0, stream>>>(Ain, qa, NN, K);
    gemm_r1<2><<<dim3(GRID_M1), dim3(256), 0, stream>>>(
        Ain, pqe, bqe, QEf, nullptr, NN, K, 0, 32, nullptr, nullptr);
    conv_edge_fused<<<dim3((NN + 3) / 4), dim3(256), 0, stream>>>(
        rowptr, esrc, qkvsb, kv8, eac, QEf, AGGb, EAn);
    conv_epilogue<<<dim3(1024), dim3(256), 0, stream>>>(
        AGGb, EAn, web, qkvsb, lng, lnb, outb);
  };

  auto gin = [&](const bf16_t* hin, const bf16_t* pw1, const bf16_t* pw2,
                 const float* const* P, int relu_out, bf16_t* outb) {
    gin_gather<<<dim3((NN + 3) / 4), dim3(256), 0, stream>>>(rowptr, esrc, hin, g_b);
    launch_filli(stream, (int*)psum, 0, 2 * 4 * DH);  // zero psum+psq (contiguous)
    gemm_r1<16><<<dim3(GRID_M1), dim3(256), 0, stream>>>(
        g_b, pw1, P[1], nullptr, Yb, NN, DH, 0, 256, psum, psq);
    bn_final_na<<<dim3(1), dim3(256), 0, stream>>>(psum, psq, P[2], P[3], bnscale, bnshift);
    bn_apply_relu8<<<dim3((NN * DH / 8 + 255) / 256), dim3(256), 0, stream>>>(
        Yb, bnscale, bnshift, g_b, NN * DH / 8);
    gemm_r1<16><<<dim3(GRID_M1), dim3(256), 0, stream>>>(
        g_b, pw2, P[5], nullptr, outb, NN, DH, relu_out, 256, nullptr, nullptr);
  };

  conv(xb, DIN, pk1q, pk1k, pk1v, pk1s, pk1qe, web1, c1, bqe1, ln1g, ln1b, h_b);
  conv(h_b, DH, pk2q, pk2k, pk2v, pk2s, pk2qe, web2, c2, bqe2, ln2g, ln2b, h_b);
  gin(h_b, pkg1a, pkg1b, g1, 1, h_b);
  gin(h_b, pkg2a, pkg2b, g2, 0, Hb);

  pool_sorted<<<dim3(NG), dim3(256), 0, stream>>>(batch, Hb, pooled);
  gemm_bias_act<<<dim3(4, 8), dim3(256), 0, stream>>>(pooled, linW, linb, zbuf, NG, DH, DH, 1);
  gemm_bias_act<<<dim3(1, 8), dim3(256), 0, stream>>>(zbuf, clfW, clfb, out, NG, DH, DOUT, 0);
}